// Round 13
// baseline (121.368 us; speedup 1.0000x reference)
//
#include <hip/hip_runtime.h>
#include <cmath>

typedef _Float16 f16;
typedef _Float16 f16x8 __attribute__((ext_vector_type(8)));
typedef _Float16 f16x4 __attribute__((ext_vector_type(4)));
typedef float    f32x4 __attribute__((ext_vector_type(4)));
typedef unsigned int u32;
typedef u32 u32x4 __attribute__((ext_vector_type(4)));

#define C_   192
#define HH   56
#define WW   56
#define NN   3136
#define BB   8
#define MM   784
#define NHEAD 4
#define HD   48
#define VT_LD 832            // padded key-dim of transposed V (784 + 48)
#define QPB  (BB*NN/64)      // 392 proj blocks, Q path
#define KVPB (BB*MM/64)      // 98 proj blocks per K / V path

#define MFMA16(a,b,c) __builtin_amdgcn_mfma_f32_16x16x32_f16(a,b,c,0,0,0)

static __device__ __forceinline__ u32 pkrtz(float a, float b) {
    typedef __fp16 fp16x2 __attribute__((ext_vector_type(2)));
    fp16x2 h = __builtin_amdgcn_cvt_pkrtz(a, b);
    return __builtin_bit_cast(u32, h);
}

// async global->LDS, 16B per lane; LDS dst = wave-uniform base + lane*16
static __device__ __forceinline__ void gload16(const void* g, void* l) {
    __builtin_amdgcn_global_load_lds(
        (const __attribute__((address_space(1))) unsigned int*)g,
        (__attribute__((address_space(3))) unsigned int*)l, 16, 0, 0);
}

// ---------------------------------------------------------------------------
// Depthwise 3x3 + BN, TWO vertically-adjacent outputs per thread (shares
// loaded rows: 12 loads / 2 outputs at stride 1 vs 18). Weights from LDS.
template<int STRIDE, int OH, int OW>
__device__ __forceinline__ void dwbn_pair(
    const float* __restrict__ x, const float* __restrict__ dwL,
    const float* __restrict__ gamma, const float* __restrict__ beta,
    const float* __restrict__ mean,  const float* __restrict__ var,
    f16* __restrict__ out, int idx)
{
    int c4 = idx % 48;
    int r1 = idx / 48;
    int ox = r1 % OW;
    int r2 = r1 / OW;
    int p  = r2 % (OH/2);
    int b  = r2 / (OH/2);
    int c0 = c4*4;

    float4 w4[9];
    #pragma unroll
    for (int j = 0; j < 9; ++j)
        w4[j] = *(const float4*)&dwL[c4*40 + j*4];
    const float* wf = (const float*)w4;   // wf[cc*9 + wi], static indices

    float4 g4  = *(const float4*)(gamma + c0);
    float4 be4 = *(const float4*)(beta + c0);
    float4 m4  = *(const float4*)(mean + c0);
    float4 v4  = *(const float4*)(var  + c0);

    const int NR = STRIDE + 3;           // union of both 3-row windows
    float4 a0 = make_float4(0.f,0.f,0.f,0.f), a1 = a0;
    int iyTop = (2*p)*STRIDE - 1;
    int ix0 = ox*STRIDE - 1;
    #pragma unroll
    for (int j = 0; j < NR; ++j) {
        int iy = iyTop + j;
        if (iy < 0 || iy >= HH) continue;
        #pragma unroll
        for (int kx = 0; kx < 3; ++kx) {
            int ix = ix0 + kx;
            if (ix < 0 || ix >= WW) continue;
            float4 xv = *reinterpret_cast<const float4*>(
                x + ((size_t)b*NN + iy*WW + ix)*C_ + c0);
            if (j <= 2) {                       // contributes to out row 2p
                const int wi = j*3 + kx;
                a0.x = fmaf(wf[ 0+wi], xv.x, a0.x);
                a0.y = fmaf(wf[ 9+wi], xv.y, a0.y);
                a0.z = fmaf(wf[18+wi], xv.z, a0.z);
                a0.w = fmaf(wf[27+wi], xv.w, a0.w);
            }
            if (j >= STRIDE) {                  // contributes to out row 2p+1
                const int wi = (j-STRIDE)*3 + kx;
                a1.x = fmaf(wf[ 0+wi], xv.x, a1.x);
                a1.y = fmaf(wf[ 9+wi], xv.y, a1.y);
                a1.z = fmaf(wf[18+wi], xv.z, a1.z);
                a1.w = fmaf(wf[27+wi], xv.w, a1.w);
            }
        }
    }
    float i0 = g4.x*__frsqrt_rn(v4.x + 1e-5f);
    float i1 = g4.y*__frsqrt_rn(v4.y + 1e-5f);
    float i2 = g4.z*__frsqrt_rn(v4.z + 1e-5f);
    float i3 = g4.w*__frsqrt_rn(v4.w + 1e-5f);
    float b0 = be4.x - m4.x*i0, b1 = be4.y - m4.y*i1;
    float b2 = be4.z - m4.z*i2, b3 = be4.w - m4.w*i3;
    f16x4 r0, r1v;
    r0[0] = (f16)(a0.x*i0 + b0); r0[1] = (f16)(a0.y*i1 + b1);
    r0[2] = (f16)(a0.z*i2 + b2); r0[3] = (f16)(a0.w*i3 + b3);
    r1v[0] = (f16)(a1.x*i0 + b0); r1v[1] = (f16)(a1.y*i1 + b1);
    r1v[2] = (f16)(a1.z*i2 + b2); r1v[3] = (f16)(a1.w*i3 + b3);
    size_t o0 = (((size_t)b*OH + 2*p)*OW + ox)*48 + c4;
    *reinterpret_cast<f16x4*>(out + o0*4)            = r0;
    *reinterpret_cast<f16x4*>(out + (o0 + (size_t)OW*48)*4) = r1v;
}

// ---------------------------------------------------------------------------
// Fused prep: dwbn-pairs (both paths) + pointwise-fold + Vt pad zero.
// blocks 0..2351       : dwbn Q path (2 rows/thread)
// blocks 2352..2939    : dwbn KV path
// blocks 2940..3515    : M-fold (192 threads active)
// blocks 3516..3803    : Vt pad columns 784..831
__global__ __launch_bounds__(256) void prep_all(
    const float* __restrict__ x,
    const float* __restrict__ dwq,  const float* __restrict__ gq,
    const float* __restrict__ bq_,  const float* __restrict__ mq,
    const float* __restrict__ vq,
    const float* __restrict__ dwkv, const float* __restrict__ gkv,
    const float* __restrict__ bkv,  const float* __restrict__ mkv,
    const float* __restrict__ vkv,
    const float* __restrict__ Wq, const float* __restrict__ Wk,
    const float* __restrict__ Wv, const float* __restrict__ pw_q,
    const float* __restrict__ pw_kv,
    f16* __restrict__ uq, f16* __restrict__ ukv,
    f16* __restrict__ Mq, f16* __restrict__ Mk, f16* __restrict__ Mv,
    f16* __restrict__ vt)
{
    int blk = blockIdx.x, tid = threadIdx.x;
    const int QB = 2352, KB = 588;
    if (blk < QB + KB) {
        bool qp = blk < QB;
        __shared__ __align__(16) float dwL[48*40];
        const float* dwg = qp ? dwq : dwkv;
        for (int i = tid; i < 432; i += 256) {
            int f  = i*4;
            int c4 = f/36, r = f%36;
            *(float4*)&dwL[c4*40 + r] = *(const float4*)(dwg + f);
        }
        __syncthreads();
        if (qp)
            dwbn_pair<1, HH, WW>(x, dwL, gq, bq_, mq, vq, uq, blk*256 + tid);
        else
            dwbn_pair<2, 28, 28>(x, dwL, gkv, bkv, mkv, vkv, ukv,
                                 (blk - QB)*256 + tid);
    } else if (blk < QB + KB + 576) {
        int fb = blk - QB - KB;
        int which = fb / 192, o = fb % 192;
        const float* Wm = which == 0 ? Wq : (which == 1 ? Wk : Wv);
        const float* P  = which == 0 ? pw_q : (which == 1 ? pw_kv : pw_kv + C_*C_);
        f16* Mo         = which == 0 ? Mq : (which == 1 ? Mk : Mv);
        __shared__ float wrow[C_];
        if (tid < C_) wrow[tid] = Wm[o*C_ + tid];
        __syncthreads();
        if (tid < C_) {
            float acc = 0.f;
            #pragma unroll 8
            for (int j = 0; j < C_; ++j)
                acc = fmaf(wrow[j], P[j*C_ + tid], acc);
            Mo[o*C_ + tid] = (f16)acc;
        }
    } else {
        int i = (blk - QB - KB - 576)*256 + tid;   // BB*C_*48 = 73728 exactly
        int b = i / (C_*48);
        int rem = i % (C_*48);
        int c = rem / 48;
        int m = MM + (rem % 48);
        vt[((size_t)b*C_ + c)*VT_LD + m] = (f16)0.f;
    }
}

// ---------------------------------------------------------------------------
// Projections, 3-way split for load balance: blocks [0,392) Q, [392,490) K,
// [490,588) V. Q/K use swapped operands (packed 8B stores); V transposed.
__global__ __launch_bounds__(256, 1) void proj_all(
    const f16* __restrict__ uq, const f16* __restrict__ ukv,
    const f16* __restrict__ Mq, const f16* __restrict__ Mk,
    const f16* __restrict__ Mv,
    const float* __restrict__ bq, const float* __restrict__ bk,
    const float* __restrict__ bv,
    f16* __restrict__ qb, f16* __restrict__ kb, f16* __restrict__ vt)
{
    int tid  = threadIdx.x;
    int w    = tid >> 6, l = tid & 63;
    int lrow = l & 15,  lgrp = l >> 4;
    int blk  = blockIdx.x;
    int path = blk < QPB ? 0 : (blk < QPB + KVPB ? 1 : 2);
    const f16* U = path == 0 ? uq : ukv;
    int rblk = path == 0 ? blk : (path == 1 ? blk - QPB : blk - QPB - KVPB);
    int r0 = rblk*64 + w*16;

    const f16* urow = U + (size_t)(r0 + lrow)*C_;
    f16x8 a[6];
    #pragma unroll
    for (int ch = 0; ch < 6; ++ch)
        a[ch] = *(const f16x8*)(urow + ch*32 + lgrp*8);

    f16x8 bfA[6], bfB[6];
    const f16* Mm = path == 0 ? Mq : (path == 1 ? Mk : Mv);

    #pragma unroll
    for (int ch = 0; ch < 6; ++ch)
        bfA[ch] = *(const f16x8*)(Mm + (size_t)lrow*C_ + ch*32 + lgrp*8);

    if (path < 2) {
        // scale: Q folds 1/sqrt(48)*log2(e) for exp2-domain softmax
        const float sc = path == 0 ? 0.14433756729740643f*1.4426950408889634f
                                   : 1.0f;
        const float* bias = path == 0 ? bq : bk;
        f16* dst = path == 0 ? qb : kb;
        #pragma unroll
        for (int ct = 0; ct < 12; ++ct) {
            f16x8* cur = (ct & 1) ? bfB : bfA;
            f16x8* nxt = (ct & 1) ? bfA : bfB;
            if (ct < 11) {
                const f16* mrow = Mm + (size_t)((ct+1)*16 + lrow)*C_;
                #pragma unroll
                for (int ch = 0; ch < 6; ++ch)
                    nxt[ch] = *(const f16x8*)(mrow + ch*32 + lgrp*8);
            }
            f32x4 acc = {0.f,0.f,0.f,0.f};
            #pragma unroll
            for (int ch = 0; ch < 6; ++ch)
                acc = MFMA16(cur[ch], a[ch], acc);          // swapped
            float4 bo = *(const float4*)(bias + ct*16 + lgrp*4);
            f16x4 st;
            st[0] = (f16)((acc[0] + bo.x)*sc);
            st[1] = (f16)((acc[1] + bo.y)*sc);
            st[2] = (f16)((acc[2] + bo.z)*sc);
            st[3] = (f16)((acc[3] + bo.w)*sc);
            *(f16x4*)(dst + (size_t)(r0 + lrow)*C_ + ct*16 + lgrp*4) = st;
        }
    } else {
        #pragma unroll
        for (int ct = 0; ct < 12; ++ct) {            // V projection (transposed)
            f16x8* cur = (ct & 1) ? bfB : bfA;
            f16x8* nxt = (ct & 1) ? bfA : bfB;
            if (ct < 11) {
                const f16* mrow = Mv + (size_t)((ct+1)*16 + lrow)*C_;
                #pragma unroll
                for (int ch = 0; ch < 6; ++ch)
                    nxt[ch] = *(const f16x8*)(mrow + ch*32 + lgrp*8);
            }
            int o = ct*16 + lrow;
            f32x4 acc = {0.f,0.f,0.f,0.f};
            #pragma unroll
            for (int ch = 0; ch < 6; ++ch)
                acc = MFMA16(a[ch], cur[ch], acc);
            float bo = bv[o];
            int rg = r0 + lgrp*4;
            int b  = rg / MM, m = rg % MM;            // 784 % 16 == 0
            f16x4 st;
            st[0] = (f16)(acc[0] + bo);
            st[1] = (f16)(acc[1] + bo);
            st[2] = (f16)(acc[2] + bo);
            st[3] = (f16)(acc[3] + bo);
            *(f16x4*)(vt + ((size_t)b*C_ + o)*VT_LD + m) = st;
        }
    }
}

// ---------------------------------------------------------------------------
// Flash attention R13: dual query-stream (32 q/wave, 128 q/block). K/V LDS
// fragments loaded ONCE per wave, reused by both groups' MFMAs -> LDS-pipe
// work per query halved; two independent softmax chains give ILP. Staging,
// counted vmcnt, raw s_barrier, XOR swizzle all unchanged from R10.
__device__ __forceinline__ void stage_tile(
    int w, int l, f16* ldsKb, f16* ldsVb,
    const f16* __restrict__ kbb, const f16* __restrict__ vbb, int m0)
{
    int rr = l >> 3, p = l & 7;
    #pragma unroll
    for (int j = 0; j < 4; ++j) {
        int u = w + j*4;
        if (u < 8) {                      // K rows 8u..8u+7
            int r = u*8 + rr;
            int c = p ^ (r & 7);
            gload16(kbb + (size_t)(m0 + r)*C_ + c*8, ldsKb + u*512);
        } else if (u < 14) {              // V rows (d) 8(u-8)..+7
            int d = (u-8)*8 + rr;
            int c = p ^ (d & 7);
            gload16(vbb + (size_t)d*VT_LD + m0 + c*8, ldsVb + (u-8)*512);
        }
    }
}

// online-softmax update for one group's 4 s-blocks; fills pk[8]
__device__ __forceinline__ float softmax_upd(
    f32x4* s, float& mrun, float& lrun, u32* pk)
{
    float t0 = fmaxf(fmaxf(s[0][0], s[0][1]), fmaxf(s[0][2], s[0][3]));
    float t1 = fmaxf(fmaxf(s[1][0], s[1][1]), fmaxf(s[1][2], s[1][3]));
    float t2 = fmaxf(fmaxf(s[2][0], s[2][1]), fmaxf(s[2][2], s[2][3]));
    float t3 = fmaxf(fmaxf(s[3][0], s[3][1]), fmaxf(s[3][2], s[3][3]));
    float tmax = fmaxf(fmaxf(t0, t1), fmaxf(t2, t3));
    tmax = fmaxf(tmax, __shfl_xor(tmax, 16));
    tmax = fmaxf(tmax, __shfl_xor(tmax, 32));
    float mnew = fmaxf(mrun, tmax);
    float corr = exp2f(mrun - mnew);
    mrun = mnew;
    float psum = 0.f;
    #pragma unroll
    for (int j = 0; j < 4; ++j) {
        #pragma unroll
        for (int r = 0; r < 4; ++r) {
            s[j][r] = exp2f(s[j][r] - mnew);
            psum += s[j][r];
        }
    }
    psum += __shfl_xor(psum, 16);
    psum += __shfl_xor(psum, 32);
    lrun = lrun*corr + psum;
    #pragma unroll
    for (int j = 0; j < 4; ++j) {
        pk[j*2]   = pkrtz(s[j][0], s[j][1]);
        pk[j*2+1] = pkrtz(s[j][2], s[j][3]);
    }
    return corr;
}

__device__ __forceinline__ void compute_tile_dual(
    const f16* ldsKb, const f16* ldsVb,
    const f16x8& qA0, const f16x8& qA1, const f16x8& qB0, const f16x8& qB1,
    float& mA, float& lA, f32x4& oA0, f32x4& oA1, f32x4& oA2,
    float& mB, float& lB, f32x4& oB0, f32x4& oB1, f32x4& oB2,
    int lrow, int g, int la, int lb, bool hi, bool tail)
{
    const char* kP = (const char*)ldsKb;
    const char* vP = (const char*)ldsVb;
    f32x4 z = {0.f,0.f,0.f,0.f};
    int sw = lrow & 7;
    int cA = (g ^ sw) << 4, cB = ((4+g) ^ sw) << 4;

    // K fragments once, reused by both query groups
    f16x8 klo[4], khi[4];
    #pragma unroll
    for (int j = 0; j < 4; ++j) {
        const char* rb = kP + (16*j + lrow)*128;
        klo[j] = *(const f16x8*)(rb + cA);
        khi[j] = *(const f16x8*)(rb + cB);
    }
    f32x4 sA[4], sB[4];
    __builtin_amdgcn_s_setprio(1);
    #pragma unroll
    for (int j = 0; j < 4; ++j) {
        f32x4 ta = MFMA16(klo[j], qA0, z);  sA[j] = MFMA16(khi[j], qA1, ta);
        f32x4 tb = MFMA16(klo[j], qB0, z);  sB[j] = MFMA16(khi[j], qB1, tb);
    }
    __builtin_amdgcn_s_setprio(0);

    if (tail) {   // keys >= 784 live in blocks 1..3 of tile 12
        f32x4 neg = {-1e30f,-1e30f,-1e30f,-1e30f};
        sA[1] = neg; sA[2] = neg; sA[3] = neg;
        sB[1] = neg; sB[2] = neg; sB[3] = neg;
    }

    u32 pkA[8], pkB[8];
    float corrA = softmax_upd(sA, mA, lA, pkA);
    float corrB = softmax_upd(sB, mB, lB, pkB);

    #pragma unroll
    for (int r = 0; r < 4; ++r) {
        oA0[r] *= corrA; oA1[r] *= corrA; oA2[r] *= corrA;
        oB0[r] *= corrB; oB1[r] *= corrB; oB2[r] *= corrB;
    }

    #pragma unroll
    for (int kc = 0; kc < 2; ++kc) {
        int off = (((kc*4 + g) ^ sw) << 4);
        f16x8 v0 = *(const f16x8*)(vP + lrow*128      + off);
        f16x8 v1 = *(const f16x8*)(vP + (16+lrow)*128 + off);
        f16x8 v2 = *(const f16x8*)(vP + (32+lrow)*128 + off);
        // group A gather + PV
        {
            u32 x0 = __shfl(pkA[4*kc+0], la), x0h = __shfl(pkA[4*kc+2], la);
            u32 x1 = __shfl(pkA[4*kc+1], la), x1h = __shfl(pkA[4*kc+3], la);
            u32 y0 = __shfl(pkA[4*kc+0], lb), y0h = __shfl(pkA[4*kc+2], lb);
            u32 y1 = __shfl(pkA[4*kc+1], lb), y1h = __shfl(pkA[4*kc+3], lb);
            u32x4 uw = { hi ? x0h : x0, hi ? x1h : x1,
                         hi ? y0h : y0, hi ? y1h : y1 };
            f16x8 pb = __builtin_bit_cast(f16x8, uw);
            __builtin_amdgcn_s_setprio(1);
            oA0 = MFMA16(v0, pb, oA0);
            oA1 = MFMA16(v1, pb, oA1);
            oA2 = MFMA16(v2, pb, oA2);
            __builtin_amdgcn_s_setprio(0);
        }
        // group B gather + PV (same v frags)
        {
            u32 x0 = __shfl(pkB[4*kc+0], la), x0h = __shfl(pkB[4*kc+2], la);
            u32 x1 = __shfl(pkB[4*kc+1], la), x1h = __shfl(pkB[4*kc+3], la);
            u32 y0 = __shfl(pkB[4*kc+0], lb), y0h = __shfl(pkB[4*kc+2], lb);
            u32 y1 = __shfl(pkB[4*kc+1], lb), y1h = __shfl(pkB[4*kc+3], lb);
            u32x4 uw = { hi ? x0h : x0, hi ? x1h : x1,
                         hi ? y0h : y0, hi ? y1h : y1 };
            f16x8 pb = __builtin_bit_cast(f16x8, uw);
            __builtin_amdgcn_s_setprio(1);
            oB0 = MFMA16(v0, pb, oB0);
            oB1 = MFMA16(v1, pb, oB1);
            oB2 = MFMA16(v2, pb, oB2);
            __builtin_amdgcn_s_setprio(0);
        }
    }
}

__global__ __launch_bounds__(256, 2) void attn_mfma(
    const f16* __restrict__ qb, const f16* __restrict__ kb,
    const f16* __restrict__ vt, float* __restrict__ out)
{
    __shared__ __align__(16) f16 ldsK[2][64*64];   // 16 KB
    __shared__ __align__(16) f16 ldsV[2][48*64];   // 12 KB

    int tid  = threadIdx.x;
    int w    = tid >> 6, l = tid & 63;
    int lrow = l & 15,  g = l >> 4;
    // XCD swizzle: 800 = 8*100; blocks sharing (b,h) land on one XCD.
    int swz  = (blockIdx.x & 7)*100 + (blockIdx.x >> 3);
    int bh   = swz / 25, qblk = swz % 25;
    int h    = bh & 3, b = bh >> 2;
    int n0a  = qblk*128 + w*16;          // group A queries
    int n0b  = n0a + 64;                 // group B queries
    bool hasB = qblk < 24;               // qblk 24: only 64 real queries

    const f16* kbb = kb + (size_t)b*MM*C_ + h*HD;
    const f16* vbb = vt + ((size_t)b*C_ + h*HD)*VT_LD;

    const f16* qrowA = qb + ((size_t)b*NN + n0a + lrow)*C_ + h*HD;
    f16x8 qA0 = *(const f16x8*)(qrowA + g*8);
    f16x8 qA1 = (f16x8){0,0,0,0,0,0,0,0};
    if (g < 2) qA1 = *(const f16x8*)(qrowA + 32 + g*8);
    f16x8 qB0 = (f16x8){0,0,0,0,0,0,0,0};
    f16x8 qB1 = (f16x8){0,0,0,0,0,0,0,0};
    if (hasB) {
        const f16* qrowB = qb + ((size_t)b*NN + n0b + lrow)*C_ + h*HD;
        qB0 = *(const f16x8*)(qrowB + g*8);
        if (g < 2) qB1 = *(const f16x8*)(qrowB + 32 + g*8);
    }
    asm volatile("" :: "v"(qA0), "v"(qA1), "v"(qB0), "v"(qB1));

    float mA = -1e30f, lA = 0.f, mB = -1e30f, lB = 0.f;
    f32x4 oA0 = {0.f,0.f,0.f,0.f}, oA1 = oA0, oA2 = oA0;
    f32x4 oB0 = oA0, oB1 = oA0, oB2 = oA0;

    int  la = lrow + ((g & 1) << 5);
    int  lb = la + 16;
    bool hi = g >= 2;

    // prologue: stage tile 0 into buffer 0
    stage_tile(w, l, &ldsK[0][0], &ldsV[0][0], kbb, vbb, 0);

    for (int t = 0; t < 13; ++t) {
        int nb = t & 1;
        if (t < 12)
            stage_tile(w, l, &ldsK[nb^1][0], &ldsV[nb^1][0], kbb, vbb, (t+1)*64);
        __builtin_amdgcn_sched_barrier(0);
        if (t < 12) {
            if (w < 2) asm volatile("s_waitcnt vmcnt(4)" ::: "memory");
            else       asm volatile("s_waitcnt vmcnt(3)" ::: "memory");
        } else {
            asm volatile("s_waitcnt vmcnt(0)" ::: "memory");
        }
        __builtin_amdgcn_s_barrier();
        __builtin_amdgcn_sched_barrier(0);
        compute_tile_dual(&ldsK[nb][0], &ldsV[nb][0], qA0, qA1, qB0, qB1,
                          mA, lA, oA0, oA1, oA2, mB, lB, oB0, oB1, oB2,
                          lrow, g, la, lb, hi, t == 12);
        __builtin_amdgcn_sched_barrier(0);
        __builtin_amdgcn_s_barrier();
    }

    {
        float inv = 1.f / lA;
        f32x4 r0, r1, r2;
        #pragma unroll
        for (int r = 0; r < 4; ++r) {
            r0[r] = oA0[r]*inv; r1[r] = oA1[r]*inv; r2[r] = oA2[r]*inv;
        }
        float* ob = out + ((size_t)b*NN + n0a + lrow)*C_ + h*HD + g*4;
        *(f32x4*)(ob)      = r0;
        *(f32x4*)(ob + 16) = r1;
        *(f32x4*)(ob + 32) = r2;
    }
    if (hasB) {
        float inv = 1.f / lB;
        f32x4 r0, r1, r2;
        #pragma unroll
        for (int r = 0; r < 4; ++r) {
            r0[r] = oB0[r]*inv; r1[r] = oB1[r]*inv; r2[r] = oB2[r]*inv;
        }
        float* ob = out + ((size_t)b*NN + n0b + lrow)*C_ + h*HD + g*4;
        *(f32x4*)(ob)      = r0;
        *(f32x4*)(ob + 16) = r1;
        *(f32x4*)(ob + 32) = r2;
    }
}

// ---------------------------------------------------------------------------
extern "C" void kernel_launch(void* const* d_in, const int* in_sizes, int n_in,
                              void* d_out, int out_size, void* d_ws, size_t ws_size,
                              hipStream_t stream)
{
    const float* x     = (const float*)d_in[0];
    const float* dw_q  = (const float*)d_in[3];
    const float* bnqg  = (const float*)d_in[4];
    const float* bnqb  = (const float*)d_in[5];
    const float* bnqm  = (const float*)d_in[6];
    const float* bnqv  = (const float*)d_in[7];
    const float* pw_q  = (const float*)d_in[8];
    const float* dw_kv = (const float*)d_in[9];
    const float* bnkg  = (const float*)d_in[10];
    const float* bnkb  = (const float*)d_in[11];
    const float* bnkm  = (const float*)d_in[12];
    const float* bnkvv = (const float*)d_in[13];
    const float* pw_kv = (const float*)d_in[14];
    const float* Wq    = (const float*)d_in[15];
    const float* bq    = (const float*)d_in[16];
    const float* Wk    = (const float*)d_in[17];
    const float* bk    = (const float*)d_in[18];
    const float* Wv    = (const float*)d_in[19];
    const float* bv    = (const float*)d_in[20];
    float* out = (float*)d_out;

    f16* p   = (f16*)d_ws;
    f16* Mq16  = p;  p += C_*C_;
    f16* Mk16  = p;  p += C_*C_;
    f16* Mv16  = p;  p += C_*C_;
    f16* uq16  = p;  p += (size_t)BB*NN*C_;
    f16* ukv16 = p;  p += (size_t)BB*MM*C_;
    f16* qb16  = p;  p += (size_t)BB*NN*C_ + 256;    // pad: frag tail reads
    f16* kb16  = p;  p += (size_t)BB*MM*C_ + 16384;  // pad: tail-tile staging overread
    f16* vt16  = p;  p += (size_t)BB*C_*VT_LD;

    prep_all<<<3804, 256, 0, stream>>>(
        x, dw_q, bnqg, bnqb, bnqm, bnqv,
        dw_kv, bnkg, bnkb, bnkm, bnkvv,
        Wq, Wk, Wv, pw_q, pw_kv,
        uq16, ukv16, Mq16, Mk16, Mv16, vt16);

    proj_all<<<QPB + 2*KVPB, 256, 0, stream>>>(
        uq16, ukv16, Mq16, Mk16, Mv16, bq, bk, bv, qb16, kb16, vt16);

    attn_mfma<<<800, 256, 0, stream>>>(qb16, kb16, vt16, out);
}

// Round 15
// 109.539 us; speedup vs baseline: 1.1080x; 1.1080x over previous
//
#include <hip/hip_runtime.h>
#include <cmath>

typedef _Float16 f16;
typedef _Float16 f16x8 __attribute__((ext_vector_type(8)));
typedef _Float16 f16x4 __attribute__((ext_vector_type(4)));
typedef float    f32x4 __attribute__((ext_vector_type(4)));
typedef unsigned int u32;
typedef u32 u32x2 __attribute__((ext_vector_type(2)));
typedef u32 u32x4 __attribute__((ext_vector_type(4)));

#define C_   192
#define HH   56
#define WW   56
#define NN   3136
#define BB   8
#define MM   784
#define NHEAD 4
#define HD   48
#define VT_LD 832            // padded key-dim of transposed V (784 + 48)
#define QPB  (BB*NN/64)      // 392 proj blocks, Q path
#define KVPB (BB*MM/64)      // 98 proj blocks per K / V path

#define MFMA16(a,b,c)  __builtin_amdgcn_mfma_f32_16x16x32_f16(a,b,c,0,0,0)
#define MFMAK16(a,b,c) __builtin_amdgcn_mfma_f32_16x16x16f16(a,b,c,0,0,0)

static __device__ __forceinline__ u32 pkrtz(float a, float b) {
    typedef __fp16 fp16x2 __attribute__((ext_vector_type(2)));
    fp16x2 h = __builtin_amdgcn_cvt_pkrtz(a, b);
    return __builtin_bit_cast(u32, h);
}

// async global->LDS, 16B per lane; LDS dst = wave-uniform base + lane*16
static __device__ __forceinline__ void gload16(const void* g, void* l) {
    __builtin_amdgcn_global_load_lds(
        (const __attribute__((address_space(1))) unsigned int*)g,
        (__attribute__((address_space(3))) unsigned int*)l, 16, 0, 0);
}

// ---------------------------------------------------------------------------
// Depthwise 3x3 + BN, TWO vertically-adjacent outputs per thread (shares
// loaded rows). Weights from LDS (coalesced staging).
template<int STRIDE, int OH, int OW>
__device__ __forceinline__ void dwbn_pair(
    const float* __restrict__ x, const float* __restrict__ dwL,
    const float* __restrict__ gamma, const float* __restrict__ beta,
    const float* __restrict__ mean,  const float* __restrict__ var,
    f16* __restrict__ out, int idx)
{
    int c4 = idx % 48;
    int r1 = idx / 48;
    int ox = r1 % OW;
    int r2 = r1 / OW;
    int p  = r2 % (OH/2);
    int b  = r2 / (OH/2);
    int c0 = c4*4;

    float4 w4[9];
    #pragma unroll
    for (int j = 0; j < 9; ++j)
        w4[j] = *(const float4*)&dwL[c4*40 + j*4];
    const float* wf = (const float*)w4;   // wf[cc*9 + wi], static indices

    float4 g4  = *(const float4*)(gamma + c0);
    float4 be4 = *(const float4*)(beta + c0);
    float4 m4  = *(const float4*)(mean + c0);
    float4 v4  = *(const float4*)(var  + c0);

    const int NR = STRIDE + 3;           // union of both 3-row windows
    float4 a0 = make_float4(0.f,0.f,0.f,0.f), a1 = a0;
    int iyTop = (2*p)*STRIDE - 1;
    int ix0 = ox*STRIDE - 1;
    #pragma unroll
    for (int j = 0; j < NR; ++j) {
        int iy = iyTop + j;
        if (iy < 0 || iy >= HH) continue;
        #pragma unroll
        for (int kx = 0; kx < 3; ++kx) {
            int ix = ix0 + kx;
            if (ix < 0 || ix >= WW) continue;
            float4 xv = *reinterpret_cast<const float4*>(
                x + ((size_t)b*NN + iy*WW + ix)*C_ + c0);
            if (j <= 2) {                       // contributes to out row 2p
                const int wi = j*3 + kx;
                a0.x = fmaf(wf[ 0+wi], xv.x, a0.x);
                a0.y = fmaf(wf[ 9+wi], xv.y, a0.y);
                a0.z = fmaf(wf[18+wi], xv.z, a0.z);
                a0.w = fmaf(wf[27+wi], xv.w, a0.w);
            }
            if (j >= STRIDE) {                  // contributes to out row 2p+1
                const int wi = (j-STRIDE)*3 + kx;
                a1.x = fmaf(wf[ 0+wi], xv.x, a1.x);
                a1.y = fmaf(wf[ 9+wi], xv.y, a1.y);
                a1.z = fmaf(wf[18+wi], xv.z, a1.z);
                a1.w = fmaf(wf[27+wi], xv.w, a1.w);
            }
        }
    }
    float i0 = g4.x*__frsqrt_rn(v4.x + 1e-5f);
    float i1 = g4.y*__frsqrt_rn(v4.y + 1e-5f);
    float i2 = g4.z*__frsqrt_rn(v4.z + 1e-5f);
    float i3 = g4.w*__frsqrt_rn(v4.w + 1e-5f);
    float b0 = be4.x - m4.x*i0, b1 = be4.y - m4.y*i1;
    float b2 = be4.z - m4.z*i2, b3 = be4.w - m4.w*i3;
    f16x4 r0, r1v;
    r0[0] = (f16)(a0.x*i0 + b0); r0[1] = (f16)(a0.y*i1 + b1);
    r0[2] = (f16)(a0.z*i2 + b2); r0[3] = (f16)(a0.w*i3 + b3);
    r1v[0] = (f16)(a1.x*i0 + b0); r1v[1] = (f16)(a1.y*i1 + b1);
    r1v[2] = (f16)(a1.z*i2 + b2); r1v[3] = (f16)(a1.w*i3 + b3);
    size_t o0 = (((size_t)b*OH + 2*p)*OW + ox)*48 + c4;
    *reinterpret_cast<f16x4*>(out + o0*4)            = r0;
    *reinterpret_cast<f16x4*>(out + (o0 + (size_t)OW*48)*4) = r1v;
}

// ---------------------------------------------------------------------------
// Fused prep: dwbn-pairs (both paths) + pointwise-fold + Vt pad zero.
__global__ __launch_bounds__(256) void prep_all(
    const float* __restrict__ x,
    const float* __restrict__ dwq,  const float* __restrict__ gq,
    const float* __restrict__ bq_,  const float* __restrict__ mq,
    const float* __restrict__ vq,
    const float* __restrict__ dwkv, const float* __restrict__ gkv,
    const float* __restrict__ bkv,  const float* __restrict__ mkv,
    const float* __restrict__ vkv,
    const float* __restrict__ Wq, const float* __restrict__ Wk,
    const float* __restrict__ Wv, const float* __restrict__ pw_q,
    const float* __restrict__ pw_kv,
    f16* __restrict__ uq, f16* __restrict__ ukv,
    f16* __restrict__ Mq, f16* __restrict__ Mk, f16* __restrict__ Mv,
    f16* __restrict__ vt)
{
    int blk = blockIdx.x, tid = threadIdx.x;
    const int QB = 2352, KB = 588;
    if (blk < QB + KB) {
        bool qp = blk < QB;
        __shared__ __align__(16) float dwL[48*40];
        const float* dwg = qp ? dwq : dwkv;
        for (int i = tid; i < 432; i += 256) {
            int f  = i*4;
            int c4 = f/36, r = f%36;
            *(float4*)&dwL[c4*40 + r] = *(const float4*)(dwg + f);
        }
        __syncthreads();
        if (qp)
            dwbn_pair<1, HH, WW>(x, dwL, gq, bq_, mq, vq, uq, blk*256 + tid);
        else
            dwbn_pair<2, 28, 28>(x, dwL, gkv, bkv, mkv, vkv, ukv,
                                 (blk - QB)*256 + tid);
    } else if (blk < QB + KB + 576) {
        int fb = blk - QB - KB;
        int which = fb / 192, o = fb % 192;
        const float* Wm = which == 0 ? Wq : (which == 1 ? Wk : Wv);
        const float* P  = which == 0 ? pw_q : (which == 1 ? pw_kv : pw_kv + C_*C_);
        f16* Mo         = which == 0 ? Mq : (which == 1 ? Mk : Mv);
        __shared__ float wrow[C_];
        if (tid < C_) wrow[tid] = Wm[o*C_ + tid];
        __syncthreads();
        if (tid < C_) {
            float acc = 0.f;
            #pragma unroll 8
            for (int j = 0; j < C_; ++j)
                acc = fmaf(wrow[j], P[j*C_ + tid], acc);
            Mo[o*C_ + tid] = (f16)acc;
        }
    } else {
        int i = (blk - QB - KB - 576)*256 + tid;   // BB*C_*48 = 73728 exactly
        int b = i / (C_*48);
        int rem = i % (C_*48);
        int c = rem / 48;
        int m = MM + (rem % 48);
        vt[((size_t)b*C_ + c)*VT_LD + m] = (f16)0.f;
    }
}

// ---------------------------------------------------------------------------
// Projections, 3-way split: blocks [0,392) Q, [392,490) K, [490,588) V.
__global__ __launch_bounds__(256, 1) void proj_all(
    const f16* __restrict__ uq, const f16* __restrict__ ukv,
    const f16* __restrict__ Mq, const f16* __restrict__ Mk,
    const f16* __restrict__ Mv,
    const float* __restrict__ bq, const float* __restrict__ bk,
    const float* __restrict__ bv,
    f16* __restrict__ qb, f16* __restrict__ kb, f16* __restrict__ vt)
{
    int tid  = threadIdx.x;
    int w    = tid >> 6, l = tid & 63;
    int lrow = l & 15,  lgrp = l >> 4;
    int blk  = blockIdx.x;
    int path = blk < QPB ? 0 : (blk < QPB + KVPB ? 1 : 2);
    const f16* U = path == 0 ? uq : ukv;
    int rblk = path == 0 ? blk : (path == 1 ? blk - QPB : blk - QPB - KVPB);
    int r0 = rblk*64 + w*16;

    const f16* urow = U + (size_t)(r0 + lrow)*C_;
    f16x8 a[6];
    #pragma unroll
    for (int ch = 0; ch < 6; ++ch)
        a[ch] = *(const f16x8*)(urow + ch*32 + lgrp*8);

    f16x8 bfA[6], bfB[6];
    const f16* Mm = path == 0 ? Mq : (path == 1 ? Mk : Mv);

    #pragma unroll
    for (int ch = 0; ch < 6; ++ch)
        bfA[ch] = *(const f16x8*)(Mm + (size_t)lrow*C_ + ch*32 + lgrp*8);

    if (path < 2) {
        // Q folds 1/sqrt(48)*log2(e) for exp2-domain softmax
        const float sc = path == 0 ? 0.14433756729740643f*1.4426950408889634f
                                   : 1.0f;
        const float* bias = path == 0 ? bq : bk;
        f16* dst = path == 0 ? qb : kb;
        #pragma unroll
        for (int ct = 0; ct < 12; ++ct) {
            f16x8* cur = (ct & 1) ? bfB : bfA;
            f16x8* nxt = (ct & 1) ? bfA : bfB;
            if (ct < 11) {
                const f16* mrow = Mm + (size_t)((ct+1)*16 + lrow)*C_;
                #pragma unroll
                for (int ch = 0; ch < 6; ++ch)
                    nxt[ch] = *(const f16x8*)(mrow + ch*32 + lgrp*8);
            }
            f32x4 acc = {0.f,0.f,0.f,0.f};
            #pragma unroll
            for (int ch = 0; ch < 6; ++ch)
                acc = MFMA16(cur[ch], a[ch], acc);          // swapped
            float4 bo = *(const float4*)(bias + ct*16 + lgrp*4);
            f16x4 st;
            st[0] = (f16)((acc[0] + bo.x)*sc);
            st[1] = (f16)((acc[1] + bo.y)*sc);
            st[2] = (f16)((acc[2] + bo.z)*sc);
            st[3] = (f16)((acc[3] + bo.w)*sc);
            *(f16x4*)(dst + (size_t)(r0 + lrow)*C_ + ct*16 + lgrp*4) = st;
        }
    } else {
        #pragma unroll
        for (int ct = 0; ct < 12; ++ct) {            // V projection (transposed)
            f16x8* cur = (ct & 1) ? bfB : bfA;
            f16x8* nxt = (ct & 1) ? bfA : bfB;
            if (ct < 11) {
                const f16* mrow = Mv + (size_t)((ct+1)*16 + lrow)*C_;
                #pragma unroll
                for (int ch = 0; ch < 6; ++ch)
                    nxt[ch] = *(const f16x8*)(mrow + ch*32 + lgrp*8);
            }
            int o = ct*16 + lrow;
            f32x4 acc = {0.f,0.f,0.f,0.f};
            #pragma unroll
            for (int ch = 0; ch < 6; ++ch)
                acc = MFMA16(a[ch], cur[ch], acc);
            float bo = bv[o];
            int rg = r0 + lgrp*4;
            int b  = rg / MM, m = rg % MM;            // 784 % 16 == 0
            f16x4 st;
            st[0] = (f16)(acc[0] + bo);
            st[1] = (f16)(acc[1] + bo);
            st[2] = (f16)(acc[2] + bo);
            st[3] = (f16)(acc[3] + bo);
            *(f16x4*)(vt + ((size_t)b*C_ + o)*VT_LD + m) = st;
        }
    }
}

// ---------------------------------------------------------------------------
// Flash attention R14: single query-stream (R12 structure, 1568 blocks) but
// PV via v_mfma_f32_16x16x16_f16 — its B-fragment (k = (lane>>4)*4+e) is
// EXACTLY where the QK D-layout leaves P (keys g*4+r, query lrow), so P is
// lane-local: the 16 ds_bpermute gathers + hi/lo selects of R12 vanish.
// V A-frags are 8-byte LDS reads. Staging/vmcnt/s_barrier/XOR-swizzle as R10.
__device__ __forceinline__ void stage_tile(
    int w, int l, f16* ldsKb, f16* ldsVb,
    const f16* __restrict__ kbb, const f16* __restrict__ vbb, int m0)
{
    int rr = l >> 3, p = l & 7;
    #pragma unroll
    for (int j = 0; j < 4; ++j) {
        int u = w + j*4;
        if (u < 8) {                      // K rows 8u..8u+7
            int r = u*8 + rr;
            int c = p ^ (r & 7);
            gload16(kbb + (size_t)(m0 + r)*C_ + c*8, ldsKb + u*512);
        } else if (u < 14) {              // V rows (d) 8(u-8)..+7
            int d = (u-8)*8 + rr;
            int c = p ^ (d & 7);
            gload16(vbb + (size_t)d*VT_LD + m0 + c*8, ldsVb + (u-8)*512);
        }
    }
}

// online-softmax update for 4 s-blocks; fills pk[8] (f16-pair packs)
__device__ __forceinline__ float softmax_upd(
    f32x4* s, float& mrun, float& lrun, u32* pk)
{
    float t0 = fmaxf(fmaxf(s[0][0], s[0][1]), fmaxf(s[0][2], s[0][3]));
    float t1 = fmaxf(fmaxf(s[1][0], s[1][1]), fmaxf(s[1][2], s[1][3]));
    float t2 = fmaxf(fmaxf(s[2][0], s[2][1]), fmaxf(s[2][2], s[2][3]));
    float t3 = fmaxf(fmaxf(s[3][0], s[3][1]), fmaxf(s[3][2], s[3][3]));
    float tmax = fmaxf(fmaxf(t0, t1), fmaxf(t2, t3));
    tmax = fmaxf(tmax, __shfl_xor(tmax, 16));
    tmax = fmaxf(tmax, __shfl_xor(tmax, 32));
    float mnew = fmaxf(mrun, tmax);
    float corr = exp2f(mrun - mnew);
    mrun = mnew;
    float psum = 0.f;
    #pragma unroll
    for (int j = 0; j < 4; ++j) {
        #pragma unroll
        for (int r = 0; r < 4; ++r) {
            s[j][r] = exp2f(s[j][r] - mnew);
            psum += s[j][r];
        }
    }
    psum += __shfl_xor(psum, 16);
    psum += __shfl_xor(psum, 32);
    lrun = lrun*corr + psum;
    #pragma unroll
    for (int j = 0; j < 4; ++j) {
        pk[j*2]   = pkrtz(s[j][0], s[j][1]);
        pk[j*2+1] = pkrtz(s[j][2], s[j][3]);
    }
    return corr;
}

__device__ __forceinline__ void compute_tile64(
    const f16* ldsKb, const f16* ldsVb,
    const f16x8& qf0, const f16x8& qf1,
    float& mrun, float& lrun, f32x4& o0, f32x4& o1, f32x4& o2,
    int lrow, int g, bool tail)
{
    const char* kP = (const char*)ldsKb;
    const char* vP = (const char*)ldsVb;
    f32x4 z = {0.f,0.f,0.f,0.f};
    int sw = lrow & 7;
    int cA = (g ^ sw) << 4, cB = ((4+g) ^ sw) << 4;

    f32x4 s[4];
    __builtin_amdgcn_s_setprio(1);
    #pragma unroll
    for (int j = 0; j < 4; ++j) {
        const char* rb = kP + (16*j + lrow)*128;
        f32x4 t = MFMA16(*(const f16x8*)(rb + cA), qf0, z);
        s[j] = MFMA16(*(const f16x8*)(rb + cB), qf1, t);
    }
    __builtin_amdgcn_s_setprio(0);

    if (tail) {   // keys >= 784 live in blocks 1..3 of tile 12
        f32x4 neg = {-1e30f,-1e30f,-1e30f,-1e30f};
        s[1] = neg; s[2] = neg; s[3] = neg;
    }

    u32 pk[8];
    float corr = softmax_upd(s, mrun, lrun, pk);

    #pragma unroll
    for (int r = 0; r < 4; ++r) { o0[r] *= corr; o1[r] *= corr; o2[r] *= corr; }

    // PV: per 16-key chunk, B-frag is lane-local {pk[2ch],pk[2ch+1]};
    // A-frag = Vt[d=16*db+lrow][m0+16ch+g*4 .. +3] (8B swizzled LDS read).
    #pragma unroll
    for (int ch = 0; ch < 4; ++ch) {
        u32x2 pw = { pk[2*ch], pk[2*ch+1] };
        f16x4 pb = __builtin_bit_cast(f16x4, pw);
        int off = (((2*ch + (g >> 1)) ^ sw) << 4) + ((g & 1) << 3);
        f16x4 v0 = *(const f16x4*)(vP + lrow*128      + off);
        f16x4 v1 = *(const f16x4*)(vP + (16+lrow)*128 + off);
        f16x4 v2 = *(const f16x4*)(vP + (32+lrow)*128 + off);
        __builtin_amdgcn_s_setprio(1);
        o0 = MFMAK16(v0, pb, o0);
        o1 = MFMAK16(v1, pb, o1);
        o2 = MFMAK16(v2, pb, o2);
        __builtin_amdgcn_s_setprio(0);
    }
}

__global__ __launch_bounds__(256, 2) void attn_mfma(
    const f16* __restrict__ qb, const f16* __restrict__ kb,
    const f16* __restrict__ vt, float* __restrict__ out)
{
    __shared__ __align__(16) f16 ldsK[2][64*64];   // 16 KB
    __shared__ __align__(16) f16 ldsV[2][48*64];   // 12 KB

    int tid  = threadIdx.x;
    int w    = tid >> 6, l = tid & 63;
    int lrow = l & 15,  g = l >> 4;
    // XCD swizzle: 1568 = 8*196; 4 (b,h) groups per XCD -> KV L2-resident.
    int swz  = (blockIdx.x & 7)*196 + (blockIdx.x >> 3);
    int bh   = swz / 49, qblk = swz % 49;
    int h    = bh & 3, b = bh >> 2;
    int n0   = qblk*64 + w*16;

    const f16* kbb = kb + (size_t)b*MM*C_ + h*HD;
    const f16* vbb = vt + ((size_t)b*C_ + h*HD)*VT_LD;

    const f16* qrow = qb + ((size_t)b*NN + n0 + lrow)*C_ + h*HD;
    f16x8 qf0 = *(const f16x8*)(qrow + g*8);
    f16x8 qf1 = (f16x8){0,0,0,0,0,0,0,0};
    if (g < 2) qf1 = *(const f16x8*)(qrow + 32 + g*8);
    asm volatile("" :: "v"(qf0), "v"(qf1));

    float mrun = -1e30f, lrun = 0.f;
    f32x4 o0 = {0.f,0.f,0.f,0.f}, o1 = o0, o2 = o0;

    // prologue: stage tile 0 into buffer 0
    stage_tile(w, l, &ldsK[0][0], &ldsV[0][0], kbb, vbb, 0);

    for (int t = 0; t < 13; ++t) {
        int nb = t & 1;
        if (t < 12)
            stage_tile(w, l, &ldsK[nb^1][0], &ldsV[nb^1][0], kbb, vbb, (t+1)*64);
        __builtin_amdgcn_sched_barrier(0);
        if (t < 12) {
            if (w < 2) asm volatile("s_waitcnt vmcnt(4)" ::: "memory");
            else       asm volatile("s_waitcnt vmcnt(3)" ::: "memory");
        } else {
            asm volatile("s_waitcnt vmcnt(0)" ::: "memory");
        }
        __builtin_amdgcn_s_barrier();
        __builtin_amdgcn_sched_barrier(0);
        compute_tile64(&ldsK[nb][0], &ldsV[nb][0], qf0, qf1,
                       mrun, lrun, o0, o1, o2, lrow, g, t == 12);
        __builtin_amdgcn_sched_barrier(0);
        __builtin_amdgcn_s_barrier();
    }

    float inv = 1.f / lrun;
    f32x4 r0, r1, r2;
    #pragma unroll
    for (int r = 0; r < 4; ++r) {
        r0[r] = o0[r]*inv; r1[r] = o1[r]*inv; r2[r] = o2[r]*inv;
    }
    float* obase = out + ((size_t)b*NN + n0 + lrow)*C_ + h*HD + g*4;
    *(f32x4*)(obase)      = r0;
    *(f32x4*)(obase + 16) = r1;
    *(f32x4*)(obase + 32) = r2;
}

// ---------------------------------------------------------------------------
extern "C" void kernel_launch(void* const* d_in, const int* in_sizes, int n_in,
                              void* d_out, int out_size, void* d_ws, size_t ws_size,
                              hipStream_t stream)
{
    const float* x     = (const float*)d_in[0];
    const float* dw_q  = (const float*)d_in[3];
    const float* bnqg  = (const float*)d_in[4];
    const float* bnqb  = (const float*)d_in[5];
    const float* bnqm  = (const float*)d_in[6];
    const float* bnqv  = (const float*)d_in[7];
    const float* pw_q  = (const float*)d_in[8];
    const float* dw_kv = (const float*)d_in[9];
    const float* bnkg  = (const float*)d_in[10];
    const float* bnkb  = (const float*)d_in[11];
    const float* bnkm  = (const float*)d_in[12];
    const float* bnkvv = (const float*)d_in[13];
    const float* pw_kv = (const float*)d_in[14];
    const float* Wq    = (const float*)d_in[15];
    const float* bq    = (const float*)d_in[16];
    const float* Wk    = (const float*)d_in[17];
    const float* bk    = (const float*)d_in[18];
    const float* Wv    = (const float*)d_in[19];
    const float* bv    = (const float*)d_in[20];
    float* out = (float*)d_out;

    f16* p   = (f16*)d_ws;
    f16* Mq16  = p;  p += C_*C_;
    f16* Mk16  = p;  p += C_*C_;
    f16* Mv16  = p;  p += C_*C_;
    f16* uq16  = p;  p += (size_t)BB*NN*C_;
    f16* ukv16 = p;  p += (size_t)BB*MM*C_;
    f16* qb16  = p;  p += (size_t)BB*NN*C_ + 256;    // pad: frag tail reads
    f16* kb16  = p;  p += (size_t)BB*MM*C_ + 16384;  // pad: tail-tile staging overread
    f16* vt16  = p;  p += (size_t)BB*C_*VT_LD;

    prep_all<<<3804, 256, 0, stream>>>(
        x, dw_q, bnqg, bnqb, bnqm, bnqv,
        dw_kv, bnkg, bnkb, bnkm, bnkvv,
        Wq, Wk, Wv, pw_q, pw_kv,
        uq16, ukv16, Mq16, Mk16, Mv16, vt16);

    proj_all<<<QPB + 2*KVPB, 256, 0, stream>>>(
        uq16, ukv16, Mq16, Mk16, Mv16, bq, bk, bv, qb16, kb16, vt16);

    attn_mfma<<<1568, 256, 0, stream>>>(qb16, kb16, vt16, out);
}

// Round 16
// 108.126 us; speedup vs baseline: 1.1225x; 1.0131x over previous
//
#include <hip/hip_runtime.h>
#include <cmath>

typedef _Float16 f16;
typedef _Float16 f16x8 __attribute__((ext_vector_type(8)));
typedef _Float16 f16x4 __attribute__((ext_vector_type(4)));
typedef float    f32x4 __attribute__((ext_vector_type(4)));
typedef unsigned int u32;
typedef u32 u32x2 __attribute__((ext_vector_type(2)));

#define C_   192
#define HH   56
#define WW   56
#define NN   3136
#define BB   8
#define MM   784
#define NHEAD 4
#define HD   48
#define VT_LD 832            // padded key-dim of transposed V (784 + 48)
#define QPB  (BB*NN/64)      // 392 proj blocks, Q path
#define KVPB (BB*MM/64)      // 98 proj blocks per K / V path

#define MFMA16(a,b,c)  __builtin_amdgcn_mfma_f32_16x16x32_f16(a,b,c,0,0,0)
#define MFMAK16(a,b,c) __builtin_amdgcn_mfma_f32_16x16x16f16(a,b,c,0,0,0)

static __device__ __forceinline__ u32 pkrtz(float a, float b) {
    typedef __fp16 fp16x2 __attribute__((ext_vector_type(2)));
    fp16x2 h = __builtin_amdgcn_cvt_pkrtz(a, b);
    return __builtin_bit_cast(u32, h);
}

// async global->LDS, 16B per lane; LDS dst = wave-uniform base + lane*16
static __device__ __forceinline__ void gload16(const void* g, void* l) {
    __builtin_amdgcn_global_load_lds(
        (const __attribute__((address_space(1))) unsigned int*)g,
        (__attribute__((address_space(3))) unsigned int*)l, 16, 0, 0);
}

// ---------------------------------------------------------------------------
// Depthwise 3x3 + BN, TWO vertically-adjacent outputs per thread (shares
// loaded rows). Weights from LDS (coalesced staging).
template<int STRIDE, int OH, int OW>
__device__ __forceinline__ void dwbn_pair(
    const float* __restrict__ x, const float* __restrict__ dwL,
    const float* __restrict__ gamma, const float* __restrict__ beta,
    const float* __restrict__ mean,  const float* __restrict__ var,
    f16* __restrict__ out, int idx)
{
    int c4 = idx % 48;
    int r1 = idx / 48;
    int ox = r1 % OW;
    int r2 = r1 / OW;
    int p  = r2 % (OH/2);
    int b  = r2 / (OH/2);
    int c0 = c4*4;

    float4 w4[9];
    #pragma unroll
    for (int j = 0; j < 9; ++j)
        w4[j] = *(const float4*)&dwL[c4*40 + j*4];
    const float* wf = (const float*)w4;   // wf[cc*9 + wi], static indices

    float4 g4  = *(const float4*)(gamma + c0);
    float4 be4 = *(const float4*)(beta + c0);
    float4 m4  = *(const float4*)(mean + c0);
    float4 v4  = *(const float4*)(var  + c0);

    const int NR = STRIDE + 3;           // union of both 3-row windows
    float4 a0 = make_float4(0.f,0.f,0.f,0.f), a1 = a0;
    int iyTop = (2*p)*STRIDE - 1;
    int ix0 = ox*STRIDE - 1;
    #pragma unroll
    for (int j = 0; j < NR; ++j) {
        int iy = iyTop + j;
        if (iy < 0 || iy >= HH) continue;
        #pragma unroll
        for (int kx = 0; kx < 3; ++kx) {
            int ix = ix0 + kx;
            if (ix < 0 || ix >= WW) continue;
            float4 xv = *reinterpret_cast<const float4*>(
                x + ((size_t)b*NN + iy*WW + ix)*C_ + c0);
            if (j <= 2) {                       // contributes to out row 2p
                const int wi = j*3 + kx;
                a0.x = fmaf(wf[ 0+wi], xv.x, a0.x);
                a0.y = fmaf(wf[ 9+wi], xv.y, a0.y);
                a0.z = fmaf(wf[18+wi], xv.z, a0.z);
                a0.w = fmaf(wf[27+wi], xv.w, a0.w);
            }
            if (j >= STRIDE) {                  // contributes to out row 2p+1
                const int wi = (j-STRIDE)*3 + kx;
                a1.x = fmaf(wf[ 0+wi], xv.x, a1.x);
                a1.y = fmaf(wf[ 9+wi], xv.y, a1.y);
                a1.z = fmaf(wf[18+wi], xv.z, a1.z);
                a1.w = fmaf(wf[27+wi], xv.w, a1.w);
            }
        }
    }
    float i0 = g4.x*__frsqrt_rn(v4.x + 1e-5f);
    float i1 = g4.y*__frsqrt_rn(v4.y + 1e-5f);
    float i2 = g4.z*__frsqrt_rn(v4.z + 1e-5f);
    float i3 = g4.w*__frsqrt_rn(v4.w + 1e-5f);
    float b0 = be4.x - m4.x*i0, b1 = be4.y - m4.y*i1;
    float b2 = be4.z - m4.z*i2, b3 = be4.w - m4.w*i3;
    f16x4 r0, r1v;
    r0[0] = (f16)(a0.x*i0 + b0); r0[1] = (f16)(a0.y*i1 + b1);
    r0[2] = (f16)(a0.z*i2 + b2); r0[3] = (f16)(a0.w*i3 + b3);
    r1v[0] = (f16)(a1.x*i0 + b0); r1v[1] = (f16)(a1.y*i1 + b1);
    r1v[2] = (f16)(a1.z*i2 + b2); r1v[3] = (f16)(a1.w*i3 + b3);
    size_t o0 = (((size_t)b*OH + 2*p)*OW + ox)*48 + c4;
    *reinterpret_cast<f16x4*>(out + o0*4)            = r0;
    *reinterpret_cast<f16x4*>(out + (o0 + (size_t)OW*48)*4) = r1v;
}

// ---------------------------------------------------------------------------
// Fused prep: dwbn-pairs (both paths) + pointwise-fold + Vt pad zero.
__global__ __launch_bounds__(256) void prep_all(
    const float* __restrict__ x,
    const float* __restrict__ dwq,  const float* __restrict__ gq,
    const float* __restrict__ bq_,  const float* __restrict__ mq,
    const float* __restrict__ vq,
    const float* __restrict__ dwkv, const float* __restrict__ gkv,
    const float* __restrict__ bkv,  const float* __restrict__ mkv,
    const float* __restrict__ vkv,
    const float* __restrict__ Wq, const float* __restrict__ Wk,
    const float* __restrict__ Wv, const float* __restrict__ pw_q,
    const float* __restrict__ pw_kv,
    f16* __restrict__ uq, f16* __restrict__ ukv,
    f16* __restrict__ Mq, f16* __restrict__ Mk, f16* __restrict__ Mv,
    f16* __restrict__ vt)
{
    int blk = blockIdx.x, tid = threadIdx.x;
    const int QB = 2352, KB = 588;
    if (blk < QB + KB) {
        bool qp = blk < QB;
        __shared__ __align__(16) float dwL[48*40];
        const float* dwg = qp ? dwq : dwkv;
        for (int i = tid; i < 432; i += 256) {
            int f  = i*4;
            int c4 = f/36, r = f%36;
            *(float4*)&dwL[c4*40 + r] = *(const float4*)(dwg + f);
        }
        __syncthreads();
        if (qp)
            dwbn_pair<1, HH, WW>(x, dwL, gq, bq_, mq, vq, uq, blk*256 + tid);
        else
            dwbn_pair<2, 28, 28>(x, dwL, gkv, bkv, mkv, vkv, ukv,
                                 (blk - QB)*256 + tid);
    } else if (blk < QB + KB + 576) {
        int fb = blk - QB - KB;
        int which = fb / 192, o = fb % 192;
        const float* Wm = which == 0 ? Wq : (which == 1 ? Wk : Wv);
        const float* P  = which == 0 ? pw_q : (which == 1 ? pw_kv : pw_kv + C_*C_);
        f16* Mo         = which == 0 ? Mq : (which == 1 ? Mk : Mv);
        __shared__ float wrow[C_];
        if (tid < C_) wrow[tid] = Wm[o*C_ + tid];
        __syncthreads();
        if (tid < C_) {
            float acc = 0.f;
            #pragma unroll 8
            for (int j = 0; j < C_; ++j)
                acc = fmaf(wrow[j], P[j*C_ + tid], acc);
            Mo[o*C_ + tid] = (f16)acc;
        }
    } else {
        int i = (blk - QB - KB - 576)*256 + tid;   // BB*C_*48 = 73728 exactly
        int b = i / (C_*48);
        int rem = i % (C_*48);
        int c = rem / 48;
        int m = MM + (rem % 48);
        vt[((size_t)b*C_ + c)*VT_LD + m] = (f16)0.f;
    }
}

// ---------------------------------------------------------------------------
// Projections, 3-way split: blocks [0,392) Q, [392,490) K, [490,588) V.
__global__ __launch_bounds__(256, 1) void proj_all(
    const f16* __restrict__ uq, const f16* __restrict__ ukv,
    const f16* __restrict__ Mq, const f16* __restrict__ Mk,
    const f16* __restrict__ Mv,
    const float* __restrict__ bq, const float* __restrict__ bk,
    const float* __restrict__ bv,
    f16* __restrict__ qb, f16* __restrict__ kb, f16* __restrict__ vt)
{
    int tid  = threadIdx.x;
    int w    = tid >> 6, l = tid & 63;
    int lrow = l & 15,  lgrp = l >> 4;
    int blk  = blockIdx.x;
    int path = blk < QPB ? 0 : (blk < QPB + KVPB ? 1 : 2);
    const f16* U = path == 0 ? uq : ukv;
    int rblk = path == 0 ? blk : (path == 1 ? blk - QPB : blk - QPB - KVPB);
    int r0 = rblk*64 + w*16;

    const f16* urow = U + (size_t)(r0 + lrow)*C_;
    f16x8 a[6];
    #pragma unroll
    for (int ch = 0; ch < 6; ++ch)
        a[ch] = *(const f16x8*)(urow + ch*32 + lgrp*8);

    f16x8 bfA[6], bfB[6];
    const f16* Mm = path == 0 ? Mq : (path == 1 ? Mk : Mv);

    #pragma unroll
    for (int ch = 0; ch < 6; ++ch)
        bfA[ch] = *(const f16x8*)(Mm + (size_t)lrow*C_ + ch*32 + lgrp*8);

    if (path < 2) {
        // Q folds 1/sqrt(48)*log2(e) for exp2-domain softmax
        const float sc = path == 0 ? 0.14433756729740643f*1.4426950408889634f
                                   : 1.0f;
        const float* bias = path == 0 ? bq : bk;
        f16* dst = path == 0 ? qb : kb;
        #pragma unroll
        for (int ct = 0; ct < 12; ++ct) {
            f16x8* cur = (ct & 1) ? bfB : bfA;
            f16x8* nxt = (ct & 1) ? bfA : bfB;
            if (ct < 11) {
                const f16* mrow = Mm + (size_t)((ct+1)*16 + lrow)*C_;
                #pragma unroll
                for (int ch = 0; ch < 6; ++ch)
                    nxt[ch] = *(const f16x8*)(mrow + ch*32 + lgrp*8);
            }
            f32x4 acc = {0.f,0.f,0.f,0.f};
            #pragma unroll
            for (int ch = 0; ch < 6; ++ch)
                acc = MFMA16(cur[ch], a[ch], acc);          // swapped
            float4 bo = *(const float4*)(bias + ct*16 + lgrp*4);
            f16x4 st;
            st[0] = (f16)((acc[0] + bo.x)*sc);
            st[1] = (f16)((acc[1] + bo.y)*sc);
            st[2] = (f16)((acc[2] + bo.z)*sc);
            st[3] = (f16)((acc[3] + bo.w)*sc);
            *(f16x4*)(dst + (size_t)(r0 + lrow)*C_ + ct*16 + lgrp*4) = st;
        }
    } else {
        #pragma unroll
        for (int ct = 0; ct < 12; ++ct) {            // V projection (transposed)
            f16x8* cur = (ct & 1) ? bfB : bfA;
            f16x8* nxt = (ct & 1) ? bfA : bfB;
            if (ct < 11) {
                const f16* mrow = Mv + (size_t)((ct+1)*16 + lrow)*C_;
                #pragma unroll
                for (int ch = 0; ch < 6; ++ch)
                    nxt[ch] = *(const f16x8*)(mrow + ch*32 + lgrp*8);
            }
            int o = ct*16 + lrow;
            f32x4 acc = {0.f,0.f,0.f,0.f};
            #pragma unroll
            for (int ch = 0; ch < 6; ++ch)
                acc = MFMA16(a[ch], cur[ch], acc);
            float bo = bv[o];
            int rg = r0 + lgrp*4;
            int b  = rg / MM, m = rg % MM;            // 784 % 16 == 0
            f16x4 st;
            st[0] = (f16)(acc[0] + bo);
            st[1] = (f16)(acc[1] + bo);
            st[2] = (f16)(acc[2] + bo);
            st[3] = (f16)(acc[3] + bo);
            *(f16x4*)(vt + ((size_t)b*C_ + o)*VT_LD + m) = st;
        }
    }
}

// ---------------------------------------------------------------------------
// Flash attention R16: R15 structure, plus
//  - QK d32-47 via K=16 MFMA (no zero-padded d48-63 work: 25% fewer QK MFMA
//    cycles and K-frag read bytes)
//  - per-lane partial lrun, cross-lane psum reduction deferred to epilogue
//    (saves 2 DS-shuffles per tile)
__device__ __forceinline__ void stage_tile(
    int w, int l, f16* ldsKb, f16* ldsVb,
    const f16* __restrict__ kbb, const f16* __restrict__ vbb, int m0)
{
    int rr = l >> 3, p = l & 7;
    #pragma unroll
    for (int j = 0; j < 4; ++j) {
        int u = w + j*4;
        if (u < 8) {                      // K rows 8u..8u+7
            int r = u*8 + rr;
            int c = p ^ (r & 7);
            gload16(kbb + (size_t)(m0 + r)*C_ + c*8, ldsKb + u*512);
        } else if (u < 14) {              // V rows (d) 8(u-8)..+7
            int d = (u-8)*8 + rr;
            int c = p ^ (d & 7);
            gload16(vbb + (size_t)d*VT_LD + m0 + c*8, ldsVb + (u-8)*512);
        }
    }
}

// online-softmax update; fills pk[8]; psum accumulated per-lane (no shuffles)
__device__ __forceinline__ float softmax_upd(
    f32x4* s, float& mrun, float& lrun, u32* pk)
{
    float t0 = fmaxf(fmaxf(s[0][0], s[0][1]), fmaxf(s[0][2], s[0][3]));
    float t1 = fmaxf(fmaxf(s[1][0], s[1][1]), fmaxf(s[1][2], s[1][3]));
    float t2 = fmaxf(fmaxf(s[2][0], s[2][1]), fmaxf(s[2][2], s[2][3]));
    float t3 = fmaxf(fmaxf(s[3][0], s[3][1]), fmaxf(s[3][2], s[3][3]));
    float tmax = fmaxf(fmaxf(t0, t1), fmaxf(t2, t3));
    tmax = fmaxf(tmax, __shfl_xor(tmax, 16));
    tmax = fmaxf(tmax, __shfl_xor(tmax, 32));
    float mnew = fmaxf(mrun, tmax);
    float corr = exp2f(mrun - mnew);
    mrun = mnew;
    float psum = 0.f;
    #pragma unroll
    for (int j = 0; j < 4; ++j) {
        #pragma unroll
        for (int r = 0; r < 4; ++r) {
            s[j][r] = exp2f(s[j][r] - mnew);
            psum += s[j][r];
        }
    }
    lrun = lrun*corr + psum;      // per-lane partial; reduced at epilogue
    #pragma unroll
    for (int j = 0; j < 4; ++j) {
        pk[j*2]   = pkrtz(s[j][0], s[j][1]);
        pk[j*2+1] = pkrtz(s[j][2], s[j][3]);
    }
    return corr;
}

__device__ __forceinline__ void compute_tile64(
    const f16* ldsKb, const f16* ldsVb,
    const f16x8& qf0, const f16x4& qfh,
    float& mrun, float& lrun, f32x4& o0, f32x4& o1, f32x4& o2,
    int lrow, int g, bool tail)
{
    const char* kP = (const char*)ldsKb;
    const char* vP = (const char*)ldsVb;
    f32x4 z = {0.f,0.f,0.f,0.f};
    int sw = lrow & 7;
    int cA = (g ^ sw) << 4;                                  // d 0..31 (16B)
    int cH = (((4 + (g >> 1)) ^ sw) << 4) + ((g & 1) << 3);  // d 32..47 (8B)

    f32x4 s[4];
    __builtin_amdgcn_s_setprio(1);
    #pragma unroll
    for (int j = 0; j < 4; ++j) {
        const char* rb = kP + (16*j + lrow)*128;
        f32x4 t = MFMA16(*(const f16x8*)(rb + cA), qf0, z);
        s[j] = MFMAK16(*(const f16x4*)(rb + cH), qfh, t);
    }
    __builtin_amdgcn_s_setprio(0);

    if (tail) {   // keys >= 784 live in blocks 1..3 of tile 12
        f32x4 neg = {-1e30f,-1e30f,-1e30f,-1e30f};
        s[1] = neg; s[2] = neg; s[3] = neg;
    }

    u32 pk[8];
    float corr = softmax_upd(s, mrun, lrun, pk);

    #pragma unroll
    for (int r = 0; r < 4; ++r) { o0[r] *= corr; o1[r] *= corr; o2[r] *= corr; }

    // PV: per 16-key chunk, B-frag is lane-local {pk[2ch],pk[2ch+1]};
    // A-frag = Vt[d=16*db+lrow][m0+16ch+g*4 .. +3] (8B swizzled LDS read).
    #pragma unroll
    for (int ch = 0; ch < 4; ++ch) {
        u32x2 pw = { pk[2*ch], pk[2*ch+1] };
        f16x4 pb = __builtin_bit_cast(f16x4, pw);
        int off = (((2*ch + (g >> 1)) ^ sw) << 4) + ((g & 1) << 3);
        f16x4 v0 = *(const f16x4*)(vP + lrow*128      + off);
        f16x4 v1 = *(const f16x4*)(vP + (16+lrow)*128 + off);
        f16x4 v2 = *(const f16x4*)(vP + (32+lrow)*128 + off);
        __builtin_amdgcn_s_setprio(1);
        o0 = MFMAK16(v0, pb, o0);
        o1 = MFMAK16(v1, pb, o1);
        o2 = MFMAK16(v2, pb, o2);
        __builtin_amdgcn_s_setprio(0);
    }
}

__global__ __launch_bounds__(256, 4) void attn_mfma(
    const f16* __restrict__ qb, const f16* __restrict__ kb,
    const f16* __restrict__ vt, float* __restrict__ out)
{
    __shared__ __align__(16) f16 ldsK[2][64*64];   // 16 KB
    __shared__ __align__(16) f16 ldsV[2][48*64];   // 12 KB

    int tid  = threadIdx.x;
    int w    = tid >> 6, l = tid & 63;
    int lrow = l & 15,  g = l >> 4;
    // XCD swizzle: 1568 = 8*196; 4 (b,h) groups per XCD -> KV L2-resident.
    int swz  = (blockIdx.x & 7)*196 + (blockIdx.x >> 3);
    int bh   = swz / 49, qblk = swz % 49;
    int h    = bh & 3, b = bh >> 2;
    int n0   = qblk*64 + w*16;

    const f16* kbb = kb + (size_t)b*MM*C_ + h*HD;
    const f16* vbb = vt + ((size_t)b*C_ + h*HD)*VT_LD;

    const f16* qrow = qb + ((size_t)b*NN + n0 + lrow)*C_ + h*HD;
    f16x8 qf0 = *(const f16x8*)(qrow + g*8);        // d 0..31 slice per g
    f16x4 qfh = *(const f16x4*)(qrow + 32 + g*4);   // d 32..47 slice per g
    asm volatile("" :: "v"(qf0), "v"(qfh));

    float mrun = -1e30f, lrun = 0.f;
    f32x4 o0 = {0.f,0.f,0.f,0.f}, o1 = o0, o2 = o0;

    // prologue: stage tile 0 into buffer 0
    stage_tile(w, l, &ldsK[0][0], &ldsV[0][0], kbb, vbb, 0);

    for (int t = 0; t < 13; ++t) {
        int nb = t & 1;
        if (t < 12)
            stage_tile(w, l, &ldsK[nb^1][0], &ldsV[nb^1][0], kbb, vbb, (t+1)*64);
        __builtin_amdgcn_sched_barrier(0);
        if (t < 12) {
            if (w < 2) asm volatile("s_waitcnt vmcnt(4)" ::: "memory");
            else       asm volatile("s_waitcnt vmcnt(3)" ::: "memory");
        } else {
            asm volatile("s_waitcnt vmcnt(0)" ::: "memory");
        }
        __builtin_amdgcn_s_barrier();
        __builtin_amdgcn_sched_barrier(0);
        compute_tile64(&ldsK[nb][0], &ldsV[nb][0], qf0, qfh,
                       mrun, lrun, o0, o1, o2, lrow, g, t == 12);
        __builtin_amdgcn_sched_barrier(0);
        __builtin_amdgcn_s_barrier();
    }

    // epilogue: reduce per-lane partial lrun across the 4 lanes of this query
    lrun += __shfl_xor(lrun, 16);
    lrun += __shfl_xor(lrun, 32);
    float inv = 1.f / lrun;
    f32x4 r0, r1, r2;
    #pragma unroll
    for (int r = 0; r < 4; ++r) {
        r0[r] = o0[r]*inv; r1[r] = o1[r]*inv; r2[r] = o2[r]*inv;
    }
    float* obase = out + ((size_t)b*NN + n0 + lrow)*C_ + h*HD + g*4;
    *(f32x4*)(obase)      = r0;
    *(f32x4*)(obase + 16) = r1;
    *(f32x4*)(obase + 32) = r2;
}

// ---------------------------------------------------------------------------
extern "C" void kernel_launch(void* const* d_in, const int* in_sizes, int n_in,
                              void* d_out, int out_size, void* d_ws, size_t ws_size,
                              hipStream_t stream)
{
    const float* x     = (const float*)d_in[0];
    const float* dw_q  = (const float*)d_in[3];
    const float* bnqg  = (const float*)d_in[4];
    const float* bnqb  = (const float*)d_in[5];
    const float* bnqm  = (const float*)d_in[6];
    const float* bnqv  = (const float*)d_in[7];
    const float* pw_q  = (const float*)d_in[8];
    const float* dw_kv = (const float*)d_in[9];
    const float* bnkg  = (const float*)d_in[10];
    const float* bnkb  = (const float*)d_in[11];
    const float* bnkm  = (const float*)d_in[12];
    const float* bnkvv = (const float*)d_in[13];
    const float* pw_kv = (const float*)d_in[14];
    const float* Wq    = (const float*)d_in[15];
    const float* bq    = (const float*)d_in[16];
    const float* Wk    = (const float*)d_in[17];
    const float* bk    = (const float*)d_in[18];
    const float* Wv    = (const float*)d_in[19];
    const float* bv    = (const float*)d_in[20];
    float* out = (float*)d_out;

    f16* p   = (f16*)d_ws;
    f16* Mq16  = p;  p += C_*C_;
    f16* Mk16  = p;  p += C_*C_;
    f16* Mv16  = p;  p += C_*C_;
    f16* uq16  = p;  p += (size_t)BB*NN*C_;
    f16* ukv16 = p;  p += (size_t)BB*MM*C_;
    f16* qb16  = p;  p += (size_t)BB*NN*C_ + 256;    // pad: frag tail reads
    f16* kb16  = p;  p += (size_t)BB*MM*C_ + 16384;  // pad: tail-tile staging overread
    f16* vt16  = p;  p += (size_t)BB*C_*VT_LD;

    prep_all<<<3804, 256, 0, stream>>>(
        x, dw_q, bnqg, bnqb, bnqm, bnqv,
        dw_kv, bnkg, bnkb, bnkm, bnkvv,
        Wq, Wk, Wv, pw_q, pw_kv,
        uq16, ukv16, Mq16, Mk16, Mv16, vt16);

    proj_all<<<QPB + 2*KVPB, 256, 0, stream>>>(
        uq16, ukv16, Mq16, Mk16, Mv16, bq, bk, bv, qb16, kb16, vt16);

    attn_mfma<<<1568, 256, 0, stream>>>(qb16, kb16, vt16, out);
}

// Round 17
// 104.270 us; speedup vs baseline: 1.1640x; 1.0370x over previous
//
#include <hip/hip_runtime.h>
#include <cmath>

typedef _Float16 f16;
typedef _Float16 f16x8 __attribute__((ext_vector_type(8)));
typedef _Float16 f16x4 __attribute__((ext_vector_type(4)));
typedef float    f32x4 __attribute__((ext_vector_type(4)));
typedef unsigned int u32;
typedef u32 u32x2 __attribute__((ext_vector_type(2)));

#define C_   192
#define HH   56
#define WW   56
#define NN   3136
#define BB   8
#define MM   784
#define NHEAD 4
#define HD   48
#define VT_LD 832            // padded key-dim of transposed V (784 + 48)
#define QPB  (BB*NN/32)      // 784 proj blocks, Q path (32 rows each)
#define KVPB (BB*MM/32)      // 196 proj blocks per K / V path

#define MFMA16(a,b,c)  __builtin_amdgcn_mfma_f32_16x16x32_f16(a,b,c,0,0,0)
#define MFMAK16(a,b,c) __builtin_amdgcn_mfma_f32_16x16x16f16(a,b,c,0,0,0)

static __device__ __forceinline__ u32 pkrtz(float a, float b) {
    typedef __fp16 fp16x2 __attribute__((ext_vector_type(2)));
    fp16x2 h = __builtin_amdgcn_cvt_pkrtz(a, b);
    return __builtin_bit_cast(u32, h);
}

// async global->LDS, 16B per lane; LDS dst = wave-uniform base + lane*16
static __device__ __forceinline__ void gload16(const void* g, void* l) {
    __builtin_amdgcn_global_load_lds(
        (const __attribute__((address_space(1))) unsigned int*)g,
        (__attribute__((address_space(3))) unsigned int*)l, 16, 0, 0);
}

// ---------------------------------------------------------------------------
// Depthwise 3x3 + BN, FOUR outputs per thread (2x2 spatial quad sharing a
// (S+3)x(S+3) window union): Q path 16 loads/4 outputs (was 6/output),
// KV path 25/4. Weights from LDS.
template<int STRIDE, int OH, int OW>
__device__ __forceinline__ void dwbn_quad(
    const float* __restrict__ x, const float* __restrict__ dwL,
    const float* __restrict__ gamma, const float* __restrict__ beta,
    const float* __restrict__ mean,  const float* __restrict__ var,
    f16* __restrict__ out, int idx)
{
    int c4 = idx % 48;
    int r1 = idx / 48;
    int qx = r1 % (OW/2);
    int r2 = r1 / (OW/2);
    int qp = r2 % (OH/2);
    int b  = r2 / (OH/2);
    int c0 = c4*4;

    float4 w4[9];
    #pragma unroll
    for (int j = 0; j < 9; ++j)
        w4[j] = *(const float4*)&dwL[c4*40 + j*4];
    const float* wf = (const float*)w4;   // wf[cc*9 + wi], static indices

    float4 g4  = *(const float4*)(gamma + c0);
    float4 be4 = *(const float4*)(beta + c0);
    float4 m4  = *(const float4*)(mean + c0);
    float4 v4  = *(const float4*)(var  + c0);

    float4 a00 = make_float4(0.f,0.f,0.f,0.f);
    float4 a01 = a00, a10 = a00, a11 = a00;
    int iyTop = (2*qp)*STRIDE - 1;
    int ix0   = (2*qx)*STRIDE - 1;
    #pragma unroll
    for (int j = 0; j < STRIDE+3; ++j) {
        int iy = iyTop + j;
        if (iy < 0 || iy >= HH) continue;
        #pragma unroll
        for (int i = 0; i < STRIDE+3; ++i) {
            int ix = ix0 + i;
            if (ix < 0 || ix >= WW) continue;
            float4 xv = *reinterpret_cast<const float4*>(
                x + ((size_t)b*NN + iy*WW + ix)*C_ + c0);
            const bool r0ok = (j <= 2), r1ok = (j >= STRIDE);
            const bool c0ok = (i <= 2), c1ok = (i >= STRIDE);
            if (r0ok && c0ok) { const int wi = j*3 + i;
                a00.x = fmaf(wf[ 0+wi], xv.x, a00.x);
                a00.y = fmaf(wf[ 9+wi], xv.y, a00.y);
                a00.z = fmaf(wf[18+wi], xv.z, a00.z);
                a00.w = fmaf(wf[27+wi], xv.w, a00.w); }
            if (r0ok && c1ok) { const int wi = j*3 + (i-STRIDE);
                a01.x = fmaf(wf[ 0+wi], xv.x, a01.x);
                a01.y = fmaf(wf[ 9+wi], xv.y, a01.y);
                a01.z = fmaf(wf[18+wi], xv.z, a01.z);
                a01.w = fmaf(wf[27+wi], xv.w, a01.w); }
            if (r1ok && c0ok) { const int wi = (j-STRIDE)*3 + i;
                a10.x = fmaf(wf[ 0+wi], xv.x, a10.x);
                a10.y = fmaf(wf[ 9+wi], xv.y, a10.y);
                a10.z = fmaf(wf[18+wi], xv.z, a10.z);
                a10.w = fmaf(wf[27+wi], xv.w, a10.w); }
            if (r1ok && c1ok) { const int wi = (j-STRIDE)*3 + (i-STRIDE);
                a11.x = fmaf(wf[ 0+wi], xv.x, a11.x);
                a11.y = fmaf(wf[ 9+wi], xv.y, a11.y);
                a11.z = fmaf(wf[18+wi], xv.z, a11.z);
                a11.w = fmaf(wf[27+wi], xv.w, a11.w); }
        }
    }
    float i0 = g4.x*__frsqrt_rn(v4.x + 1e-5f);
    float i1 = g4.y*__frsqrt_rn(v4.y + 1e-5f);
    float i2 = g4.z*__frsqrt_rn(v4.z + 1e-5f);
    float i3 = g4.w*__frsqrt_rn(v4.w + 1e-5f);
    float b0 = be4.x - m4.x*i0, b1 = be4.y - m4.y*i1;
    float b2 = be4.z - m4.z*i2, b3 = be4.w - m4.w*i3;
    size_t base = (((size_t)b*OH + 2*qp)*OW + 2*qx)*48 + c4;
    f16x4 r;
    r[0]=(f16)(a00.x*i0+b0); r[1]=(f16)(a00.y*i1+b1);
    r[2]=(f16)(a00.z*i2+b2); r[3]=(f16)(a00.w*i3+b3);
    *reinterpret_cast<f16x4*>(out + base*4) = r;
    r[0]=(f16)(a01.x*i0+b0); r[1]=(f16)(a01.y*i1+b1);
    r[2]=(f16)(a01.z*i2+b2); r[3]=(f16)(a01.w*i3+b3);
    *reinterpret_cast<f16x4*>(out + (base + 48)*4) = r;
    r[0]=(f16)(a10.x*i0+b0); r[1]=(f16)(a10.y*i1+b1);
    r[2]=(f16)(a10.z*i2+b2); r[3]=(f16)(a10.w*i3+b3);
    *reinterpret_cast<f16x4*>(out + (base + (size_t)OW*48)*4) = r;
    r[0]=(f16)(a11.x*i0+b0); r[1]=(f16)(a11.y*i1+b1);
    r[2]=(f16)(a11.z*i2+b2); r[3]=(f16)(a11.w*i3+b3);
    *reinterpret_cast<f16x4*>(out + (base + (size_t)OW*48 + 48)*4) = r;
}

// ---------------------------------------------------------------------------
// Fused prep: dwbn-quads (both paths) + pointwise-fold + Vt pad zero.
// blocks 0..1175       : dwbn Q path (2x2 outputs/thread)
// blocks 1176..1469    : dwbn KV path
// blocks 1470..2045    : M-fold (192 threads active)
// blocks 2046..2333    : Vt pad columns 784..831
__global__ __launch_bounds__(256) void prep_all(
    const float* __restrict__ x,
    const float* __restrict__ dwq,  const float* __restrict__ gq,
    const float* __restrict__ bq_,  const float* __restrict__ mq,
    const float* __restrict__ vq,
    const float* __restrict__ dwkv, const float* __restrict__ gkv,
    const float* __restrict__ bkv,  const float* __restrict__ mkv,
    const float* __restrict__ vkv,
    const float* __restrict__ Wq, const float* __restrict__ Wk,
    const float* __restrict__ Wv, const float* __restrict__ pw_q,
    const float* __restrict__ pw_kv,
    f16* __restrict__ uq, f16* __restrict__ ukv,
    f16* __restrict__ Mq, f16* __restrict__ Mk, f16* __restrict__ Mv,
    f16* __restrict__ vt)
{
    int blk = blockIdx.x, tid = threadIdx.x;
    const int QB = 1176, KB = 294;
    if (blk < QB + KB) {
        bool qp = blk < QB;
        __shared__ __align__(16) float dwL[48*40];
        const float* dwg = qp ? dwq : dwkv;
        for (int i = tid; i < 432; i += 256) {
            int f  = i*4;
            int c4 = f/36, r = f%36;
            *(float4*)&dwL[c4*40 + r] = *(const float4*)(dwg + f);
        }
        __syncthreads();
        if (qp)
            dwbn_quad<1, HH, WW>(x, dwL, gq, bq_, mq, vq, uq, blk*256 + tid);
        else
            dwbn_quad<2, 28, 28>(x, dwL, gkv, bkv, mkv, vkv, ukv,
                                 (blk - QB)*256 + tid);
    } else if (blk < QB + KB + 576) {
        int fb = blk - QB - KB;
        int which = fb / 192, o = fb % 192;
        const float* Wm = which == 0 ? Wq : (which == 1 ? Wk : Wv);
        const float* P  = which == 0 ? pw_q : (which == 1 ? pw_kv : pw_kv + C_*C_);
        f16* Mo         = which == 0 ? Mq : (which == 1 ? Mk : Mv);
        __shared__ float wrow[C_];
        if (tid < C_) wrow[tid] = Wm[o*C_ + tid];
        __syncthreads();
        if (tid < C_) {
            float acc = 0.f;
            #pragma unroll 8
            for (int j = 0; j < C_; ++j)
                acc = fmaf(wrow[j], P[j*C_ + tid], acc);
            Mo[o*C_ + tid] = (f16)acc;
        }
    } else {
        int i = (blk - QB - KB - 576)*256 + tid;   // BB*C_*48 = 73728 exactly
        int b = i / (C_*48);
        int rem = i % (C_*48);
        int c = rem / 48;
        int m = MM + (rem % 48);
        vt[((size_t)b*C_ + c)*VT_LD + m] = (f16)0.f;
    }
}

// ---------------------------------------------------------------------------
// Projections, 128-thread blocks (32 rows) for occupancy: blocks [0,784) Q,
// [784,980) K, [980,1176) V. Q/K swapped operands; V transposed.
__global__ __launch_bounds__(128, 1) void proj_all(
    const f16* __restrict__ uq, const f16* __restrict__ ukv,
    const f16* __restrict__ Mq, const f16* __restrict__ Mk,
    const f16* __restrict__ Mv,
    const float* __restrict__ bq, const float* __restrict__ bk,
    const float* __restrict__ bv,
    f16* __restrict__ qb, f16* __restrict__ kb, f16* __restrict__ vt)
{
    int tid  = threadIdx.x;
    int w    = tid >> 6, l = tid & 63;
    int lrow = l & 15,  lgrp = l >> 4;
    int blk  = blockIdx.x;
    int path = blk < QPB ? 0 : (blk < QPB + KVPB ? 1 : 2);
    const f16* U = path == 0 ? uq : ukv;
    int rblk = path == 0 ? blk : (path == 1 ? blk - QPB : blk - QPB - KVPB);
    int r0 = rblk*32 + w*16;

    const f16* urow = U + (size_t)(r0 + lrow)*C_;
    f16x8 a[6];
    #pragma unroll
    for (int ch = 0; ch < 6; ++ch)
        a[ch] = *(const f16x8*)(urow + ch*32 + lgrp*8);

    f16x8 bfA[6], bfB[6];
    const f16* Mm = path == 0 ? Mq : (path == 1 ? Mk : Mv);

    #pragma unroll
    for (int ch = 0; ch < 6; ++ch)
        bfA[ch] = *(const f16x8*)(Mm + (size_t)lrow*C_ + ch*32 + lgrp*8);

    if (path < 2) {
        // Q folds 1/sqrt(48)*log2(e) for exp2-domain softmax
        const float sc = path == 0 ? 0.14433756729740643f*1.4426950408889634f
                                   : 1.0f;
        const float* bias = path == 0 ? bq : bk;
        f16* dst = path == 0 ? qb : kb;
        #pragma unroll
        for (int ct = 0; ct < 12; ++ct) {
            f16x8* cur = (ct & 1) ? bfB : bfA;
            f16x8* nxt = (ct & 1) ? bfA : bfB;
            if (ct < 11) {
                const f16* mrow = Mm + (size_t)((ct+1)*16 + lrow)*C_;
                #pragma unroll
                for (int ch = 0; ch < 6; ++ch)
                    nxt[ch] = *(const f16x8*)(mrow + ch*32 + lgrp*8);
            }
            f32x4 acc = {0.f,0.f,0.f,0.f};
            #pragma unroll
            for (int ch = 0; ch < 6; ++ch)
                acc = MFMA16(cur[ch], a[ch], acc);          // swapped
            float4 bo = *(const float4*)(bias + ct*16 + lgrp*4);
            f16x4 st;
            st[0] = (f16)((acc[0] + bo.x)*sc);
            st[1] = (f16)((acc[1] + bo.y)*sc);
            st[2] = (f16)((acc[2] + bo.z)*sc);
            st[3] = (f16)((acc[3] + bo.w)*sc);
            *(f16x4*)(dst + (size_t)(r0 + lrow)*C_ + ct*16 + lgrp*4) = st;
        }
    } else {
        #pragma unroll
        for (int ct = 0; ct < 12; ++ct) {            // V projection (transposed)
            f16x8* cur = (ct & 1) ? bfB : bfA;
            f16x8* nxt = (ct & 1) ? bfA : bfB;
            if (ct < 11) {
                const f16* mrow = Mv + (size_t)((ct+1)*16 + lrow)*C_;
                #pragma unroll
                for (int ch = 0; ch < 6; ++ch)
                    nxt[ch] = *(const f16x8*)(mrow + ch*32 + lgrp*8);
            }
            int o = ct*16 + lrow;
            f32x4 acc = {0.f,0.f,0.f,0.f};
            #pragma unroll
            for (int ch = 0; ch < 6; ++ch)
                acc = MFMA16(a[ch], cur[ch], acc);
            float bo = bv[o];
            int rg = r0 + lgrp*4;
            int b  = rg / MM, m = rg % MM;            // 784 % 16 == 0
            f16x4 st;
            st[0] = (f16)(acc[0] + bo);
            st[1] = (f16)(acc[1] + bo);
            st[2] = (f16)(acc[2] + bo);
            st[3] = (f16)(acc[3] + bo);
            *(f16x4*)(vt + ((size_t)b*C_ + o)*VT_LD + m) = st;
        }
    }
}

// ---------------------------------------------------------------------------
// Flash attention (R16, unchanged): LDS-staged K/V, K=32+K=16 QK MFMA,
// lane-local P PV via K=16 MFMA, deferred lrun reduction.
__device__ __forceinline__ void stage_tile(
    int w, int l, f16* ldsKb, f16* ldsVb,
    const f16* __restrict__ kbb, const f16* __restrict__ vbb, int m0)
{
    int rr = l >> 3, p = l & 7;
    #pragma unroll
    for (int j = 0; j < 4; ++j) {
        int u = w + j*4;
        if (u < 8) {                      // K rows 8u..8u+7
            int r = u*8 + rr;
            int c = p ^ (r & 7);
            gload16(kbb + (size_t)(m0 + r)*C_ + c*8, ldsKb + u*512);
        } else if (u < 14) {              // V rows (d) 8(u-8)..+7
            int d = (u-8)*8 + rr;
            int c = p ^ (d & 7);
            gload16(vbb + (size_t)d*VT_LD + m0 + c*8, ldsVb + (u-8)*512);
        }
    }
}

// online-softmax update; fills pk[8]; psum accumulated per-lane (no shuffles)
__device__ __forceinline__ float softmax_upd(
    f32x4* s, float& mrun, float& lrun, u32* pk)
{
    float t0 = fmaxf(fmaxf(s[0][0], s[0][1]), fmaxf(s[0][2], s[0][3]));
    float t1 = fmaxf(fmaxf(s[1][0], s[1][1]), fmaxf(s[1][2], s[1][3]));
    float t2 = fmaxf(fmaxf(s[2][0], s[2][1]), fmaxf(s[2][2], s[2][3]));
    float t3 = fmaxf(fmaxf(s[3][0], s[3][1]), fmaxf(s[3][2], s[3][3]));
    float tmax = fmaxf(fmaxf(t0, t1), fmaxf(t2, t3));
    tmax = fmaxf(tmax, __shfl_xor(tmax, 16));
    tmax = fmaxf(tmax, __shfl_xor(tmax, 32));
    float mnew = fmaxf(mrun, tmax);
    float corr = exp2f(mrun - mnew);
    mrun = mnew;
    float psum = 0.f;
    #pragma unroll
    for (int j = 0; j < 4; ++j) {
        #pragma unroll
        for (int r = 0; r < 4; ++r) {
            s[j][r] = exp2f(s[j][r] - mnew);
            psum += s[j][r];
        }
    }
    lrun = lrun*corr + psum;      // per-lane partial; reduced at epilogue
    #pragma unroll
    for (int j = 0; j < 4; ++j) {
        pk[j*2]   = pkrtz(s[j][0], s[j][1]);
        pk[j*2+1] = pkrtz(s[j][2], s[j][3]);
    }
    return corr;
}

__device__ __forceinline__ void compute_tile64(
    const f16* ldsKb, const f16* ldsVb,
    const f16x8& qf0, const f16x4& qfh,
    float& mrun, float& lrun, f32x4& o0, f32x4& o1, f32x4& o2,
    int lrow, int g, bool tail)
{
    const char* kP = (const char*)ldsKb;
    const char* vP = (const char*)ldsVb;
    f32x4 z = {0.f,0.f,0.f,0.f};
    int sw = lrow & 7;
    int cA = (g ^ sw) << 4;                                  // d 0..31 (16B)
    int cH = (((4 + (g >> 1)) ^ sw) << 4) + ((g & 1) << 3);  // d 32..47 (8B)

    f32x4 s[4];
    __builtin_amdgcn_s_setprio(1);
    #pragma unroll
    for (int j = 0; j < 4; ++j) {
        const char* rb = kP + (16*j + lrow)*128;
        f32x4 t = MFMA16(*(const f16x8*)(rb + cA), qf0, z);
        s[j] = MFMAK16(*(const f16x4*)(rb + cH), qfh, t);
    }
    __builtin_amdgcn_s_setprio(0);

    if (tail) {   // keys >= 784 live in blocks 1..3 of tile 12
        f32x4 neg = {-1e30f,-1e30f,-1e30f,-1e30f};
        s[1] = neg; s[2] = neg; s[3] = neg;
    }

    u32 pk[8];
    float corr = softmax_upd(s, mrun, lrun, pk);

    #pragma unroll
    for (int r = 0; r < 4; ++r) { o0[r] *= corr; o1[r] *= corr; o2[r] *= corr; }

    // PV: per 16-key chunk, B-frag is lane-local {pk[2ch],pk[2ch+1]};
    // A-frag = Vt[d=16*db+lrow][m0+16ch+g*4 .. +3] (8B swizzled LDS read).
    #pragma unroll
    for (int ch = 0; ch < 4; ++ch) {
        u32x2 pw = { pk[2*ch], pk[2*ch+1] };
        f16x4 pb = __builtin_bit_cast(f16x4, pw);
        int off = (((2*ch + (g >> 1)) ^ sw) << 4) + ((g & 1) << 3);
        f16x4 v0 = *(const f16x4*)(vP + lrow*128      + off);
        f16x4 v1 = *(const f16x4*)(vP + (16+lrow)*128 + off);
        f16x4 v2 = *(const f16x4*)(vP + (32+lrow)*128 + off);
        __builtin_amdgcn_s_setprio(1);
        o0 = MFMAK16(v0, pb, o0);
        o1 = MFMAK16(v1, pb, o1);
        o2 = MFMAK16(v2, pb, o2);
        __builtin_amdgcn_s_setprio(0);
    }
}

__global__ __launch_bounds__(256, 4) void attn_mfma(
    const f16* __restrict__ qb, const f16* __restrict__ kb,
    const f16* __restrict__ vt, float* __restrict__ out)
{
    __shared__ __align__(16) f16 ldsK[2][64*64];   // 16 KB
    __shared__ __align__(16) f16 ldsV[2][48*64];   // 12 KB

    int tid  = threadIdx.x;
    int w    = tid >> 6, l = tid & 63;
    int lrow = l & 15,  g = l >> 4;
    // XCD swizzle: 1568 = 8*196; 4 (b,h) groups per XCD -> KV L2-resident.
    int swz  = (blockIdx.x & 7)*196 + (blockIdx.x >> 3);
    int bh   = swz / 49, qblk = swz % 49;
    int h    = bh & 3, b = bh >> 2;
    int n0   = qblk*64 + w*16;

    const f16* kbb = kb + (size_t)b*MM*C_ + h*HD;
    const f16* vbb = vt + ((size_t)b*C_ + h*HD)*VT_LD;

    const f16* qrow = qb + ((size_t)b*NN + n0 + lrow)*C_ + h*HD;
    f16x8 qf0 = *(const f16x8*)(qrow + g*8);        // d 0..31 slice per g
    f16x4 qfh = *(const f16x4*)(qrow + 32 + g*4);   // d 32..47 slice per g
    asm volatile("" :: "v"(qf0), "v"(qfh));

    float mrun = -1e30f, lrun = 0.f;
    f32x4 o0 = {0.f,0.f,0.f,0.f}, o1 = o0, o2 = o0;

    // prologue: stage tile 0 into buffer 0
    stage_tile(w, l, &ldsK[0][0], &ldsV[0][0], kbb, vbb, 0);

    for (int t = 0; t < 13; ++t) {
        int nb = t & 1;
        if (t < 12)
            stage_tile(w, l, &ldsK[nb^1][0], &ldsV[nb^1][0], kbb, vbb, (t+1)*64);
        __builtin_amdgcn_sched_barrier(0);
        if (t < 12) {
            if (w < 2) asm volatile("s_waitcnt vmcnt(4)" ::: "memory");
            else       asm volatile("s_waitcnt vmcnt(3)" ::: "memory");
        } else {
            asm volatile("s_waitcnt vmcnt(0)" ::: "memory");
        }
        __builtin_amdgcn_s_barrier();
        __builtin_amdgcn_sched_barrier(0);
        compute_tile64(&ldsK[nb][0], &ldsV[nb][0], qf0, qfh,
                       mrun, lrun, o0, o1, o2, lrow, g, t == 12);
        __builtin_amdgcn_sched_barrier(0);
        __builtin_amdgcn_s_barrier();
    }

    // epilogue: reduce per-lane partial lrun across the 4 lanes of this query
    lrun += __shfl_xor(lrun, 16);
    lrun += __shfl_xor(lrun, 32);
    float inv = 1.f / lrun;
    f32x4 r0, r1, r2;
    #pragma unroll
    for (int r = 0; r < 4; ++r) {
        r0[r] = o0[r]*inv; r1[r] = o1[r]*inv; r2[r] = o2[r]*inv;
    }
    float* obase = out + ((size_t)b*NN + n0 + lrow)*C_ + h*HD + g*4;
    *(f32x4*)(obase)      = r0;
    *(f32x4*)(obase + 16) = r1;
    *(f32x4*)(obase + 32) = r2;
}

// ---------------------------------------------------------------------------
extern "C" void kernel_launch(void* const* d_in, const int* in_sizes, int n_in,
                              void* d_out, int out_size, void* d_ws, size_t ws_size,
                              hipStream_t stream)
{
    const float* x     = (const float*)d_in[0];
    const float* dw_q  = (const float*)d_in[3];
    const float* bnqg  = (const float*)d_in[4];
    const float* bnqb  = (const float*)d_in[5];
    const float* bnqm  = (const float*)d_in[6];
    const float* bnqv  = (const float*)d_in[7];
    const float* pw_q  = (const float*)d_in[8];
    const float* dw_kv = (const float*)d_in[9];
    const float* bnkg  = (const float*)d_in[10];
    const float* bnkb  = (const float*)d_in[11];
    const float* bnkm  = (const float*)d_in[12];
    const float* bnkvv = (const float*)d_in[13];
    const float* pw_kv = (const float*)d_in[14];
    const float* Wq    = (const float*)d_in[15];
    const float* bq    = (const float*)d_in[16];
    const float* Wk    = (const float*)d_in[17];
    const float* bk    = (const float*)d_in[18];
    const float* Wv    = (const float*)d_in[19];
    const float* bv    = (const float*)d_in[20];
    float* out = (float*)d_out;

    f16* p   = (f16*)d_ws;
    f16* Mq16  = p;  p += C_*C_;
    f16* Mk16  = p;  p += C_*C_;
    f16* Mv16  = p;  p += C_*C_;
    f16* uq16  = p;  p += (size_t)BB*NN*C_;
    f16* ukv16 = p;  p += (size_t)BB*MM*C_;
    f16* qb16  = p;  p += (size_t)BB*NN*C_ + 256;    // pad: frag tail reads
    f16* kb16  = p;  p += (size_t)BB*MM*C_ + 16384;  // pad: tail-tile staging overread
    f16* vt16  = p;  p += (size_t)BB*C_*VT_LD;

    prep_all<<<2334, 256, 0, stream>>>(
        x, dw_q, bnqg, bnqb, bnqm, bnqv,
        dw_kv, bnkg, bnkb, bnkm, bnkvv,
        Wq, Wk, Wv, pw_q, pw_kv,
        uq16, ukv16, Mq16, Mk16, Mv16, vt16);

    proj_all<<<QPB + 2*KVPB, 128, 0, stream>>>(
        uq16, ukv16, Mq16, Mk16, Mv16, bq, bk, bv, qb16, kb16, vt16);

    attn_mfma<<<1568, 256, 0, stream>>>(qb16, kb16, vt16, out);
}

// Round 18
// 100.440 us; speedup vs baseline: 1.2084x; 1.0381x over previous
//
#include <hip/hip_runtime.h>
#include <cmath>

typedef _Float16 f16;
typedef _Float16 f16x8 __attribute__((ext_vector_type(8)));
typedef _Float16 f16x4 __attribute__((ext_vector_type(4)));
typedef float    f32x4 __attribute__((ext_vector_type(4)));
typedef unsigned int u32;
typedef u32 u32x2 __attribute__((ext_vector_type(2)));

#define C_   192
#define HH   56
#define WW   56
#define NN   3136
#define BB   8
#define MM   784
#define NHEAD 4
#define HD   48
#define VT_LD 832            // padded key-dim of transposed V (784 + 48)
#define KVPB (BB*MM/32)      // 196 proj blocks per K / V path

#define MFMA16(a,b,c)  __builtin_amdgcn_mfma_f32_16x16x32_f16(a,b,c,0,0,0)
#define MFMAK16(a,b,c) __builtin_amdgcn_mfma_f32_16x16x16f16(a,b,c,0,0,0)

static __device__ __forceinline__ u32 pkrtz(float a, float b) {
    typedef __fp16 fp16x2 __attribute__((ext_vector_type(2)));
    fp16x2 h = __builtin_amdgcn_cvt_pkrtz(a, b);
    return __builtin_bit_cast(u32, h);
}

// async global->LDS, 16B per lane; LDS dst = wave-uniform base + lane*16
static __device__ __forceinline__ void gload16(const void* g, void* l) {
    __builtin_amdgcn_global_load_lds(
        (const __attribute__((address_space(1))) unsigned int*)g,
        (__attribute__((address_space(3))) unsigned int*)l, 16, 0, 0);
}

// ---------------------------------------------------------------------------
// Depthwise 3x3 + BN, FOUR outputs per thread (2x2 spatial quad). Weights
// from LDS (coalesced staging).
template<int STRIDE, int OH, int OW>
__device__ __forceinline__ void dwbn_quad(
    const float* __restrict__ x, const float* __restrict__ dwL,
    const float* __restrict__ gamma, const float* __restrict__ beta,
    const float* __restrict__ mean,  const float* __restrict__ var,
    f16* __restrict__ out, int idx)
{
    int c4 = idx % 48;
    int r1 = idx / 48;
    int qx = r1 % (OW/2);
    int r2 = r1 / (OW/2);
    int qp = r2 % (OH/2);
    int b  = r2 / (OH/2);
    int c0 = c4*4;

    float4 w4[9];
    #pragma unroll
    for (int j = 0; j < 9; ++j)
        w4[j] = *(const float4*)&dwL[c4*40 + j*4];
    const float* wf = (const float*)w4;   // wf[cc*9 + wi], static indices

    float4 g4  = *(const float4*)(gamma + c0);
    float4 be4 = *(const float4*)(beta + c0);
    float4 m4  = *(const float4*)(mean + c0);
    float4 v4  = *(const float4*)(var  + c0);

    float4 a00 = make_float4(0.f,0.f,0.f,0.f);
    float4 a01 = a00, a10 = a00, a11 = a00;
    int iyTop = (2*qp)*STRIDE - 1;
    int ix0   = (2*qx)*STRIDE - 1;
    #pragma unroll
    for (int j = 0; j < STRIDE+3; ++j) {
        int iy = iyTop + j;
        if (iy < 0 || iy >= HH) continue;
        #pragma unroll
        for (int i = 0; i < STRIDE+3; ++i) {
            int ix = ix0 + i;
            if (ix < 0 || ix >= WW) continue;
            float4 xv = *reinterpret_cast<const float4*>(
                x + ((size_t)b*NN + iy*WW + ix)*C_ + c0);
            const bool r0ok = (j <= 2), r1ok = (j >= STRIDE);
            const bool c0ok = (i <= 2), c1ok = (i >= STRIDE);
            if (r0ok && c0ok) { const int wi = j*3 + i;
                a00.x = fmaf(wf[ 0+wi], xv.x, a00.x);
                a00.y = fmaf(wf[ 9+wi], xv.y, a00.y);
                a00.z = fmaf(wf[18+wi], xv.z, a00.z);
                a00.w = fmaf(wf[27+wi], xv.w, a00.w); }
            if (r0ok && c1ok) { const int wi = j*3 + (i-STRIDE);
                a01.x = fmaf(wf[ 0+wi], xv.x, a01.x);
                a01.y = fmaf(wf[ 9+wi], xv.y, a01.y);
                a01.z = fmaf(wf[18+wi], xv.z, a01.z);
                a01.w = fmaf(wf[27+wi], xv.w, a01.w); }
            if (r1ok && c0ok) { const int wi = (j-STRIDE)*3 + i;
                a10.x = fmaf(wf[ 0+wi], xv.x, a10.x);
                a10.y = fmaf(wf[ 9+wi], xv.y, a10.y);
                a10.z = fmaf(wf[18+wi], xv.z, a10.z);
                a10.w = fmaf(wf[27+wi], xv.w, a10.w); }
            if (r1ok && c1ok) { const int wi = (j-STRIDE)*3 + (i-STRIDE);
                a11.x = fmaf(wf[ 0+wi], xv.x, a11.x);
                a11.y = fmaf(wf[ 9+wi], xv.y, a11.y);
                a11.z = fmaf(wf[18+wi], xv.z, a11.z);
                a11.w = fmaf(wf[27+wi], xv.w, a11.w); }
        }
    }
    float i0 = g4.x*__frsqrt_rn(v4.x + 1e-5f);
    float i1 = g4.y*__frsqrt_rn(v4.y + 1e-5f);
    float i2 = g4.z*__frsqrt_rn(v4.z + 1e-5f);
    float i3 = g4.w*__frsqrt_rn(v4.w + 1e-5f);
    float b0 = be4.x - m4.x*i0, b1 = be4.y - m4.y*i1;
    float b2 = be4.z - m4.z*i2, b3 = be4.w - m4.w*i3;
    size_t base = (((size_t)b*OH + 2*qp)*OW + 2*qx)*48 + c4;
    f16x4 r;
    r[0]=(f16)(a00.x*i0+b0); r[1]=(f16)(a00.y*i1+b1);
    r[2]=(f16)(a00.z*i2+b2); r[3]=(f16)(a00.w*i3+b3);
    *reinterpret_cast<f16x4*>(out + base*4) = r;
    r[0]=(f16)(a01.x*i0+b0); r[1]=(f16)(a01.y*i1+b1);
    r[2]=(f16)(a01.z*i2+b2); r[3]=(f16)(a01.w*i3+b3);
    *reinterpret_cast<f16x4*>(out + (base + 48)*4) = r;
    r[0]=(f16)(a10.x*i0+b0); r[1]=(f16)(a10.y*i1+b1);
    r[2]=(f16)(a10.z*i2+b2); r[3]=(f16)(a10.w*i3+b3);
    *reinterpret_cast<f16x4*>(out + (base + (size_t)OW*48)*4) = r;
    r[0]=(f16)(a11.x*i0+b0); r[1]=(f16)(a11.y*i1+b1);
    r[2]=(f16)(a11.z*i2+b2); r[3]=(f16)(a11.w*i3+b3);
    *reinterpret_cast<f16x4*>(out + (base + (size_t)OW*48 + 48)*4) = r;
}

// ---------------------------------------------------------------------------
// Fused prep: dwbn-quads (both paths) + pointwise-fold + Vt pad zero.
__global__ __launch_bounds__(256) void prep_all(
    const float* __restrict__ x,
    const float* __restrict__ dwq,  const float* __restrict__ gq,
    const float* __restrict__ bq_,  const float* __restrict__ mq,
    const float* __restrict__ vq,
    const float* __restrict__ dwkv, const float* __restrict__ gkv,
    const float* __restrict__ bkv,  const float* __restrict__ mkv,
    const float* __restrict__ vkv,
    const float* __restrict__ Wq, const float* __restrict__ Wk,
    const float* __restrict__ Wv, const float* __restrict__ pw_q,
    const float* __restrict__ pw_kv,
    f16* __restrict__ uq, f16* __restrict__ ukv,
    f16* __restrict__ Mq, f16* __restrict__ Mk, f16* __restrict__ Mv,
    f16* __restrict__ vt)
{
    int blk = blockIdx.x, tid = threadIdx.x;
    const int QB = 1176, KB = 294;
    if (blk < QB + KB) {
        bool qp = blk < QB;
        __shared__ __align__(16) float dwL[48*40];
        const float* dwg = qp ? dwq : dwkv;
        for (int i = tid; i < 432; i += 256) {
            int f  = i*4;
            int c4 = f/36, r = f%36;
            *(float4*)&dwL[c4*40 + r] = *(const float4*)(dwg + f);
        }
        __syncthreads();
        if (qp)
            dwbn_quad<1, HH, WW>(x, dwL, gq, bq_, mq, vq, uq, blk*256 + tid);
        else
            dwbn_quad<2, 28, 28>(x, dwL, gkv, bkv, mkv, vkv, ukv,
                                 (blk - QB)*256 + tid);
    } else if (blk < QB + KB + 576) {
        int fb = blk - QB - KB;
        int which = fb / 192, o = fb % 192;
        const float* Wm = which == 0 ? Wq : (which == 1 ? Wk : Wv);
        const float* P  = which == 0 ? pw_q : (which == 1 ? pw_kv : pw_kv + C_*C_);
        f16* Mo         = which == 0 ? Mq : (which == 1 ? Mk : Mv);
        __shared__ float wrow[C_];
        if (tid < C_) wrow[tid] = Wm[o*C_ + tid];
        __syncthreads();
        if (tid < C_) {
            float acc = 0.f;
            #pragma unroll 8
            for (int j = 0; j < C_; ++j)
                acc = fmaf(wrow[j], P[j*C_ + tid], acc);
            Mo[o*C_ + tid] = (f16)acc;
        }
    } else {
        int i = (blk - QB - KB - 576)*256 + tid;   // BB*C_*48 = 73728 exactly
        int b = i / (C_*48);
        int rem = i % (C_*48);
        int c = rem / 48;
        int m = MM + (rem % 48);
        vt[((size_t)b*C_ + c)*VT_LD + m] = (f16)0.f;
    }
}

// ---------------------------------------------------------------------------
// K/V projections only (Q is fused into attn). 128-thread blocks, 32 rows.
// blocks [0,196) K (swapped operands, packed stores); [196,392) V transposed.
__global__ __launch_bounds__(128, 1) void proj_kv(
    const f16* __restrict__ ukv,
    const f16* __restrict__ Mk, const f16* __restrict__ Mv,
    const float* __restrict__ bk, const float* __restrict__ bv,
    f16* __restrict__ kb, f16* __restrict__ vt)
{
    int tid  = threadIdx.x;
    int w    = tid >> 6, l = tid & 63;
    int lrow = l & 15,  lgrp = l >> 4;
    int blk  = blockIdx.x;
    int path = blk < KVPB ? 1 : 2;
    int rblk = path == 1 ? blk : blk - KVPB;
    int r0 = rblk*32 + w*16;

    const f16* urow = ukv + (size_t)(r0 + lrow)*C_;
    f16x8 a[6];
    #pragma unroll
    for (int ch = 0; ch < 6; ++ch)
        a[ch] = *(const f16x8*)(urow + ch*32 + lgrp*8);

    f16x8 bfA[6], bfB[6];
    const f16* Mm = path == 1 ? Mk : Mv;

    #pragma unroll
    for (int ch = 0; ch < 6; ++ch)
        bfA[ch] = *(const f16x8*)(Mm + (size_t)lrow*C_ + ch*32 + lgrp*8);

    if (path == 1) {
        #pragma unroll
        for (int ct = 0; ct < 12; ++ct) {            // K projection (swapped)
            f16x8* cur = (ct & 1) ? bfB : bfA;
            f16x8* nxt = (ct & 1) ? bfA : bfB;
            if (ct < 11) {
                const f16* mrow = Mm + (size_t)((ct+1)*16 + lrow)*C_;
                #pragma unroll
                for (int ch = 0; ch < 6; ++ch)
                    nxt[ch] = *(const f16x8*)(mrow + ch*32 + lgrp*8);
            }
            f32x4 acc = {0.f,0.f,0.f,0.f};
            #pragma unroll
            for (int ch = 0; ch < 6; ++ch)
                acc = MFMA16(cur[ch], a[ch], acc);
            float4 bo = *(const float4*)(bk + ct*16 + lgrp*4);
            f16x4 st;
            st[0] = (f16)(acc[0] + bo.x);
            st[1] = (f16)(acc[1] + bo.y);
            st[2] = (f16)(acc[2] + bo.z);
            st[3] = (f16)(acc[3] + bo.w);
            *(f16x4*)(kb + (size_t)(r0 + lrow)*C_ + ct*16 + lgrp*4) = st;
        }
    } else {
        #pragma unroll
        for (int ct = 0; ct < 12; ++ct) {            // V projection (transposed)
            f16x8* cur = (ct & 1) ? bfB : bfA;
            f16x8* nxt = (ct & 1) ? bfA : bfB;
            if (ct < 11) {
                const f16* mrow = Mv + (size_t)((ct+1)*16 + lrow)*C_;
                #pragma unroll
                for (int ch = 0; ch < 6; ++ch)
                    nxt[ch] = *(const f16x8*)(mrow + ch*32 + lgrp*8);
            }
            int o = ct*16 + lrow;
            f32x4 acc = {0.f,0.f,0.f,0.f};
            #pragma unroll
            for (int ch = 0; ch < 6; ++ch)
                acc = MFMA16(a[ch], cur[ch], acc);
            float bo = bv[o];
            int rg = r0 + lgrp*4;
            int b  = rg / MM, m = rg % MM;            // 784 % 16 == 0
            f16x4 st;
            st[0] = (f16)(acc[0] + bo);
            st[1] = (f16)(acc[1] + bo);
            st[2] = (f16)(acc[2] + bo);
            st[3] = (f16)(acc[3] + bo);
            *(f16x4*)(vt + ((size_t)b*C_ + o)*VT_LD + m) = st;
        }
    }
}

// ---------------------------------------------------------------------------
// Flash attention R18: R16 loop + FUSED Q-projection in the prologue.
// Per wave: 18 MFMAs compute Q[16 rows][48 d] from u (global, L2-hot) and
// Mq (global, L1-hot); result routed via a per-wave LDS tile into the same
// qf0/qfh fragments as before. Same numerics as the old proj-Q path (RN).
__device__ __forceinline__ void stage_tile(
    int w, int l, f16* ldsKb, f16* ldsVb,
    const f16* __restrict__ kbb, const f16* __restrict__ vbb, int m0)
{
    int rr = l >> 3, p = l & 7;
    #pragma unroll
    for (int j = 0; j < 4; ++j) {
        int u = w + j*4;
        if (u < 8) {                      // K rows 8u..8u+7
            int r = u*8 + rr;
            int c = p ^ (r & 7);
            gload16(kbb + (size_t)(m0 + r)*C_ + c*8, ldsKb + u*512);
        } else if (u < 14) {              // V rows (d) 8(u-8)..+7
            int d = (u-8)*8 + rr;
            int c = p ^ (d & 7);
            gload16(vbb + (size_t)d*VT_LD + m0 + c*8, ldsVb + (u-8)*512);
        }
    }
}

// online-softmax update; fills pk[8]; psum accumulated per-lane (no shuffles)
__device__ __forceinline__ float softmax_upd(
    f32x4* s, float& mrun, float& lrun, u32* pk)
{
    float t0 = fmaxf(fmaxf(s[0][0], s[0][1]), fmaxf(s[0][2], s[0][3]));
    float t1 = fmaxf(fmaxf(s[1][0], s[1][1]), fmaxf(s[1][2], s[1][3]));
    float t2 = fmaxf(fmaxf(s[2][0], s[2][1]), fmaxf(s[2][2], s[2][3]));
    float t3 = fmaxf(fmaxf(s[3][0], s[3][1]), fmaxf(s[3][2], s[3][3]));
    float tmax = fmaxf(fmaxf(t0, t1), fmaxf(t2, t3));
    tmax = fmaxf(tmax, __shfl_xor(tmax, 16));
    tmax = fmaxf(tmax, __shfl_xor(tmax, 32));
    float mnew = fmaxf(mrun, tmax);
    float corr = exp2f(mrun - mnew);
    mrun = mnew;
    float psum = 0.f;
    #pragma unroll
    for (int j = 0; j < 4; ++j) {
        #pragma unroll
        for (int r = 0; r < 4; ++r) {
            s[j][r] = exp2f(s[j][r] - mnew);
            psum += s[j][r];
        }
    }
    lrun = lrun*corr + psum;      // per-lane partial; reduced at epilogue
    #pragma unroll
    for (int j = 0; j < 4; ++j) {
        pk[j*2]   = pkrtz(s[j][0], s[j][1]);
        pk[j*2+1] = pkrtz(s[j][2], s[j][3]);
    }
    return corr;
}

__device__ __forceinline__ void compute_tile64(
    const f16* ldsKb, const f16* ldsVb,
    const f16x8& qf0, const f16x4& qfh,
    float& mrun, float& lrun, f32x4& o0, f32x4& o1, f32x4& o2,
    int lrow, int g, bool tail)
{
    const char* kP = (const char*)ldsKb;
    const char* vP = (const char*)ldsVb;
    f32x4 z = {0.f,0.f,0.f,0.f};
    int sw = lrow & 7;
    int cA = (g ^ sw) << 4;                                  // d 0..31 (16B)
    int cH = (((4 + (g >> 1)) ^ sw) << 4) + ((g & 1) << 3);  // d 32..47 (8B)

    f32x4 s[4];
    __builtin_amdgcn_s_setprio(1);
    #pragma unroll
    for (int j = 0; j < 4; ++j) {
        const char* rb = kP + (16*j + lrow)*128;
        f32x4 t = MFMA16(*(const f16x8*)(rb + cA), qf0, z);
        s[j] = MFMAK16(*(const f16x4*)(rb + cH), qfh, t);
    }
    __builtin_amdgcn_s_setprio(0);

    if (tail) {   // keys >= 784 live in blocks 1..3 of tile 12
        f32x4 neg = {-1e30f,-1e30f,-1e30f,-1e30f};
        s[1] = neg; s[2] = neg; s[3] = neg;
    }

    u32 pk[8];
    float corr = softmax_upd(s, mrun, lrun, pk);

    #pragma unroll
    for (int r = 0; r < 4; ++r) { o0[r] *= corr; o1[r] *= corr; o2[r] *= corr; }

    // PV: per 16-key chunk, B-frag is lane-local {pk[2ch],pk[2ch+1]};
    // A-frag = Vt[d=16*db+lrow][m0+16ch+g*4 .. +3] (8B swizzled LDS read).
    #pragma unroll
    for (int ch = 0; ch < 4; ++ch) {
        u32x2 pw = { pk[2*ch], pk[2*ch+1] };
        f16x4 pb = __builtin_bit_cast(f16x4, pw);
        int off = (((2*ch + (g >> 1)) ^ sw) << 4) + ((g & 1) << 3);
        f16x4 v0 = *(const f16x4*)(vP + lrow*128      + off);
        f16x4 v1 = *(const f16x4*)(vP + (16+lrow)*128 + off);
        f16x4 v2 = *(const f16x4*)(vP + (32+lrow)*128 + off);
        __builtin_amdgcn_s_setprio(1);
        o0 = MFMAK16(v0, pb, o0);
        o1 = MFMAK16(v1, pb, o1);
        o2 = MFMAK16(v2, pb, o2);
        __builtin_amdgcn_s_setprio(0);
    }
}

__global__ __launch_bounds__(256, 2) void attn_mfma(
    const f16* __restrict__ uq, const f16* __restrict__ Mq,
    const float* __restrict__ bq,
    const f16* __restrict__ kb, const f16* __restrict__ vt,
    float* __restrict__ out)
{
    __shared__ __align__(16) f16 ldsK[2][64*64];   // 16 KB
    __shared__ __align__(16) f16 ldsV[2][48*64];   // 12 KB
    __shared__ __align__(16) f16 qL[4][16*56];     // 7 KB, per-wave Q tiles

    int tid  = threadIdx.x;
    int w    = tid >> 6, l = tid & 63;
    int lrow = l & 15,  g = l >> 4;
    // XCD swizzle: 1568 = 8*196; 4 (b,h) groups per XCD -> KV L2-resident.
    int swz  = (blockIdx.x & 7)*196 + (blockIdx.x >> 3);
    int bh   = swz / 49, qblk = swz % 49;
    int h    = bh & 3, b = bh >> 2;
    int n0   = qblk*64 + w*16;

    const f16* kbb = kb + (size_t)b*MM*C_ + h*HD;
    const f16* vbb = vt + ((size_t)b*C_ + h*HD)*VT_LD;

    // prologue: stage tile 0 (DMA latency hides under the Q-proj MFMAs)
    stage_tile(w, l, &ldsK[0][0], &ldsV[0][0], kbb, vbb, 0);

    // ---- fused Q projection: Q[n0w+lrow][d] for this wave's 16 rows ----
    {
        const float qsc = 0.14433756729740643f * 1.4426950408889634f;
        f16* qw = &qL[w][0];
        const f16* urow = uq + ((size_t)b*NN + n0 + lrow)*C_;
        f16x8 ufr[6];
        #pragma unroll
        for (int ch = 0; ch < 6; ++ch)
            ufr[ch] = *(const f16x8*)(urow + ch*32 + g*8);
        #pragma unroll
        for (int dt = 0; dt < 3; ++dt) {
            const f16* mrow = Mq + (size_t)(h*HD + dt*16 + lrow)*C_;
            f32x4 acc = {0.f,0.f,0.f,0.f};
            #pragma unroll
            for (int ch = 0; ch < 6; ++ch)
                acc = MFMA16(*(const f16x8*)(mrow + ch*32 + g*8), ufr[ch], acc);
            float4 bo = *(const float4*)(bq + h*HD + dt*16 + g*4);
            f16x4 st;
            st[0] = (f16)((acc[0] + bo.x)*qsc);
            st[1] = (f16)((acc[1] + bo.y)*qsc);
            st[2] = (f16)((acc[2] + bo.z)*qsc);
            st[3] = (f16)((acc[3] + bo.w)*qsc);
            *(f16x4*)(qw + lrow*56 + dt*16 + g*4) = st;   // lane (lrow,g):
        }                                                  // n=lrow, d=dt*16+g*4+r
    }
    // same wave wrote its own slice; in-wave LDS ordering handled by compiler
    f16x8 qf0 = *(const f16x8*)(&qL[w][0] + lrow*56 + g*8);
    f16x4 qfh = *(const f16x4*)(&qL[w][0] + lrow*56 + 32 + g*4);
    asm volatile("" :: "v"(qf0), "v"(qfh));

    float mrun = -1e30f, lrun = 0.f;
    f32x4 o0 = {0.f,0.f,0.f,0.f}, o1 = o0, o2 = o0;

    for (int t = 0; t < 13; ++t) {
        int nb = t & 1;
        if (t < 12)
            stage_tile(w, l, &ldsK[nb^1][0], &ldsV[nb^1][0], kbb, vbb, (t+1)*64);
        __builtin_amdgcn_sched_barrier(0);
        if (t < 12) {
            if (w < 2) asm volatile("s_waitcnt vmcnt(4)" ::: "memory");
            else       asm volatile("s_waitcnt vmcnt(3)" ::: "memory");
        } else {
            asm volatile("s_waitcnt vmcnt(0)" ::: "memory");
        }
        __builtin_amdgcn_s_barrier();
        __builtin_amdgcn_sched_barrier(0);
        compute_tile64(&ldsK[nb][0], &ldsV[nb][0], qf0, qfh,
                       mrun, lrun, o0, o1, o2, lrow, g, t == 12);
        __builtin_amdgcn_sched_barrier(0);
        __builtin_amdgcn_s_barrier();
    }

    // epilogue: reduce per-lane partial lrun across the 4 lanes of this query
    lrun += __shfl_xor(lrun, 16);
    lrun += __shfl_xor(lrun, 32);
    float inv = 1.f / lrun;
    f32x4 r0, r1, r2;
    #pragma unroll
    for (int r = 0; r < 4; ++r) {
        r0[r] = o0[r]*inv; r1[r] = o1[r]*inv; r2[r] = o2[r]*inv;
    }
    float* obase = out + ((size_t)b*NN + n0 + lrow)*C_ + h*HD + g*4;
    *(f32x4*)(obase)      = r0;
    *(f32x4*)(obase + 16) = r1;
    *(f32x4*)(obase + 32) = r2;
}

// ---------------------------------------------------------------------------
extern "C" void kernel_launch(void* const* d_in, const int* in_sizes, int n_in,
                              void* d_out, int out_size, void* d_ws, size_t ws_size,
                              hipStream_t stream)
{
    const float* x     = (const float*)d_in[0];
    const float* dw_q  = (const float*)d_in[3];
    const float* bnqg  = (const float*)d_in[4];
    const float* bnqb  = (const float*)d_in[5];
    const float* bnqm  = (const float*)d_in[6];
    const float* bnqv  = (const float*)d_in[7];
    const float* pw_q  = (const float*)d_in[8];
    const float* dw_kv = (const float*)d_in[9];
    const float* bnkg  = (const float*)d_in[10];
    const float* bnkb  = (const float*)d_in[11];
    const float* bnkm  = (const float*)d_in[12];
    const float* bnkvv = (const float*)d_in[13];
    const float* pw_kv = (const float*)d_in[14];
    const float* Wq    = (const float*)d_in[15];
    const float* bq    = (const float*)d_in[16];
    const float* Wk    = (const float*)d_in[17];
    const float* bk    = (const float*)d_in[18];
    const float* Wv    = (const float*)d_in[19];
    const float* bv    = (const float*)d_in[20];
    float* out = (float*)d_out;

    f16* p   = (f16*)d_ws;
    f16* Mq16  = p;  p += C_*C_;
    f16* Mk16  = p;  p += C_*C_;
    f16* Mv16  = p;  p += C_*C_;
    f16* uq16  = p;  p += (size_t)BB*NN*C_ + 256;    // pad: frag tail reads
    f16* ukv16 = p;  p += (size_t)BB*MM*C_;
    f16* kb16  = p;  p += (size_t)BB*MM*C_ + 16384;  // pad: tail-tile staging overread
    f16* vt16  = p;  p += (size_t)BB*C_*VT_LD;

    prep_all<<<2334, 256, 0, stream>>>(
        x, dw_q, bnqg, bnqb, bnqm, bnqv,
        dw_kv, bnkg, bnkb, bnkm, bnkvv,
        Wq, Wk, Wv, pw_q, pw_kv,
        uq16, ukv16, Mq16, Mk16, Mv16, vt16);

    proj_kv<<<2*KVPB, 128, 0, stream>>>(
        ukv16, Mk16, Mv16, bk, bv, kb16, vt16);

    attn_mfma<<<1568, 256, 0, stream>>>(uq16, Mq16, bq, kb16, vt16, out);
}

// Round 19
// 97.798 us; speedup vs baseline: 1.2410x; 1.0270x over previous
//
#include <hip/hip_runtime.h>
#include <cmath>

typedef _Float16 f16;
typedef _Float16 f16x8 __attribute__((ext_vector_type(8)));
typedef _Float16 f16x4 __attribute__((ext_vector_type(4)));
typedef float    f32x4 __attribute__((ext_vector_type(4)));
typedef unsigned int u32;
typedef u32 u32x2 __attribute__((ext_vector_type(2)));

#define C_   192
#define HH   56
#define WW   56
#define NN   3136
#define BB   8
#define MM   784
#define NHEAD 4
#define HD   48
#define VT_LD 832            // padded key-dim of transposed V (784 + 48)
#define KVPB (BB*MM/32)      // 196 proj blocks per K / V path

#define MFMA16(a,b,c)  __builtin_amdgcn_mfma_f32_16x16x32_f16(a,b,c,0,0,0)
#define MFMAK16(a,b,c) __builtin_amdgcn_mfma_f32_16x16x16f16(a,b,c,0,0,0)

static __device__ __forceinline__ u32 pkrtz(float a, float b) {
    typedef __fp16 fp16x2 __attribute__((ext_vector_type(2)));
    fp16x2 h = __builtin_amdgcn_cvt_pkrtz(a, b);
    return __builtin_bit_cast(u32, h);
}

// async global->LDS, 16B per lane; LDS dst = wave-uniform base + lane*16
static __device__ __forceinline__ void gload16(const void* g, void* l) {
    __builtin_amdgcn_global_load_lds(
        (const __attribute__((address_space(1))) unsigned int*)g,
        (__attribute__((address_space(3))) unsigned int*)l, 16, 0, 0);
}

// ---------------------------------------------------------------------------
// Depthwise 3x3 + BN (stride 1), EIGHT outputs per thread (2x4 octet sharing
// a 4x6 window union): 24 loads / 8 outputs = 3/output. Weights from LDS.
__device__ __forceinline__ void dwbn_oct(
    const float* __restrict__ x, const float* __restrict__ dwL,
    const float* __restrict__ gamma, const float* __restrict__ beta,
    const float* __restrict__ mean,  const float* __restrict__ var,
    f16* __restrict__ out, int idx)
{
    int c4 = idx % 48;
    int r1 = idx / 48;
    int qx = r1 % (WW/4);
    int r2 = r1 / (WW/4);
    int qp = r2 % (HH/2);
    int b  = r2 / (HH/2);
    int c0 = c4*4;

    float4 w4[9];
    #pragma unroll
    for (int j = 0; j < 9; ++j)
        w4[j] = *(const float4*)&dwL[c4*40 + j*4];
    const float* wf = (const float*)w4;   // wf[cc*9 + wi], static indices

    float4 g4  = *(const float4*)(gamma + c0);
    float4 be4 = *(const float4*)(beta + c0);
    float4 m4  = *(const float4*)(mean + c0);
    float4 v4  = *(const float4*)(var  + c0);

    float4 acc[2][4];
    #pragma unroll
    for (int jj = 0; jj < 2; ++jj)
        #pragma unroll
        for (int ii = 0; ii < 4; ++ii)
            acc[jj][ii] = make_float4(0.f,0.f,0.f,0.f);

    int iyTop = 2*qp - 1;
    int ix0   = 4*qx - 1;
    #pragma unroll
    for (int j = 0; j < 4; ++j) {
        int iy = iyTop + j;
        if (iy < 0 || iy >= HH) continue;
        #pragma unroll
        for (int i = 0; i < 6; ++i) {
            int ix = ix0 + i;
            if (ix < 0 || ix >= WW) continue;
            float4 xv = *reinterpret_cast<const float4*>(
                x + ((size_t)b*NN + iy*WW + ix)*C_ + c0);
            #pragma unroll
            for (int jj = 0; jj < 2; ++jj) {
                if (j < jj || j > jj+2) continue;
                #pragma unroll
                for (int ii = 0; ii < 4; ++ii) {
                    if (i < ii || i > ii+2) continue;
                    const int wi = (j-jj)*3 + (i-ii);
                    acc[jj][ii].x = fmaf(wf[ 0+wi], xv.x, acc[jj][ii].x);
                    acc[jj][ii].y = fmaf(wf[ 9+wi], xv.y, acc[jj][ii].y);
                    acc[jj][ii].z = fmaf(wf[18+wi], xv.z, acc[jj][ii].z);
                    acc[jj][ii].w = fmaf(wf[27+wi], xv.w, acc[jj][ii].w);
                }
            }
        }
    }
    float i0 = g4.x*__frsqrt_rn(v4.x + 1e-5f);
    float i1 = g4.y*__frsqrt_rn(v4.y + 1e-5f);
    float i2 = g4.z*__frsqrt_rn(v4.z + 1e-5f);
    float i3 = g4.w*__frsqrt_rn(v4.w + 1e-5f);
    float b0 = be4.x - m4.x*i0, b1 = be4.y - m4.y*i1;
    float b2 = be4.z - m4.z*i2, b3 = be4.w - m4.w*i3;
    #pragma unroll
    for (int jj = 0; jj < 2; ++jj) {
        #pragma unroll
        for (int ii = 0; ii < 4; ++ii) {
            f16x4 r;
            r[0] = (f16)(acc[jj][ii].x*i0 + b0);
            r[1] = (f16)(acc[jj][ii].y*i1 + b1);
            r[2] = (f16)(acc[jj][ii].z*i2 + b2);
            r[3] = (f16)(acc[jj][ii].w*i3 + b3);
            size_t o = (((size_t)b*HH + 2*qp + jj)*WW + 4*qx + ii)*48 + c4;
            *reinterpret_cast<f16x4*>(out + o*4) = r;
        }
    }
}

// ---------------------------------------------------------------------------
// Depthwise 3x3 + BN stride 2, FOUR outputs per thread (2x2 quad, 5x5 window).
__device__ __forceinline__ void dwbn_quad2(
    const float* __restrict__ x, const float* __restrict__ dwL,
    const float* __restrict__ gamma, const float* __restrict__ beta,
    const float* __restrict__ mean,  const float* __restrict__ var,
    f16* __restrict__ out, int idx)
{
    const int OH = 28, OW = 28, STRIDE = 2;
    int c4 = idx % 48;
    int r1 = idx / 48;
    int qx = r1 % (OW/2);
    int r2 = r1 / (OW/2);
    int qp = r2 % (OH/2);
    int b  = r2 / (OH/2);
    int c0 = c4*4;

    float4 w4[9];
    #pragma unroll
    for (int j = 0; j < 9; ++j)
        w4[j] = *(const float4*)&dwL[c4*40 + j*4];
    const float* wf = (const float*)w4;

    float4 g4  = *(const float4*)(gamma + c0);
    float4 be4 = *(const float4*)(beta + c0);
    float4 m4  = *(const float4*)(mean + c0);
    float4 v4  = *(const float4*)(var  + c0);

    float4 a00 = make_float4(0.f,0.f,0.f,0.f);
    float4 a01 = a00, a10 = a00, a11 = a00;
    int iyTop = (2*qp)*STRIDE - 1;
    int ix0   = (2*qx)*STRIDE - 1;
    #pragma unroll
    for (int j = 0; j < STRIDE+3; ++j) {
        int iy = iyTop + j;
        if (iy < 0 || iy >= HH) continue;
        #pragma unroll
        for (int i = 0; i < STRIDE+3; ++i) {
            int ix = ix0 + i;
            if (ix < 0 || ix >= WW) continue;
            float4 xv = *reinterpret_cast<const float4*>(
                x + ((size_t)b*NN + iy*WW + ix)*C_ + c0);
            const bool r0ok = (j <= 2), r1ok = (j >= STRIDE);
            const bool c0ok = (i <= 2), c1ok = (i >= STRIDE);
            if (r0ok && c0ok) { const int wi = j*3 + i;
                a00.x = fmaf(wf[ 0+wi], xv.x, a00.x);
                a00.y = fmaf(wf[ 9+wi], xv.y, a00.y);
                a00.z = fmaf(wf[18+wi], xv.z, a00.z);
                a00.w = fmaf(wf[27+wi], xv.w, a00.w); }
            if (r0ok && c1ok) { const int wi = j*3 + (i-STRIDE);
                a01.x = fmaf(wf[ 0+wi], xv.x, a01.x);
                a01.y = fmaf(wf[ 9+wi], xv.y, a01.y);
                a01.z = fmaf(wf[18+wi], xv.z, a01.z);
                a01.w = fmaf(wf[27+wi], xv.w, a01.w); }
            if (r1ok && c0ok) { const int wi = (j-STRIDE)*3 + i;
                a10.x = fmaf(wf[ 0+wi], xv.x, a10.x);
                a10.y = fmaf(wf[ 9+wi], xv.y, a10.y);
                a10.z = fmaf(wf[18+wi], xv.z, a10.z);
                a10.w = fmaf(wf[27+wi], xv.w, a10.w); }
            if (r1ok && c1ok) { const int wi = (j-STRIDE)*3 + (i-STRIDE);
                a11.x = fmaf(wf[ 0+wi], xv.x, a11.x);
                a11.y = fmaf(wf[ 9+wi], xv.y, a11.y);
                a11.z = fmaf(wf[18+wi], xv.z, a11.z);
                a11.w = fmaf(wf[27+wi], xv.w, a11.w); }
        }
    }
    float i0 = g4.x*__frsqrt_rn(v4.x + 1e-5f);
    float i1 = g4.y*__frsqrt_rn(v4.y + 1e-5f);
    float i2 = g4.z*__frsqrt_rn(v4.z + 1e-5f);
    float i3 = g4.w*__frsqrt_rn(v4.w + 1e-5f);
    float b0 = be4.x - m4.x*i0, b1 = be4.y - m4.y*i1;
    float b2 = be4.z - m4.z*i2, b3 = be4.w - m4.w*i3;
    size_t base = (((size_t)b*OH + 2*qp)*OW + 2*qx)*48 + c4;
    f16x4 r;
    r[0]=(f16)(a00.x*i0+b0); r[1]=(f16)(a00.y*i1+b1);
    r[2]=(f16)(a00.z*i2+b2); r[3]=(f16)(a00.w*i3+b3);
    *reinterpret_cast<f16x4*>(out + base*4) = r;
    r[0]=(f16)(a01.x*i0+b0); r[1]=(f16)(a01.y*i1+b1);
    r[2]=(f16)(a01.z*i2+b2); r[3]=(f16)(a01.w*i3+b3);
    *reinterpret_cast<f16x4*>(out + (base + 48)*4) = r;
    r[0]=(f16)(a10.x*i0+b0); r[1]=(f16)(a10.y*i1+b1);
    r[2]=(f16)(a10.z*i2+b2); r[3]=(f16)(a10.w*i3+b3);
    *reinterpret_cast<f16x4*>(out + (base + (size_t)OW*48)*4) = r;
    r[0]=(f16)(a11.x*i0+b0); r[1]=(f16)(a11.y*i1+b1);
    r[2]=(f16)(a11.z*i2+b2); r[3]=(f16)(a11.w*i3+b3);
    *reinterpret_cast<f16x4*>(out + (base + (size_t)OW*48 + 48)*4) = r;
}

// ---------------------------------------------------------------------------
// Fused prep: dwbn (oct Q, quad KV) + pointwise-fold + Vt pad zero.
// blocks 0..587        : dwbn Q path (2x4 outputs/thread)
// blocks 588..881      : dwbn KV path (2x2)
// blocks 882..1457     : M-fold (192 threads active)
// blocks 1458..1745    : Vt pad columns 784..831
__global__ __launch_bounds__(256) void prep_all(
    const float* __restrict__ x,
    const float* __restrict__ dwq,  const float* __restrict__ gq,
    const float* __restrict__ bq_,  const float* __restrict__ mq,
    const float* __restrict__ vq,
    const float* __restrict__ dwkv, const float* __restrict__ gkv,
    const float* __restrict__ bkv,  const float* __restrict__ mkv,
    const float* __restrict__ vkv,
    const float* __restrict__ Wq, const float* __restrict__ Wk,
    const float* __restrict__ Wv, const float* __restrict__ pw_q,
    const float* __restrict__ pw_kv,
    f16* __restrict__ uq, f16* __restrict__ ukv,
    f16* __restrict__ Mq, f16* __restrict__ Mk, f16* __restrict__ Mv,
    f16* __restrict__ vt)
{
    int blk = blockIdx.x, tid = threadIdx.x;
    const int QB = 588, KB = 294;
    if (blk < QB + KB) {
        bool qp = blk < QB;
        __shared__ __align__(16) float dwL[48*40];
        const float* dwg = qp ? dwq : dwkv;
        for (int i = tid; i < 432; i += 256) {
            int f  = i*4;
            int c4 = f/36, r = f%36;
            *(float4*)&dwL[c4*40 + r] = *(const float4*)(dwg + f);
        }
        __syncthreads();
        if (qp)
            dwbn_oct(x, dwL, gq, bq_, mq, vq, uq, blk*256 + tid);
        else
            dwbn_quad2(x, dwL, gkv, bkv, mkv, vkv, ukv, (blk - QB)*256 + tid);
    } else if (blk < QB + KB + 576) {
        int fb = blk - QB - KB;
        int which = fb / 192, o = fb % 192;
        const float* Wm = which == 0 ? Wq : (which == 1 ? Wk : Wv);
        const float* P  = which == 0 ? pw_q : (which == 1 ? pw_kv : pw_kv + C_*C_);
        f16* Mo         = which == 0 ? Mq : (which == 1 ? Mk : Mv);
        __shared__ float wrow[C_];
        if (tid < C_) wrow[tid] = Wm[o*C_ + tid];
        __syncthreads();
        if (tid < C_) {
            float acc = 0.f;
            #pragma unroll 8
            for (int j = 0; j < C_; ++j)
                acc = fmaf(wrow[j], P[j*C_ + tid], acc);
            Mo[o*C_ + tid] = (f16)acc;
        }
    } else {
        int i = (blk - QB - KB - 576)*256 + tid;   // BB*C_*48 = 73728 exactly
        int b = i / (C_*48);
        int rem = i % (C_*48);
        int c = rem / 48;
        int m = MM + (rem % 48);
        vt[((size_t)b*C_ + c)*VT_LD + m] = (f16)0.f;
    }
}

// ---------------------------------------------------------------------------
// K/V projections only (Q is fused into attn). 128-thread blocks, 32 rows.
__global__ __launch_bounds__(128, 1) void proj_kv(
    const f16* __restrict__ ukv,
    const f16* __restrict__ Mk, const f16* __restrict__ Mv,
    const float* __restrict__ bk, const float* __restrict__ bv,
    f16* __restrict__ kb, f16* __restrict__ vt)
{
    int tid  = threadIdx.x;
    int w    = tid >> 6, l = tid & 63;
    int lrow = l & 15,  lgrp = l >> 4;
    int blk  = blockIdx.x;
    int path = blk < KVPB ? 1 : 2;
    int rblk = path == 1 ? blk : blk - KVPB;
    int r0 = rblk*32 + w*16;

    const f16* urow = ukv + (size_t)(r0 + lrow)*C_;
    f16x8 a[6];
    #pragma unroll
    for (int ch = 0; ch < 6; ++ch)
        a[ch] = *(const f16x8*)(urow + ch*32 + lgrp*8);

    f16x8 bfA[6], bfB[6];
    const f16* Mm = path == 1 ? Mk : Mv;

    #pragma unroll
    for (int ch = 0; ch < 6; ++ch)
        bfA[ch] = *(const f16x8*)(Mm + (size_t)lrow*C_ + ch*32 + lgrp*8);

    if (path == 1) {
        #pragma unroll
        for (int ct = 0; ct < 12; ++ct) {            // K projection (swapped)
            f16x8* cur = (ct & 1) ? bfB : bfA;
            f16x8* nxt = (ct & 1) ? bfA : bfB;
            if (ct < 11) {
                const f16* mrow = Mm + (size_t)((ct+1)*16 + lrow)*C_;
                #pragma unroll
                for (int ch = 0; ch < 6; ++ch)
                    nxt[ch] = *(const f16x8*)(mrow + ch*32 + lgrp*8);
            }
            f32x4 acc = {0.f,0.f,0.f,0.f};
            #pragma unroll
            for (int ch = 0; ch < 6; ++ch)
                acc = MFMA16(cur[ch], a[ch], acc);
            float4 bo = *(const float4*)(bk + ct*16 + lgrp*4);
            f16x4 st;
            st[0] = (f16)(acc[0] + bo.x);
            st[1] = (f16)(acc[1] + bo.y);
            st[2] = (f16)(acc[2] + bo.z);
            st[3] = (f16)(acc[3] + bo.w);
            *(f16x4*)(kb + (size_t)(r0 + lrow)*C_ + ct*16 + lgrp*4) = st;
        }
    } else {
        #pragma unroll
        for (int ct = 0; ct < 12; ++ct) {            // V projection (transposed)
            f16x8* cur = (ct & 1) ? bfB : bfA;
            f16x8* nxt = (ct & 1) ? bfA : bfB;
            if (ct < 11) {
                const f16* mrow = Mv + (size_t)((ct+1)*16 + lrow)*C_;
                #pragma unroll
                for (int ch = 0; ch < 6; ++ch)
                    nxt[ch] = *(const f16x8*)(mrow + ch*32 + lgrp*8);
            }
            int o = ct*16 + lrow;
            f32x4 acc = {0.f,0.f,0.f,0.f};
            #pragma unroll
            for (int ch = 0; ch < 6; ++ch)
                acc = MFMA16(a[ch], cur[ch], acc);
            float bo = bv[o];
            int rg = r0 + lgrp*4;
            int b  = rg / MM, m = rg % MM;            // 784 % 16 == 0
            f16x4 st;
            st[0] = (f16)(acc[0] + bo);
            st[1] = (f16)(acc[1] + bo);
            st[2] = (f16)(acc[2] + bo);
            st[3] = (f16)(acc[3] + bo);
            *(f16x4*)(vt + ((size_t)b*C_ + o)*VT_LD + m) = st;
        }
    }
}

// ---------------------------------------------------------------------------
// Flash attention (R18): fused Q-projection prologue + R16 loop.
__device__ __forceinline__ void stage_tile(
    int w, int l, f16* ldsKb, f16* ldsVb,
    const f16* __restrict__ kbb, const f16* __restrict__ vbb, int m0)
{
    int rr = l >> 3, p = l & 7;
    #pragma unroll
    for (int j = 0; j < 4; ++j) {
        int u = w + j*4;
        if (u < 8) {                      // K rows 8u..8u+7
            int r = u*8 + rr;
            int c = p ^ (r & 7);
            gload16(kbb + (size_t)(m0 + r)*C_ + c*8, ldsKb + u*512);
        } else if (u < 14) {              // V rows (d) 8(u-8)..+7
            int d = (u-8)*8 + rr;
            int c = p ^ (d & 7);
            gload16(vbb + (size_t)d*VT_LD + m0 + c*8, ldsVb + (u-8)*512);
        }
    }
}

// online-softmax update; fills pk[8]; psum accumulated per-lane (no shuffles)
__device__ __forceinline__ float softmax_upd(
    f32x4* s, float& mrun, float& lrun, u32* pk)
{
    float t0 = fmaxf(fmaxf(s[0][0], s[0][1]), fmaxf(s[0][2], s[0][3]));
    float t1 = fmaxf(fmaxf(s[1][0], s[1][1]), fmaxf(s[1][2], s[1][3]));
    float t2 = fmaxf(fmaxf(s[2][0], s[2][1]), fmaxf(s[2][2], s[2][3]));
    float t3 = fmaxf(fmaxf(s[3][0], s[3][1]), fmaxf(s[3][2], s[3][3]));
    float tmax = fmaxf(fmaxf(t0, t1), fmaxf(t2, t3));
    tmax = fmaxf(tmax, __shfl_xor(tmax, 16));
    tmax = fmaxf(tmax, __shfl_xor(tmax, 32));
    float mnew = fmaxf(mrun, tmax);
    float corr = exp2f(mrun - mnew);
    mrun = mnew;
    float psum = 0.f;
    #pragma unroll
    for (int j = 0; j < 4; ++j) {
        #pragma unroll
        for (int r = 0; r < 4; ++r) {
            s[j][r] = exp2f(s[j][r] - mnew);
            psum += s[j][r];
        }
    }
    lrun = lrun*corr + psum;      // per-lane partial; reduced at epilogue
    #pragma unroll
    for (int j = 0; j < 4; ++j) {
        pk[j*2]   = pkrtz(s[j][0], s[j][1]);
        pk[j*2+1] = pkrtz(s[j][2], s[j][3]);
    }
    return corr;
}

__device__ __forceinline__ void compute_tile64(
    const f16* ldsKb, const f16* ldsVb,
    const f16x8& qf0, const f16x4& qfh,
    float& mrun, float& lrun, f32x4& o0, f32x4& o1, f32x4& o2,
    int lrow, int g, bool tail)
{
    const char* kP = (const char*)ldsKb;
    const char* vP = (const char*)ldsVb;
    f32x4 z = {0.f,0.f,0.f,0.f};
    int sw = lrow & 7;
    int cA = (g ^ sw) << 4;                                  // d 0..31 (16B)
    int cH = (((4 + (g >> 1)) ^ sw) << 4) + ((g & 1) << 3);  // d 32..47 (8B)

    f32x4 s[4];
    __builtin_amdgcn_s_setprio(1);
    #pragma unroll
    for (int j = 0; j < 4; ++j) {
        const char* rb = kP + (16*j + lrow)*128;
        f32x4 t = MFMA16(*(const f16x8*)(rb + cA), qf0, z);
        s[j] = MFMAK16(*(const f16x4*)(rb + cH), qfh, t);
    }
    __builtin_amdgcn_s_setprio(0);

    if (tail) {   // keys >= 784 live in blocks 1..3 of tile 12
        f32x4 neg = {-1e30f,-1e30f,-1e30f,-1e30f};
        s[1] = neg; s[2] = neg; s[3] = neg;
    }

    u32 pk[8];
    float corr = softmax_upd(s, mrun, lrun, pk);

    #pragma unroll
    for (int r = 0; r < 4; ++r) { o0[r] *= corr; o1[r] *= corr; o2[r] *= corr; }

    // PV: per 16-key chunk, B-frag is lane-local {pk[2ch],pk[2ch+1]};
    // A-frag = Vt[d=16*db+lrow][m0+16ch+g*4 .. +3] (8B swizzled LDS read).
    #pragma unroll
    for (int ch = 0; ch < 4; ++ch) {
        u32x2 pw = { pk[2*ch], pk[2*ch+1] };
        f16x4 pb = __builtin_bit_cast(f16x4, pw);
        int off = (((2*ch + (g >> 1)) ^ sw) << 4) + ((g & 1) << 3);
        f16x4 v0 = *(const f16x4*)(vP + lrow*128      + off);
        f16x4 v1 = *(const f16x4*)(vP + (16+lrow)*128 + off);
        f16x4 v2 = *(const f16x4*)(vP + (32+lrow)*128 + off);
        __builtin_amdgcn_s_setprio(1);
        o0 = MFMAK16(v0, pb, o0);
        o1 = MFMAK16(v1, pb, o1);
        o2 = MFMAK16(v2, pb, o2);
        __builtin_amdgcn_s_setprio(0);
    }
}

__global__ __launch_bounds__(256, 2) void attn_mfma(
    const f16* __restrict__ uq, const f16* __restrict__ Mq,
    const float* __restrict__ bq,
    const f16* __restrict__ kb, const f16* __restrict__ vt,
    float* __restrict__ out)
{
    __shared__ __align__(16) f16 ldsK[2][64*64];   // 16 KB
    __shared__ __align__(16) f16 ldsV[2][48*64];   // 12 KB
    __shared__ __align__(16) f16 qL[4][16*56];     // 7 KB, per-wave Q tiles

    int tid  = threadIdx.x;
    int w    = tid >> 6, l = tid & 63;
    int lrow = l & 15,  g = l >> 4;
    // XCD swizzle: 1568 = 8*196; 4 (b,h) groups per XCD -> KV L2-resident.
    int swz  = (blockIdx.x & 7)*196 + (blockIdx.x >> 3);
    int bh   = swz / 49, qblk = swz % 49;
    int h    = bh & 3, b = bh >> 2;
    int n0   = qblk*64 + w*16;

    const f16* kbb = kb + (size_t)b*MM*C_ + h*HD;
    const f16* vbb = vt + ((size_t)b*C_ + h*HD)*VT_LD;

    // u-frags head the prologue dependency chain -> issue them first
    const f16* urow = uq + ((size_t)b*NN + n0 + lrow)*C_;
    f16x8 ufr[6];
    #pragma unroll
    for (int ch = 0; ch < 6; ++ch)
        ufr[ch] = *(const f16x8*)(urow + ch*32 + g*8);

    // stage tile 0 (DMA latency hides under the Q-proj MFMAs)
    stage_tile(w, l, &ldsK[0][0], &ldsV[0][0], kbb, vbb, 0);

    // ---- fused Q projection: Q[n0+lrow][d] for this wave's 16 rows ----
    {
        const float qsc = 0.14433756729740643f * 1.4426950408889634f;
        f16* qw = &qL[w][0];
        #pragma unroll
        for (int dt = 0; dt < 3; ++dt) {
            const f16* mrow = Mq + (size_t)(h*HD + dt*16 + lrow)*C_;
            f32x4 acc = {0.f,0.f,0.f,0.f};
            #pragma unroll
            for (int ch = 0; ch < 6; ++ch)
                acc = MFMA16(*(const f16x8*)(mrow + ch*32 + g*8), ufr[ch], acc);
            float4 bo = *(const float4*)(bq + h*HD + dt*16 + g*4);
            f16x4 st;
            st[0] = (f16)((acc[0] + bo.x)*qsc);
            st[1] = (f16)((acc[1] + bo.y)*qsc);
            st[2] = (f16)((acc[2] + bo.z)*qsc);
            st[3] = (f16)((acc[3] + bo.w)*qsc);
            *(f16x4*)(qw + lrow*56 + dt*16 + g*4) = st;   // lane (lrow,g):
        }                                                  // n=lrow, d=dt*16+g*4+r
    }
    // same wave wrote its own slice; in-wave LDS ordering handled by compiler
    f16x8 qf0 = *(const f16x8*)(&qL[w][0] + lrow*56 + g*8);
    f16x4 qfh = *(const f16x4*)(&qL[w][0] + lrow*56 + 32 + g*4);
    asm volatile("" :: "v"(qf0), "v"(qfh));

    float mrun = -1e30f, lrun = 0.f;
    f32x4 o0 = {0.f,0.f,0.f,0.f}, o1 = o0, o2 = o0;

    for (int t = 0; t < 13; ++t) {
        int nb = t & 1;
        if (t < 12)
            stage_tile(w, l, &ldsK[nb^1][0], &ldsV[nb^1][0], kbb, vbb, (t+1)*64);
        __builtin_amdgcn_sched_barrier(0);
        if (t < 12) {
            if (w < 2) asm volatile("s_waitcnt vmcnt(4)" ::: "memory");
            else       asm volatile("s_waitcnt vmcnt(3)" ::: "memory");
        } else {
            asm volatile("s_waitcnt vmcnt(0)" ::: "memory");
        }
        __builtin_amdgcn_s_barrier();
        __builtin_amdgcn_sched_barrier(0);
        compute_tile64(&ldsK[nb][0], &ldsV[nb][0], qf0, qfh,
                       mrun, lrun, o0, o1, o2, lrow, g, t == 12);
        __builtin_amdgcn_sched_barrier(0);
        __builtin_amdgcn_s_barrier();
    }

    // epilogue: reduce per-lane partial lrun across the 4 lanes of this query
    lrun += __shfl_xor(lrun, 16);
    lrun += __shfl_xor(lrun, 32);
    float inv = 1.f / lrun;
    f32x4 r0, r1, r2;
    #pragma unroll
    for (int r = 0; r < 4; ++r) {
        r0[r] = o0[r]*inv; r1[r] = o1[r]*inv; r2[r] = o2[r]*inv;
    }
    float* obase = out + ((size_t)b*NN + n0 + lrow)*C_ + h*HD + g*4;
    *(f32x4*)(obase)      = r0;
    *(f32x4*)(obase + 16) = r1;
    *(f32x4*)(obase + 32) = r2;
}

// ---------------------------------------------------------------------------
extern "C" void kernel_launch(void* const* d_in, const int* in_sizes, int n_in,
                              void* d_out, int out_size, void* d_ws, size_t ws_size,
                              hipStream_t stream)
{
    const float* x     = (const float*)d_in[0];
    const float* dw_q  = (const float*)d_in[3];
    const float* bnqg  = (const float*)d_in[4];
    const float* bnqb  = (const float*)d_in[5];
    const float* bnqm  = (const float*)d_in[6];
    const float* bnqv  = (const float*)d_in[7];
    const float* pw_q  = (const float*)d_in[8];
    const float* dw_kv = (const float*)d_in[9];
    const float* bnkg  = (const float*)d_in[10];
    const float* bnkb  = (const float*)d_in[11];
    const float* bnkm  = (const float*)d_in[12];
    const float* bnkvv = (const float*)d_in[13];
    const float* pw_kv = (const float*)d_in[14];
    const float* Wq    = (const float*)d_in[15];
    const float* bq    = (const float*)d_in[16];
    const float* Wk    = (const float*)d_in[17];
    const float* bk    = (const float*)d_in[18];
    const float* Wv    = (const float*)d_in[19];
    const float* bv    = (const float*)d_in[20];
    float* out = (float*)d_out;

    f16* p   = (f16*)d_ws;
    f16* Mq16  = p;  p += C_*C_;
    f16* Mk16  = p;  p += C_*C_;
    f16* Mv16  = p;  p += C_*C_;
    f16* uq16  = p;  p += (size_t)BB*NN*C_ + 256;    // pad: frag tail reads
    f16* ukv16 = p;  p += (size_t)BB*MM*C_;
    f16* kb16  = p;  p += (size_t)BB*MM*C_ + 16384;  // pad: tail-tile staging overread
    f16* vt16  = p;  p += (size_t)BB*C_*VT_LD;

    prep_all<<<1746, 256, 0, stream>>>(
        x, dw_q, bnqg, bnqb, bnqm, bnqv,
        dw_kv, bnkg, bnkb, bnkm, bnkvv,
        Wq, Wk, Wv, pw_q, pw_kv,
        uq16, ukv16, Mq16, Mk16, Mv16, vt16);

    proj_kv<<<2*KVPB, 128, 0, stream>>>(
        ukv16, Mk16, Mv16, bk, bv, kb16, vt16);

    attn_mfma<<<1568, 256, 0, stream>>>(uq16, Mq16, bq, kb16, vt16, out);
}

// Round 20
// 95.049 us; speedup vs baseline: 1.2769x; 1.0289x over previous
//
#include <hip/hip_runtime.h>
#include <cmath>

typedef _Float16 f16;
typedef _Float16 f16x8 __attribute__((ext_vector_type(8)));
typedef _Float16 f16x4 __attribute__((ext_vector_type(4)));
typedef float    f32x4 __attribute__((ext_vector_type(4)));
typedef unsigned int u32;
typedef u32 u32x2 __attribute__((ext_vector_type(2)));

#define C_   192
#define HH   56
#define WW   56
#define NN   3136
#define BB   8
#define MM   784
#define NHEAD 4
#define HD   48
#define VT_LD 832            // padded key-dim of transposed V (784 + 48)
#define KVPB (BB*MM/32)      // 196 proj blocks per K / V path

#define MFMA16(a,b,c)  __builtin_amdgcn_mfma_f32_16x16x32_f16(a,b,c,0,0,0)
#define MFMAK16(a,b,c) __builtin_amdgcn_mfma_f32_16x16x16f16(a,b,c,0,0,0)

static __device__ __forceinline__ u32 pkrtz(float a, float b) {
    typedef __fp16 fp16x2 __attribute__((ext_vector_type(2)));
    fp16x2 h = __builtin_amdgcn_cvt_pkrtz(a, b);
    return __builtin_bit_cast(u32, h);
}

// async global->LDS, 16B per lane; LDS dst = wave-uniform base + lane*16
static __device__ __forceinline__ void gload16(const void* g, void* l) {
    __builtin_amdgcn_global_load_lds(
        (const __attribute__((address_space(1))) unsigned int*)g,
        (__attribute__((address_space(3))) unsigned int*)l, 16, 0, 0);
}

// ---------------------------------------------------------------------------
// Depthwise 3x3 + BN (stride 1), EIGHT outputs per thread (2x4 octet sharing
// a 4x6 window union): 24 loads / 8 outputs = 3/output. Weights from LDS.
__device__ __forceinline__ void dwbn_oct(
    const float* __restrict__ x, const float* __restrict__ dwL,
    const float* __restrict__ gamma, const float* __restrict__ beta,
    const float* __restrict__ mean,  const float* __restrict__ var,
    f16* __restrict__ out, int idx)
{
    int c4 = idx % 48;
    int r1 = idx / 48;
    int qx = r1 % (WW/4);
    int r2 = r1 / (WW/4);
    int qp = r2 % (HH/2);
    int b  = r2 / (HH/2);
    int c0 = c4*4;

    float4 w4[9];
    #pragma unroll
    for (int j = 0; j < 9; ++j)
        w4[j] = *(const float4*)&dwL[c4*40 + j*4];
    const float* wf = (const float*)w4;   // wf[cc*9 + wi], static indices

    float4 g4  = *(const float4*)(gamma + c0);
    float4 be4 = *(const float4*)(beta + c0);
    float4 m4  = *(const float4*)(mean + c0);
    float4 v4  = *(const float4*)(var  + c0);

    float4 acc[2][4];
    #pragma unroll
    for (int jj = 0; jj < 2; ++jj)
        #pragma unroll
        for (int ii = 0; ii < 4; ++ii)
            acc[jj][ii] = make_float4(0.f,0.f,0.f,0.f);

    int iyTop = 2*qp - 1;
    int ix0   = 4*qx - 1;
    #pragma unroll
    for (int j = 0; j < 4; ++j) {
        int iy = iyTop + j;
        if (iy < 0 || iy >= HH) continue;
        #pragma unroll
        for (int i = 0; i < 6; ++i) {
            int ix = ix0 + i;
            if (ix < 0 || ix >= WW) continue;
            float4 xv = *reinterpret_cast<const float4*>(
                x + ((size_t)b*NN + iy*WW + ix)*C_ + c0);
            #pragma unroll
            for (int jj = 0; jj < 2; ++jj) {
                if (j < jj || j > jj+2) continue;
                #pragma unroll
                for (int ii = 0; ii < 4; ++ii) {
                    if (i < ii || i > ii+2) continue;
                    const int wi = (j-jj)*3 + (i-ii);
                    acc[jj][ii].x = fmaf(wf[ 0+wi], xv.x, acc[jj][ii].x);
                    acc[jj][ii].y = fmaf(wf[ 9+wi], xv.y, acc[jj][ii].y);
                    acc[jj][ii].z = fmaf(wf[18+wi], xv.z, acc[jj][ii].z);
                    acc[jj][ii].w = fmaf(wf[27+wi], xv.w, acc[jj][ii].w);
                }
            }
        }
    }
    float i0 = g4.x*__frsqrt_rn(v4.x + 1e-5f);
    float i1 = g4.y*__frsqrt_rn(v4.y + 1e-5f);
    float i2 = g4.z*__frsqrt_rn(v4.z + 1e-5f);
    float i3 = g4.w*__frsqrt_rn(v4.w + 1e-5f);
    float b0 = be4.x - m4.x*i0, b1 = be4.y - m4.y*i1;
    float b2 = be4.z - m4.z*i2, b3 = be4.w - m4.w*i3;
    #pragma unroll
    for (int jj = 0; jj < 2; ++jj) {
        #pragma unroll
        for (int ii = 0; ii < 4; ++ii) {
            f16x4 r;
            r[0] = (f16)(acc[jj][ii].x*i0 + b0);
            r[1] = (f16)(acc[jj][ii].y*i1 + b1);
            r[2] = (f16)(acc[jj][ii].z*i2 + b2);
            r[3] = (f16)(acc[jj][ii].w*i3 + b3);
            size_t o = (((size_t)b*HH + 2*qp + jj)*WW + 4*qx + ii)*48 + c4;
            *reinterpret_cast<f16x4*>(out + o*4) = r;
        }
    }
}

// ---------------------------------------------------------------------------
// Depthwise 3x3 + BN stride 2, FOUR outputs per thread (2x2 quad, 5x5 window).
__device__ __forceinline__ void dwbn_quad2(
    const float* __restrict__ x, const float* __restrict__ dwL,
    const float* __restrict__ gamma, const float* __restrict__ beta,
    const float* __restrict__ mean,  const float* __restrict__ var,
    f16* __restrict__ out, int idx)
{
    const int OH = 28, OW = 28, STRIDE = 2;
    int c4 = idx % 48;
    int r1 = idx / 48;
    int qx = r1 % (OW/2);
    int r2 = r1 / (OW/2);
    int qp = r2 % (OH/2);
    int b  = r2 / (OH/2);
    int c0 = c4*4;

    float4 w4[9];
    #pragma unroll
    for (int j = 0; j < 9; ++j)
        w4[j] = *(const float4*)&dwL[c4*40 + j*4];
    const float* wf = (const float*)w4;

    float4 g4  = *(const float4*)(gamma + c0);
    float4 be4 = *(const float4*)(beta + c0);
    float4 m4  = *(const float4*)(mean + c0);
    float4 v4  = *(const float4*)(var  + c0);

    float4 a00 = make_float4(0.f,0.f,0.f,0.f);
    float4 a01 = a00, a10 = a00, a11 = a00;
    int iyTop = (2*qp)*STRIDE - 1;
    int ix0   = (2*qx)*STRIDE - 1;
    #pragma unroll
    for (int j = 0; j < STRIDE+3; ++j) {
        int iy = iyTop + j;
        if (iy < 0 || iy >= HH) continue;
        #pragma unroll
        for (int i = 0; i < STRIDE+3; ++i) {
            int ix = ix0 + i;
            if (ix < 0 || ix >= WW) continue;
            float4 xv = *reinterpret_cast<const float4*>(
                x + ((size_t)b*NN + iy*WW + ix)*C_ + c0);
            const bool r0ok = (j <= 2), r1ok = (j >= STRIDE);
            const bool c0ok = (i <= 2), c1ok = (i >= STRIDE);
            if (r0ok && c0ok) { const int wi = j*3 + i;
                a00.x = fmaf(wf[ 0+wi], xv.x, a00.x);
                a00.y = fmaf(wf[ 9+wi], xv.y, a00.y);
                a00.z = fmaf(wf[18+wi], xv.z, a00.z);
                a00.w = fmaf(wf[27+wi], xv.w, a00.w); }
            if (r0ok && c1ok) { const int wi = j*3 + (i-STRIDE);
                a01.x = fmaf(wf[ 0+wi], xv.x, a01.x);
                a01.y = fmaf(wf[ 9+wi], xv.y, a01.y);
                a01.z = fmaf(wf[18+wi], xv.z, a01.z);
                a01.w = fmaf(wf[27+wi], xv.w, a01.w); }
            if (r1ok && c0ok) { const int wi = (j-STRIDE)*3 + i;
                a10.x = fmaf(wf[ 0+wi], xv.x, a10.x);
                a10.y = fmaf(wf[ 9+wi], xv.y, a10.y);
                a10.z = fmaf(wf[18+wi], xv.z, a10.z);
                a10.w = fmaf(wf[27+wi], xv.w, a10.w); }
            if (r1ok && c1ok) { const int wi = (j-STRIDE)*3 + (i-STRIDE);
                a11.x = fmaf(wf[ 0+wi], xv.x, a11.x);
                a11.y = fmaf(wf[ 9+wi], xv.y, a11.y);
                a11.z = fmaf(wf[18+wi], xv.z, a11.z);
                a11.w = fmaf(wf[27+wi], xv.w, a11.w); }
        }
    }
    float i0 = g4.x*__frsqrt_rn(v4.x + 1e-5f);
    float i1 = g4.y*__frsqrt_rn(v4.y + 1e-5f);
    float i2 = g4.z*__frsqrt_rn(v4.z + 1e-5f);
    float i3 = g4.w*__frsqrt_rn(v4.w + 1e-5f);
    float b0 = be4.x - m4.x*i0, b1 = be4.y - m4.y*i1;
    float b2 = be4.z - m4.z*i2, b3 = be4.w - m4.w*i3;
    size_t base = (((size_t)b*OH + 2*qp)*OW + 2*qx)*48 + c4;
    f16x4 r;
    r[0]=(f16)(a00.x*i0+b0); r[1]=(f16)(a00.y*i1+b1);
    r[2]=(f16)(a00.z*i2+b2); r[3]=(f16)(a00.w*i3+b3);
    *reinterpret_cast<f16x4*>(out + base*4) = r;
    r[0]=(f16)(a01.x*i0+b0); r[1]=(f16)(a01.y*i1+b1);
    r[2]=(f16)(a01.z*i2+b2); r[3]=(f16)(a01.w*i3+b3);
    *reinterpret_cast<f16x4*>(out + (base + 48)*4) = r;
    r[0]=(f16)(a10.x*i0+b0); r[1]=(f16)(a10.y*i1+b1);
    r[2]=(f16)(a10.z*i2+b2); r[3]=(f16)(a10.w*i3+b3);
    *reinterpret_cast<f16x4*>(out + (base + (size_t)OW*48)*4) = r;
    r[0]=(f16)(a11.x*i0+b0); r[1]=(f16)(a11.y*i1+b1);
    r[2]=(f16)(a11.z*i2+b2); r[3]=(f16)(a11.w*i3+b3);
    *reinterpret_cast<f16x4*>(out + (base + (size_t)OW*48 + 48)*4) = r;
}

// ---------------------------------------------------------------------------
// Fused prep: dwbn (oct Q, quad KV) + pointwise-fold + Vt pad zero.
__global__ __launch_bounds__(256) void prep_all(
    const float* __restrict__ x,
    const float* __restrict__ dwq,  const float* __restrict__ gq,
    const float* __restrict__ bq_,  const float* __restrict__ mq,
    const float* __restrict__ vq,
    const float* __restrict__ dwkv, const float* __restrict__ gkv,
    const float* __restrict__ bkv,  const float* __restrict__ mkv,
    const float* __restrict__ vkv,
    const float* __restrict__ Wq, const float* __restrict__ Wk,
    const float* __restrict__ Wv, const float* __restrict__ pw_q,
    const float* __restrict__ pw_kv,
    f16* __restrict__ uq, f16* __restrict__ ukv,
    f16* __restrict__ Mq, f16* __restrict__ Mk, f16* __restrict__ Mv,
    f16* __restrict__ vt)
{
    int blk = blockIdx.x, tid = threadIdx.x;
    const int QB = 588, KB = 294;
    if (blk < QB + KB) {
        bool qp = blk < QB;
        __shared__ __align__(16) float dwL[48*40];
        const float* dwg = qp ? dwq : dwkv;
        for (int i = tid; i < 432; i += 256) {
            int f  = i*4;
            int c4 = f/36, r = f%36;
            *(float4*)&dwL[c4*40 + r] = *(const float4*)(dwg + f);
        }
        __syncthreads();
        if (qp)
            dwbn_oct(x, dwL, gq, bq_, mq, vq, uq, blk*256 + tid);
        else
            dwbn_quad2(x, dwL, gkv, bkv, mkv, vkv, ukv, (blk - QB)*256 + tid);
    } else if (blk < QB + KB + 576) {
        int fb = blk - QB - KB;
        int which = fb / 192, o = fb % 192;
        const float* Wm = which == 0 ? Wq : (which == 1 ? Wk : Wv);
        const float* P  = which == 0 ? pw_q : (which == 1 ? pw_kv : pw_kv + C_*C_);
        f16* Mo         = which == 0 ? Mq : (which == 1 ? Mk : Mv);
        __shared__ float wrow[C_];
        if (tid < C_) wrow[tid] = Wm[o*C_ + tid];
        __syncthreads();
        if (tid < C_) {
            float acc = 0.f;
            #pragma unroll 8
            for (int j = 0; j < C_; ++j)
                acc = fmaf(wrow[j], P[j*C_ + tid], acc);
            Mo[o*C_ + tid] = (f16)acc;
        }
    } else {
        int i = (blk - QB - KB - 576)*256 + tid;   // BB*C_*48 = 73728 exactly
        int b = i / (C_*48);
        int rem = i % (C_*48);
        int c = rem / 48;
        int m = MM + (rem % 48);
        vt[((size_t)b*C_ + c)*VT_LD + m] = (f16)0.f;
    }
}

// ---------------------------------------------------------------------------
// K/V projections only (Q is fused into attn). 128-thread blocks, 32 rows.
__global__ __launch_bounds__(128, 1) void proj_kv(
    const f16* __restrict__ ukv,
    const f16* __restrict__ Mk, const f16* __restrict__ Mv,
    const float* __restrict__ bk, const float* __restrict__ bv,
    f16* __restrict__ kb, f16* __restrict__ vt)
{
    int tid  = threadIdx.x;
    int w    = tid >> 6, l = tid & 63;
    int lrow = l & 15,  lgrp = l >> 4;
    int blk  = blockIdx.x;
    int path = blk < KVPB ? 1 : 2;
    int rblk = path == 1 ? blk : blk - KVPB;
    int r0 = rblk*32 + w*16;

    const f16* urow = ukv + (size_t)(r0 + lrow)*C_;
    f16x8 a[6];
    #pragma unroll
    for (int ch = 0; ch < 6; ++ch)
        a[ch] = *(const f16x8*)(urow + ch*32 + lgrp*8);

    f16x8 bfA[6], bfB[6];
    const f16* Mm = path == 1 ? Mk : Mv;

    #pragma unroll
    for (int ch = 0; ch < 6; ++ch)
        bfA[ch] = *(const f16x8*)(Mm + (size_t)lrow*C_ + ch*32 + lgrp*8);

    if (path == 1) {
        #pragma unroll
        for (int ct = 0; ct < 12; ++ct) {            // K projection (swapped)
            f16x8* cur = (ct & 1) ? bfB : bfA;
            f16x8* nxt = (ct & 1) ? bfA : bfB;
            if (ct < 11) {
                const f16* mrow = Mm + (size_t)((ct+1)*16 + lrow)*C_;
                #pragma unroll
                for (int ch = 0; ch < 6; ++ch)
                    nxt[ch] = *(const f16x8*)(mrow + ch*32 + lgrp*8);
            }
            f32x4 acc = {0.f,0.f,0.f,0.f};
            #pragma unroll
            for (int ch = 0; ch < 6; ++ch)
                acc = MFMA16(cur[ch], a[ch], acc);
            float4 bo = *(const float4*)(bk + ct*16 + lgrp*4);
            f16x4 st;
            st[0] = (f16)(acc[0] + bo.x);
            st[1] = (f16)(acc[1] + bo.y);
            st[2] = (f16)(acc[2] + bo.z);
            st[3] = (f16)(acc[3] + bo.w);
            *(f16x4*)(kb + (size_t)(r0 + lrow)*C_ + ct*16 + lgrp*4) = st;
        }
    } else {
        #pragma unroll
        for (int ct = 0; ct < 12; ++ct) {            // V projection (transposed)
            f16x8* cur = (ct & 1) ? bfB : bfA;
            f16x8* nxt = (ct & 1) ? bfA : bfB;
            if (ct < 11) {
                const f16* mrow = Mv + (size_t)((ct+1)*16 + lrow)*C_;
                #pragma unroll
                for (int ch = 0; ch < 6; ++ch)
                    nxt[ch] = *(const f16x8*)(mrow + ch*32 + lgrp*8);
            }
            int o = ct*16 + lrow;
            f32x4 acc = {0.f,0.f,0.f,0.f};
            #pragma unroll
            for (int ch = 0; ch < 6; ++ch)
                acc = MFMA16(a[ch], cur[ch], acc);
            float bo = bv[o];
            int rg = r0 + lgrp*4;
            int b  = rg / MM, m = rg % MM;            // 784 % 16 == 0
            f16x4 st;
            st[0] = (f16)(acc[0] + bo);
            st[1] = (f16)(acc[1] + bo);
            st[2] = (f16)(acc[2] + bo);
            st[3] = (f16)(acc[3] + bo);
            *(f16x4*)(vt + ((size_t)b*C_ + o)*VT_LD + m) = st;
        }
    }
}

// ---------------------------------------------------------------------------
// Flash attention R20: fused Q-proj prologue with qL ALIASED onto ldsK[1]
// (LDS 35.8->28.7 KB -> 5 blocks/CU), plus defer-max (THR=8, exp2 domain):
// common tiles skip the 2 cross-lane max shuffles, corr exp2 and the 12
// O-rescale muls (wave-uniform __all branch).
__device__ __forceinline__ void stage_tile(
    int w, int l, f16* ldsKb, f16* ldsVb,
    const f16* __restrict__ kbb, const f16* __restrict__ vbb, int m0)
{
    int rr = l >> 3, p = l & 7;
    #pragma unroll
    for (int j = 0; j < 4; ++j) {
        int u = w + j*4;
        if (u < 8) {                      // K rows 8u..8u+7
            int r = u*8 + rr;
            int c = p ^ (r & 7);
            gload16(kbb + (size_t)(m0 + r)*C_ + c*8, ldsKb + u*512);
        } else if (u < 14) {              // V rows (d) 8(u-8)..+7
            int d = (u-8)*8 + rr;
            int c = p ^ (d & 7);
            gload16(vbb + (size_t)d*VT_LD + m0 + c*8, ldsVb + (u-8)*512);
        }
    }
}

__device__ __forceinline__ float max16(const f32x4* s)
{
    float t0 = fmaxf(fmaxf(s[0][0], s[0][1]), fmaxf(s[0][2], s[0][3]));
    float t1 = fmaxf(fmaxf(s[1][0], s[1][1]), fmaxf(s[1][2], s[1][3]));
    float t2 = fmaxf(fmaxf(s[2][0], s[2][1]), fmaxf(s[2][2], s[2][3]));
    float t3 = fmaxf(fmaxf(s[3][0], s[3][1]), fmaxf(s[3][2], s[3][3]));
    return fmaxf(fmaxf(t0, t1), fmaxf(t2, t3));
}

__device__ __forceinline__ void compute_tile64(
    const f16* ldsKb, const f16* ldsVb,
    const f16x8& qf0, const f16x4& qfh,
    float& mrun, float& lrun, f32x4& o0, f32x4& o1, f32x4& o2,
    int lrow, int g, bool first, bool tail)
{
    const char* kP = (const char*)ldsKb;
    const char* vP = (const char*)ldsVb;
    f32x4 z = {0.f,0.f,0.f,0.f};
    int sw = lrow & 7;
    int cA = (g ^ sw) << 4;                                  // d 0..31 (16B)
    int cH = (((4 + (g >> 1)) ^ sw) << 4) + ((g & 1) << 3);  // d 32..47 (8B)

    f32x4 s[4];
    __builtin_amdgcn_s_setprio(1);
    #pragma unroll
    for (int j = 0; j < 4; ++j) {
        const char* rb = kP + (16*j + lrow)*128;
        f32x4 t = MFMA16(*(const f16x8*)(rb + cA), qf0, z);
        s[j] = MFMAK16(*(const f16x4*)(rb + cH), qfh, t);
    }
    __builtin_amdgcn_s_setprio(0);

    if (tail) {   // keys >= 784 live in blocks 1..3 of tile 12
        f32x4 neg = {-1e30f,-1e30f,-1e30f,-1e30f};
        s[1] = neg; s[2] = neg; s[3] = neg;
    }

    u32 pk[8];
    float tl = max16(s);
    bool fast = false;
    if (!first) fast = (__all(tl <= mrun + 8.0f) != 0);

    if (fast) {
        // defer-max: keep mrun; P = exp2(s - mrun) <= 2^8, no O rescale
        float psum = 0.f;
        #pragma unroll
        for (int j = 0; j < 4; ++j) {
            #pragma unroll
            for (int r = 0; r < 4; ++r) {
                s[j][r] = exp2f(s[j][r] - mrun);
                psum += s[j][r];
            }
        }
        lrun += psum;     // per-lane partial; reduced at epilogue
        #pragma unroll
        for (int j = 0; j < 4; ++j) {
            pk[j*2]   = pkrtz(s[j][0], s[j][1]);
            pk[j*2+1] = pkrtz(s[j][2], s[j][3]);
        }
    } else {
        float tmax = tl;
        tmax = fmaxf(tmax, __shfl_xor(tmax, 16));
        tmax = fmaxf(tmax, __shfl_xor(tmax, 32));
        float mnew = fmaxf(mrun, tmax);
        float corr = exp2f(mrun - mnew);
        mrun = mnew;
        float psum = 0.f;
        #pragma unroll
        for (int j = 0; j < 4; ++j) {
            #pragma unroll
            for (int r = 0; r < 4; ++r) {
                s[j][r] = exp2f(s[j][r] - mnew);
                psum += s[j][r];
            }
        }
        lrun = lrun*corr + psum;
        #pragma unroll
        for (int j = 0; j < 4; ++j) {
            pk[j*2]   = pkrtz(s[j][0], s[j][1]);
            pk[j*2+1] = pkrtz(s[j][2], s[j][3]);
        }
        #pragma unroll
        for (int r = 0; r < 4; ++r) {
            o0[r] *= corr; o1[r] *= corr; o2[r] *= corr;
        }
    }

    // PV: per 16-key chunk, B-frag is lane-local {pk[2ch],pk[2ch+1]};
    // A-frag = Vt[d=16*db+lrow][m0+16ch+g*4 .. +3] (8B swizzled LDS read).
    #pragma unroll
    for (int ch = 0; ch < 4; ++ch) {
        u32x2 pw = { pk[2*ch], pk[2*ch+1] };
        f16x4 pb = __builtin_bit_cast(f16x4, pw);
        int off = (((2*ch + (g >> 1)) ^ sw) << 4) + ((g & 1) << 3);
        f16x4 v0 = *(const f16x4*)(vP + lrow*128      + off);
        f16x4 v1 = *(const f16x4*)(vP + (16+lrow)*128 + off);
        f16x4 v2 = *(const f16x4*)(vP + (32+lrow)*128 + off);
        __builtin_amdgcn_s_setprio(1);
        o0 = MFMAK16(v0, pb, o0);
        o1 = MFMAK16(v1, pb, o1);
        o2 = MFMAK16(v2, pb, o2);
        __builtin_amdgcn_s_setprio(0);
    }
}

__global__ __launch_bounds__(256, 2) void attn_mfma(
    const f16* __restrict__ uq, const f16* __restrict__ Mq,
    const float* __restrict__ bq,
    const f16* __restrict__ kb, const f16* __restrict__ vt,
    float* __restrict__ out)
{
    // flat LDS: K0 | K1 | V0 | V1 ; qL aliases K1 (dead after prologue,
    // first overwritten when tile 1 stages inside the loop)
    __shared__ __align__(16) f16 lds[2*4096 + 2*3072];   // 28672 B
    f16* ldsK0 = lds;
    f16* ldsK1 = lds + 4096;
    f16* ldsV0 = lds + 8192;
    f16* ldsV1 = lds + 8192 + 3072;
    f16* qL    = ldsK1;                  // 4 waves x 896 f16 = 3584 <= 4096

    int tid  = threadIdx.x;
    int w    = tid >> 6, l = tid & 63;
    int lrow = l & 15,  g = l >> 4;
    // XCD swizzle: 1568 = 8*196; 4 (b,h) groups per XCD -> KV L2-resident.
    int swz  = (blockIdx.x & 7)*196 + (blockIdx.x >> 3);
    int bh   = swz / 49, qblk = swz % 49;
    int h    = bh & 3, b = bh >> 2;
    int n0   = qblk*64 + w*16;

    const f16* kbb = kb + (size_t)b*MM*C_ + h*HD;
    const f16* vbb = vt + ((size_t)b*C_ + h*HD)*VT_LD;

    // ---- fused Q projection (u-frags head the dependency chain) ----
    const f16* urow = uq + ((size_t)b*NN + n0 + lrow)*C_;
    f16x8 ufr[6];
    #pragma unroll
    for (int ch = 0; ch < 6; ++ch)
        ufr[ch] = *(const f16x8*)(urow + ch*32 + g*8);
    {
        const float qsc = 0.14433756729740643f * 1.4426950408889634f;
        f16* qw = qL + w*896;
        #pragma unroll
        for (int dt = 0; dt < 3; ++dt) {
            const f16* mrow = Mq + (size_t)(h*HD + dt*16 + lrow)*C_;
            f32x4 acc = {0.f,0.f,0.f,0.f};
            #pragma unroll
            for (int ch = 0; ch < 6; ++ch)
                acc = MFMA16(*(const f16x8*)(mrow + ch*32 + g*8), ufr[ch], acc);
            float4 bo = *(const float4*)(bq + h*HD + dt*16 + g*4);
            f16x4 st;
            st[0] = (f16)((acc[0] + bo.x)*qsc);
            st[1] = (f16)((acc[1] + bo.y)*qsc);
            st[2] = (f16)((acc[2] + bo.z)*qsc);
            st[3] = (f16)((acc[3] + bo.w)*qsc);
            *(f16x4*)(qw + lrow*56 + dt*16 + g*4) = st;   // n=lrow, d=dt*16+g*4+r
        }
    }
    // read own slice (asm forces the lgkm wait), then barrier so no wave
    // stages tile 1 (into ldsK1) before all waves finished reading qL
    f16x8 qf0 = *(const f16x8*)(qL + w*896 + lrow*56 + g*8);
    f16x4 qfh = *(const f16x4*)(qL + w*896 + lrow*56 + 32 + g*4);
    asm volatile("" :: "v"(qf0), "v"(qfh));
    __builtin_amdgcn_s_barrier();

    // stage tile 0 (latency covered by the t=0 vmcnt wait)
    stage_tile(w, l, ldsK0, ldsV0, kbb, vbb, 0);

    float mrun = -1e30f, lrun = 0.f;
    f32x4 o0 = {0.f,0.f,0.f,0.f}, o1 = o0, o2 = o0;

    for (int t = 0; t < 13; ++t) {
        int nb = t & 1;
        if (t < 12)
            stage_tile(w, l, nb ? ldsK0 : ldsK1, nb ? ldsV0 : ldsV1,
                       kbb, vbb, (t+1)*64);
        __builtin_amdgcn_sched_barrier(0);
        if (t < 12) {
            if (w < 2) asm volatile("s_waitcnt vmcnt(4)" ::: "memory");
            else       asm volatile("s_waitcnt vmcnt(3)" ::: "memory");
        } else {
            asm volatile("s_waitcnt vmcnt(0)" ::: "memory");
        }
        __builtin_amdgcn_s_barrier();
        __builtin_amdgcn_sched_barrier(0);
        compute_tile64(nb ? ldsK1 : ldsK0, nb ? ldsV1 : ldsV0, qf0, qfh,
                       mrun, lrun, o0, o1, o2, lrow, g, t == 0, t == 12);
        __builtin_amdgcn_sched_barrier(0);
        __builtin_amdgcn_s_barrier();
    }

    // epilogue: reduce per-lane partial lrun across the 4 lanes of this query
    lrun += __shfl_xor(lrun, 16);
    lrun += __shfl_xor(lrun, 32);
    float inv = 1.f / lrun;
    f32x4 r0, r1, r2;
    #pragma unroll
    for (int r = 0; r < 4; ++r) {
        r0[r] = o0[r]*inv; r1[r] = o1[r]*inv; r2[r] = o2[r]*inv;
    }
    float* obase = out + ((size_t)b*NN + n0 + lrow)*C_ + h*HD + g*4;
    *(f32x4*)(obase)      = r0;
    *(f32x4*)(obase + 16) = r1;
    *(f32x4*)(obase + 32) = r2;
}

// ---------------------------------------------------------------------------
extern "C" void kernel_launch(void* const* d_in, const int* in_sizes, int n_in,
                              void* d_out, int out_size, void* d_ws, size_t ws_size,
                              hipStream_t stream)
{
    const float* x     = (const float*)d_in[0];
    const float* dw_q  = (const float*)d_in[3];
    const float* bnqg  = (const float*)d_in[4];
    const float* bnqb  = (const float*)d_in[5];
    const float* bnqm  = (const float*)d_in[6];
    const float* bnqv  = (const float*)d_in[7];
    const float* pw_q  = (const float*)d_in[8];
    const float* dw_kv = (const float*)d_in[9];
    const float* bnkg  = (const float*)d_in[10];
    const float* bnkb  = (const float*)d_in[11];
    const float* bnkm  = (const float*)d_in[12];
    const float* bnkvv = (const float*)d_in[13];
    const float* pw_kv = (const float*)d_in[14];
    const float* Wq    = (const float*)d_in[15];
    const float* bq    = (const float*)d_in[16];
    const float* Wk    = (const float*)d_in[17];
    const float* bk    = (const float*)d_in[18];
    const float* Wv    = (const float*)d_in[19];
    const float* bv    = (const float*)d_in[20];
    float* out = (float*)d_out;

    f16* p   = (f16*)d_ws;
    f16* Mq16  = p;  p += C_*C_;
    f16* Mk16  = p;  p += C_*C_;
    f16* Mv16  = p;  p += C_*C_;
    f16* uq16  = p;  p += (size_t)BB*NN*C_ + 256;    // pad: frag tail reads
    f16* ukv16 = p;  p += (size_t)BB*MM*C_;
    f16* kb16  = p;  p += (size_t)BB*MM*C_ + 16384;  // pad: tail-tile staging overread
    f16* vt16  = p;  p += (size_t)BB*C_*VT_LD;

    prep_all<<<1746, 256, 0, stream>>>(
        x, dw_q, bnqg, bnqb, bnqm, bnqv,
        dw_kv, bnkg, bnkb, bnkm, bnkvv,
        Wq, Wk, Wv, pw_q, pw_kv,
        uq16, ukv16, Mq16, Mk16, Mv16, vt16);

    proj_kv<<<2*KVPB, 128, 0, stream>>>(
        ukv16, Mk16, Mv16, bk, bv, kb16, vt16);

    attn_mfma<<<1568, 256, 0, stream>>>(uq16, Mq16, bq, kb16, vt16, out);
}

// Round 23
// 95.025 us; speedup vs baseline: 1.2772x; 1.0003x over previous
//
#include <hip/hip_runtime.h>
#include <cmath>

typedef _Float16 f16;
typedef _Float16 f16x8 __attribute__((ext_vector_type(8)));
typedef _Float16 f16x4 __attribute__((ext_vector_type(4)));
typedef float    f32x4 __attribute__((ext_vector_type(4)));
typedef unsigned int u32;
typedef u32 u32x2 __attribute__((ext_vector_type(2)));

#define C_   192
#define HH   56
#define WW   56
#define NN   3136
#define BB   8
#define MM   784
#define NHEAD 4
#define HD   48
#define VT_LD 832            // padded key-dim of transposed V (784 + 48)
#define KVPB (BB*MM/32)      // 196 proj blocks per K / V path

#define MFMA16(a,b,c)  __builtin_amdgcn_mfma_f32_16x16x32_f16(a,b,c,0,0,0)
#define MFMAK16(a,b,c) __builtin_amdgcn_mfma_f32_16x16x16f16(a,b,c,0,0,0)

static __device__ __forceinline__ u32 pkrtz(float a, float b) {
    typedef __fp16 fp16x2 __attribute__((ext_vector_type(2)));
    fp16x2 h = __builtin_amdgcn_cvt_pkrtz(a, b);
    return __builtin_bit_cast(u32, h);
}

// async global->LDS, 16B per lane; LDS dst = wave-uniform base + lane*16
static __device__ __forceinline__ void gload16(const void* g, void* l) {
    __builtin_amdgcn_global_load_lds(
        (const __attribute__((address_space(1))) unsigned int*)g,
        (__attribute__((address_space(3))) unsigned int*)l, 16, 0, 0);
}

// ---------------------------------------------------------------------------
// Depthwise 3x3 + BN (stride 1), EIGHT outputs per thread (2x4 octet sharing
// a 4x6 window union): 24 loads / 8 outputs = 3/output. Weights from LDS.
__device__ __forceinline__ void dwbn_oct(
    const float* __restrict__ x, const float* __restrict__ dwL,
    const float* __restrict__ gamma, const float* __restrict__ beta,
    const float* __restrict__ mean,  const float* __restrict__ var,
    f16* __restrict__ out, int idx)
{
    int c4 = idx % 48;
    int r1 = idx / 48;
    int qx = r1 % (WW/4);
    int r2 = r1 / (WW/4);
    int qp = r2 % (HH/2);
    int b  = r2 / (HH/2);
    int c0 = c4*4;

    float4 w4[9];
    #pragma unroll
    for (int j = 0; j < 9; ++j)
        w4[j] = *(const float4*)&dwL[c4*40 + j*4];
    const float* wf = (const float*)w4;   // wf[cc*9 + wi], static indices

    float4 g4  = *(const float4*)(gamma + c0);
    float4 be4 = *(const float4*)(beta + c0);
    float4 m4  = *(const float4*)(mean + c0);
    float4 v4  = *(const float4*)(var  + c0);

    float4 acc[2][4];
    #pragma unroll
    for (int jj = 0; jj < 2; ++jj)
        #pragma unroll
        for (int ii = 0; ii < 4; ++ii)
            acc[jj][ii] = make_float4(0.f,0.f,0.f,0.f);

    int iyTop = 2*qp - 1;
    int ix0   = 4*qx - 1;
    #pragma unroll
    for (int j = 0; j < 4; ++j) {
        int iy = iyTop + j;
        if (iy < 0 || iy >= HH) continue;
        #pragma unroll
        for (int i = 0; i < 6; ++i) {
            int ix = ix0 + i;
            if (ix < 0 || ix >= WW) continue;
            float4 xv = *reinterpret_cast<const float4*>(
                x + ((size_t)b*NN + iy*WW + ix)*C_ + c0);
            #pragma unroll
            for (int jj = 0; jj < 2; ++jj) {
                if (j < jj || j > jj+2) continue;
                #pragma unroll
                for (int ii = 0; ii < 4; ++ii) {
                    if (i < ii || i > ii+2) continue;
                    const int wi = (j-jj)*3 + (i-ii);
                    acc[jj][ii].x = fmaf(wf[ 0+wi], xv.x, acc[jj][ii].x);
                    acc[jj][ii].y = fmaf(wf[ 9+wi], xv.y, acc[jj][ii].y);
                    acc[jj][ii].z = fmaf(wf[18+wi], xv.z, acc[jj][ii].z);
                    acc[jj][ii].w = fmaf(wf[27+wi], xv.w, acc[jj][ii].w);
                }
            }
        }
    }
    float i0 = g4.x*__frsqrt_rn(v4.x + 1e-5f);
    float i1 = g4.y*__frsqrt_rn(v4.y + 1e-5f);
    float i2 = g4.z*__frsqrt_rn(v4.z + 1e-5f);
    float i3 = g4.w*__frsqrt_rn(v4.w + 1e-5f);
    float b0 = be4.x - m4.x*i0, b1 = be4.y - m4.y*i1;
    float b2 = be4.z - m4.z*i2, b3 = be4.w - m4.w*i3;
    #pragma unroll
    for (int jj = 0; jj < 2; ++jj) {
        #pragma unroll
        for (int ii = 0; ii < 4; ++ii) {
            f16x4 r;
            r[0] = (f16)(acc[jj][ii].x*i0 + b0);
            r[1] = (f16)(acc[jj][ii].y*i1 + b1);
            r[2] = (f16)(acc[jj][ii].z*i2 + b2);
            r[3] = (f16)(acc[jj][ii].w*i3 + b3);
            size_t o = (((size_t)b*HH + 2*qp + jj)*WW + 4*qx + ii)*48 + c4;
            *reinterpret_cast<f16x4*>(out + o*4) = r;
        }
    }
}

// ---------------------------------------------------------------------------
// Depthwise 3x3 + BN stride 2, FOUR outputs per thread (2x2 quad, 5x5 window).
__device__ __forceinline__ void dwbn_quad2(
    const float* __restrict__ x, const float* __restrict__ dwL,
    const float* __restrict__ gamma, const float* __restrict__ beta,
    const float* __restrict__ mean,  const float* __restrict__ var,
    f16* __restrict__ out, int idx)
{
    const int OH = 28, OW = 28, STRIDE = 2;
    int c4 = idx % 48;
    int r1 = idx / 48;
    int qx = r1 % (OW/2);
    int r2 = r1 / (OW/2);
    int qp = r2 % (OH/2);
    int b  = r2 / (OH/2);
    int c0 = c4*4;

    float4 w4[9];
    #pragma unroll
    for (int j = 0; j < 9; ++j)
        w4[j] = *(const float4*)&dwL[c4*40 + j*4];
    const float* wf = (const float*)w4;

    float4 g4  = *(const float4*)(gamma + c0);
    float4 be4 = *(const float4*)(beta + c0);
    float4 m4  = *(const float4*)(mean + c0);
    float4 v4  = *(const float4*)(var  + c0);

    float4 a00 = make_float4(0.f,0.f,0.f,0.f);
    float4 a01 = a00, a10 = a00, a11 = a00;
    int iyTop = (2*qp)*STRIDE - 1;
    int ix0   = (2*qx)*STRIDE - 1;
    #pragma unroll
    for (int j = 0; j < STRIDE+3; ++j) {
        int iy = iyTop + j;
        if (iy < 0 || iy >= HH) continue;
        #pragma unroll
        for (int i = 0; i < STRIDE+3; ++i) {
            int ix = ix0 + i;
            if (ix < 0 || ix >= WW) continue;
            float4 xv = *reinterpret_cast<const float4*>(
                x + ((size_t)b*NN + iy*WW + ix)*C_ + c0);
            const bool r0ok = (j <= 2), r1ok = (j >= STRIDE);
            const bool c0ok = (i <= 2), c1ok = (i >= STRIDE);
            if (r0ok && c0ok) { const int wi = j*3 + i;
                a00.x = fmaf(wf[ 0+wi], xv.x, a00.x);
                a00.y = fmaf(wf[ 9+wi], xv.y, a00.y);
                a00.z = fmaf(wf[18+wi], xv.z, a00.z);
                a00.w = fmaf(wf[27+wi], xv.w, a00.w); }
            if (r0ok && c1ok) { const int wi = j*3 + (i-STRIDE);
                a01.x = fmaf(wf[ 0+wi], xv.x, a01.x);
                a01.y = fmaf(wf[ 9+wi], xv.y, a01.y);
                a01.z = fmaf(wf[18+wi], xv.z, a01.z);
                a01.w = fmaf(wf[27+wi], xv.w, a01.w); }
            if (r1ok && c0ok) { const int wi = (j-STRIDE)*3 + i;
                a10.x = fmaf(wf[ 0+wi], xv.x, a10.x);
                a10.y = fmaf(wf[ 9+wi], xv.y, a10.y);
                a10.z = fmaf(wf[18+wi], xv.z, a10.z);
                a10.w = fmaf(wf[27+wi], xv.w, a10.w); }
            if (r1ok && c1ok) { const int wi = (j-STRIDE)*3 + (i-STRIDE);
                a11.x = fmaf(wf[ 0+wi], xv.x, a11.x);
                a11.y = fmaf(wf[ 9+wi], xv.y, a11.y);
                a11.z = fmaf(wf[18+wi], xv.z, a11.z);
                a11.w = fmaf(wf[27+wi], xv.w, a11.w); }
        }
    }
    float i0 = g4.x*__frsqrt_rn(v4.x + 1e-5f);
    float i1 = g4.y*__frsqrt_rn(v4.y + 1e-5f);
    float i2 = g4.z*__frsqrt_rn(v4.z + 1e-5f);
    float i3 = g4.w*__frsqrt_rn(v4.w + 1e-5f);
    float b0 = be4.x - m4.x*i0, b1 = be4.y - m4.y*i1;
    float b2 = be4.z - m4.z*i2, b3 = be4.w - m4.w*i3;
    size_t base = (((size_t)b*OH + 2*qp)*OW + 2*qx)*48 + c4;
    f16x4 r;
    r[0]=(f16)(a00.x*i0+b0); r[1]=(f16)(a00.y*i1+b1);
    r[2]=(f16)(a00.z*i2+b2); r[3]=(f16)(a00.w*i3+b3);
    *reinterpret_cast<f16x4*>(out + base*4) = r;
    r[0]=(f16)(a01.x*i0+b0); r[1]=(f16)(a01.y*i1+b1);
    r[2]=(f16)(a01.z*i2+b2); r[3]=(f16)(a01.w*i3+b3);
    *reinterpret_cast<f16x4*>(out + (base + 48)*4) = r;
    r[0]=(f16)(a10.x*i0+b0); r[1]=(f16)(a10.y*i1+b1);
    r[2]=(f16)(a10.z*i2+b2); r[3]=(f16)(a10.w*i3+b3);
    *reinterpret_cast<f16x4*>(out + (base + (size_t)OW*48)*4) = r;
    r[0]=(f16)(a11.x*i0+b0); r[1]=(f16)(a11.y*i1+b1);
    r[2]=(f16)(a11.z*i2+b2); r[3]=(f16)(a11.w*i3+b3);
    *reinterpret_cast<f16x4*>(out + (base + (size_t)OW*48 + 48)*4) = r;
}

// ---------------------------------------------------------------------------
// Fused prep: dwbn (oct Q, quad KV) + pointwise-fold + Vt pad zero.
__global__ __launch_bounds__(256) void prep_all(
    const float* __restrict__ x,
    const float* __restrict__ dwq,  const float* __restrict__ gq,
    const float* __restrict__ bq_,  const float* __restrict__ mq,
    const float* __restrict__ vq,
    const float* __restrict__ dwkv, const float* __restrict__ gkv,
    const float* __restrict__ bkv,  const float* __restrict__ mkv,
    const float* __restrict__ vkv,
    const float* __restrict__ Wq, const float* __restrict__ Wk,
    const float* __restrict__ Wv, const float* __restrict__ pw_q,
    const float* __restrict__ pw_kv,
    f16* __restrict__ uq, f16* __restrict__ ukv,
    f16* __restrict__ Mq, f16* __restrict__ Mk, f16* __restrict__ Mv,
    f16* __restrict__ vt)
{
    int blk = blockIdx.x, tid = threadIdx.x;
    const int QB = 588, KB = 294;
    if (blk < QB + KB) {
        bool qp = blk < QB;
        __shared__ __align__(16) float dwL[48*40];
        const float* dwg = qp ? dwq : dwkv;
        for (int i = tid; i < 432; i += 256) {
            int f  = i*4;
            int c4 = f/36, r = f%36;
            *(float4*)&dwL[c4*40 + r] = *(const float4*)(dwg + f);
        }
        __syncthreads();
        if (qp)
            dwbn_oct(x, dwL, gq, bq_, mq, vq, uq, blk*256 + tid);
        else
            dwbn_quad2(x, dwL, gkv, bkv, mkv, vkv, ukv, (blk - QB)*256 + tid);
    } else if (blk < QB + KB + 576) {
        int fb = blk - QB - KB;
        int which = fb / 192, o = fb % 192;
        const float* Wm = which == 0 ? Wq : (which == 1 ? Wk : Wv);
        const float* P  = which == 0 ? pw_q : (which == 1 ? pw_kv : pw_kv + C_*C_);
        f16* Mo         = which == 0 ? Mq : (which == 1 ? Mk : Mv);
        __shared__ float wrow[C_];
        if (tid < C_) wrow[tid] = Wm[o*C_ + tid];
        __syncthreads();
        if (tid < C_) {
            float acc = 0.f;
            #pragma unroll 8
            for (int j = 0; j < C_; ++j)
                acc = fmaf(wrow[j], P[j*C_ + tid], acc);
            Mo[o*C_ + tid] = (f16)acc;
        }
    } else {
        int i = (blk - QB - KB - 576)*256 + tid;   // BB*C_*48 = 73728 exactly
        int b = i / (C_*48);
        int rem = i % (C_*48);
        int c = rem / 48;
        int m = MM + (rem % 48);
        vt[((size_t)b*C_ + c)*VT_LD + m] = (f16)0.f;
    }
}

// ---------------------------------------------------------------------------
// K/V projections only (Q is fused into attn). 128-thread blocks, 32 rows.
__global__ __launch_bounds__(128, 1) void proj_kv(
    const f16* __restrict__ ukv,
    const f16* __restrict__ Mk, const f16* __restrict__ Mv,
    const float* __restrict__ bk, const float* __restrict__ bv,
    f16* __restrict__ kb, f16* __restrict__ vt)
{
    int tid  = threadIdx.x;
    int w    = tid >> 6, l = tid & 63;
    int lrow = l & 15,  lgrp = l >> 4;
    int blk  = blockIdx.x;
    int path = blk < KVPB ? 1 : 2;
    int rblk = path == 1 ? blk : blk - KVPB;
    int r0 = rblk*32 + w*16;

    const f16* urow = ukv + (size_t)(r0 + lrow)*C_;
    f16x8 a[6];
    #pragma unroll
    for (int ch = 0; ch < 6; ++ch)
        a[ch] = *(const f16x8*)(urow + ch*32 + lgrp*8);

    f16x8 bfA[6], bfB[6];
    const f16* Mm = path == 1 ? Mk : Mv;

    #pragma unroll
    for (int ch = 0; ch < 6; ++ch)
        bfA[ch] = *(const f16x8*)(Mm + (size_t)lrow*C_ + ch*32 + lgrp*8);

    if (path == 1) {
        #pragma unroll
        for (int ct = 0; ct < 12; ++ct) {            // K projection (swapped)
            f16x8* cur = (ct & 1) ? bfB : bfA;
            f16x8* nxt = (ct & 1) ? bfA : bfB;
            if (ct < 11) {
                const f16* mrow = Mm + (size_t)((ct+1)*16 + lrow)*C_;
                #pragma unroll
                for (int ch = 0; ch < 6; ++ch)
                    nxt[ch] = *(const f16x8*)(mrow + ch*32 + lgrp*8);
            }
            f32x4 acc = {0.f,0.f,0.f,0.f};
            #pragma unroll
            for (int ch = 0; ch < 6; ++ch)
                acc = MFMA16(cur[ch], a[ch], acc);
            float4 bo = *(const float4*)(bk + ct*16 + lgrp*4);
            f16x4 st;
            st[0] = (f16)(acc[0] + bo.x);
            st[1] = (f16)(acc[1] + bo.y);
            st[2] = (f16)(acc[2] + bo.z);
            st[3] = (f16)(acc[3] + bo.w);
            *(f16x4*)(kb + (size_t)(r0 + lrow)*C_ + ct*16 + lgrp*4) = st;
        }
    } else {
        #pragma unroll
        for (int ct = 0; ct < 12; ++ct) {            // V projection (transposed)
            f16x8* cur = (ct & 1) ? bfB : bfA;
            f16x8* nxt = (ct & 1) ? bfA : bfB;
            if (ct < 11) {
                const f16* mrow = Mv + (size_t)((ct+1)*16 + lrow)*C_;
                #pragma unroll
                for (int ch = 0; ch < 6; ++ch)
                    nxt[ch] = *(const f16x8*)(mrow + ch*32 + lgrp*8);
            }
            int o = ct*16 + lrow;
            f32x4 acc = {0.f,0.f,0.f,0.f};
            #pragma unroll
            for (int ch = 0; ch < 6; ++ch)
                acc = MFMA16(a[ch], cur[ch], acc);
            float bo = bv[o];
            int rg = r0 + lgrp*4;
            int b  = rg / MM, m = rg % MM;            // 784 % 16 == 0
            f16x4 st;
            st[0] = (f16)(acc[0] + bo);
            st[1] = (f16)(acc[1] + bo);
            st[2] = (f16)(acc[2] + bo);
            st[3] = (f16)(acc[3] + bo);
            *(f16x4*)(vt + ((size_t)b*C_ + o)*VT_LD + m) = st;
        }
    }
}

// ---------------------------------------------------------------------------
// Flash attention (R20, known-good): fused Q-proj prologue with qL aliased
// onto ldsK[1] (28672 B LDS -> 5 blocks/CU), defer-max fast path (THR=8),
// lane-local P PV (K=16 MFMA), counted vmcnt, raw s_barrier, XOR swizzle.
__device__ __forceinline__ void stage_tile(
    int w, int l, f16* ldsKb, f16* ldsVb,
    const f16* __restrict__ kbb, const f16* __restrict__ vbb, int m0)
{
    int rr = l >> 3, p = l & 7;
    #pragma unroll
    for (int j = 0; j < 4; ++j) {
        int u = w + j*4;
        if (u < 8) {                      // K rows 8u..8u+7
            int r = u*8 + rr;
            int c = p ^ (r & 7);
            gload16(kbb + (size_t)(m0 + r)*C_ + c*8, ldsKb + u*512);
        } else if (u < 14) {              // V rows (d) 8(u-8)..+7
            int d = (u-8)*8 + rr;
            int c = p ^ (d & 7);
            gload16(vbb + (size_t)d*VT_LD + m0 + c*8, ldsVb + (u-8)*512);
        }
    }
}

__device__ __forceinline__ float max16(const f32x4* s)
{
    float t0 = fmaxf(fmaxf(s[0][0], s[0][1]), fmaxf(s[0][2], s[0][3]));
    float t1 = fmaxf(fmaxf(s[1][0], s[1][1]), fmaxf(s[1][2], s[1][3]));
    float t2 = fmaxf(fmaxf(s[2][0], s[2][1]), fmaxf(s[2][2], s[2][3]));
    float t3 = fmaxf(fmaxf(s[3][0], s[3][1]), fmaxf(s[3][2], s[3][3]));
    return fmaxf(fmaxf(t0, t1), fmaxf(t2, t3));
}

__device__ __forceinline__ void compute_tile64(
    const f16* ldsKb, const f16* ldsVb,
    const f16x8& qf0, const f16x4& qfh,
    float& mrun, float& lrun, f32x4& o0, f32x4& o1, f32x4& o2,
    int lrow, int g, bool first, bool tail)
{
    const char* kP = (const char*)ldsKb;
    const char* vP = (const char*)ldsVb;
    f32x4 z = {0.f,0.f,0.f,0.f};
    int sw = lrow & 7;
    int cA = (g ^ sw) << 4;                                  // d 0..31 (16B)
    int cH = (((4 + (g >> 1)) ^ sw) << 4) + ((g & 1) << 3);  // d 32..47 (8B)

    f32x4 s[4];
    __builtin_amdgcn_s_setprio(1);
    #pragma unroll
    for (int j = 0; j < 4; ++j) {
        const char* rb = kP + (16*j + lrow)*128;
        f32x4 t = MFMA16(*(const f16x8*)(rb + cA), qf0, z);
        s[j] = MFMAK16(*(const f16x4*)(rb + cH), qfh, t);
    }
    __builtin_amdgcn_s_setprio(0);

    if (tail) {   // keys >= 784 live in blocks 1..3 of tile 12
        f32x4 neg = {-1e30f,-1e30f,-1e30f,-1e30f};
        s[1] = neg; s[2] = neg; s[3] = neg;
    }

    u32 pk[8];
    float tl = max16(s);
    bool fast = false;
    if (!first) fast = (__all(tl <= mrun + 8.0f) != 0);

    if (fast) {
        // defer-max: keep mrun; P = exp2(s - mrun) <= 2^8, no O rescale
        float psum = 0.f;
        #pragma unroll
        for (int j = 0; j < 4; ++j) {
            #pragma unroll
            for (int r = 0; r < 4; ++r) {
                s[j][r] = exp2f(s[j][r] - mrun);
                psum += s[j][r];
            }
        }
        lrun += psum;     // per-lane partial; reduced at epilogue
        #pragma unroll
        for (int j = 0; j < 4; ++j) {
            pk[j*2]   = pkrtz(s[j][0], s[j][1]);
            pk[j*2+1] = pkrtz(s[j][2], s[j][3]);
        }
    } else {
        float tmax = tl;
        tmax = fmaxf(tmax, __shfl_xor(tmax, 16));
        tmax = fmaxf(tmax, __shfl_xor(tmax, 32));
        float mnew = fmaxf(mrun, tmax);
        float corr = exp2f(mrun - mnew);
        mrun = mnew;
        float psum = 0.f;
        #pragma unroll
        for (int j = 0; j < 4; ++j) {
            #pragma unroll
            for (int r = 0; r < 4; ++r) {
                s[j][r] = exp2f(s[j][r] - mnew);
                psum += s[j][r];
            }
        }
        lrun = lrun*corr + psum;
        #pragma unroll
        for (int j = 0; j < 4; ++j) {
            pk[j*2]   = pkrtz(s[j][0], s[j][1]);
            pk[j*2+1] = pkrtz(s[j][2], s[j][3]);
        }
        #pragma unroll
        for (int r = 0; r < 4; ++r) {
            o0[r] *= corr; o1[r] *= corr; o2[r] *= corr;
        }
    }

    // PV: per 16-key chunk, B-frag is lane-local {pk[2ch],pk[2ch+1]};
    // A-frag = Vt[d=16*db+lrow][m0+16ch+g*4 .. +3] (8B swizzled LDS read).
    #pragma unroll
    for (int ch = 0; ch < 4; ++ch) {
        u32x2 pw = { pk[2*ch], pk[2*ch+1] };
        f16x4 pb = __builtin_bit_cast(f16x4, pw);
        int off = (((2*ch + (g >> 1)) ^ sw) << 4) + ((g & 1) << 3);
        f16x4 v0 = *(const f16x4*)(vP + lrow*128      + off);
        f16x4 v1 = *(const f16x4*)(vP + (16+lrow)*128 + off);
        f16x4 v2 = *(const f16x4*)(vP + (32+lrow)*128 + off);
        __builtin_amdgcn_s_setprio(1);
        o0 = MFMAK16(v0, pb, o0);
        o1 = MFMAK16(v1, pb, o1);
        o2 = MFMAK16(v2, pb, o2);
        __builtin_amdgcn_s_setprio(0);
    }
}

__global__ __launch_bounds__(256, 2) void attn_mfma(
    const f16* __restrict__ uq, const f16* __restrict__ Mq,
    const float* __restrict__ bq,
    const f16* __restrict__ kb, const f16* __restrict__ vt,
    float* __restrict__ out)
{
    // flat LDS: K0 | K1 | V0 | V1 ; qL aliases K1 (dead after prologue,
    // first overwritten when tile 1 stages inside the loop)
    __shared__ __align__(16) f16 lds[2*4096 + 2*3072];   // 28672 B
    f16* ldsK0 = lds;
    f16* ldsK1 = lds + 4096;
    f16* ldsV0 = lds + 8192;
    f16* ldsV1 = lds + 8192 + 3072;
    f16* qL    = ldsK1;                  // 4 waves x 896 f16 = 3584 <= 4096

    int tid  = threadIdx.x;
    int w    = tid >> 6, l = tid & 63;
    int lrow = l & 15,  g = l >> 4;
    // XCD swizzle: 1568 = 8*196; 4 (b,h) groups per XCD -> KV L2-resident.
    int swz  = (blockIdx.x & 7)*196 + (blockIdx.x >> 3);
    int bh   = swz / 49, qblk = swz % 49;
    int h    = bh & 3, b = bh >> 2;
    int n0   = qblk*64 + w*16;

    const f16* kbb = kb + (size_t)b*MM*C_ + h*HD;
    const f16* vbb = vt + ((size_t)b*C_ + h*HD)*VT_LD;

    // ---- fused Q projection (u-frags head the dependency chain) ----
    const f16* urow = uq + ((size_t)b*NN + n0 + lrow)*C_;
    f16x8 ufr[6];
    #pragma unroll
    for (int ch = 0; ch < 6; ++ch)
        ufr[ch] = *(const f16x8*)(urow + ch*32 + g*8);
    {
        const float qsc = 0.14433756729740643f * 1.4426950408889634f;
        f16* qw = qL + w*896;
        #pragma unroll
        for (int dt = 0; dt < 3; ++dt) {
            const f16* mrow = Mq + (size_t)(h*HD + dt*16 + lrow)*C_;
            f32x4 acc = {0.f,0.f,0.f,0.f};
            #pragma unroll
            for (int ch = 0; ch < 6; ++ch)
                acc = MFMA16(*(const f16x8*)(mrow + ch*32 + g*8), ufr[ch], acc);
            float4 bo = *(const float4*)(bq + h*HD + dt*16 + g*4);
            f16x4 st;
            st[0] = (f16)((acc[0] + bo.x)*qsc);
            st[1] = (f16)((acc[1] + bo.y)*qsc);
            st[2] = (f16)((acc[2] + bo.z)*qsc);
            st[3] = (f16)((acc[3] + bo.w)*qsc);
            *(f16x4*)(qw + lrow*56 + dt*16 + g*4) = st;   // n=lrow, d=dt*16+g*4+r
        }
    }
    // read own slice (asm forces the lgkm wait), then barrier so no wave
    // stages tile 1 (into ldsK1) before all waves finished reading qL
    f16x8 qf0 = *(const f16x8*)(qL + w*896 + lrow*56 + g*8);
    f16x4 qfh = *(const f16x4*)(qL + w*896 + lrow*56 + 32 + g*4);
    asm volatile("" :: "v"(qf0), "v"(qfh));
    __builtin_amdgcn_s_barrier();

    // stage tile 0 (latency covered by the t=0 vmcnt wait)
    stage_tile(w, l, ldsK0, ldsV0, kbb, vbb, 0);

    float mrun = -1e30f, lrun = 0.f;
    f32x4 o0 = {0.f,0.f,0.f,0.f}, o1 = o0, o2 = o0;

    for (int t = 0; t < 13; ++t) {
        int nb = t & 1;
        if (t < 12)
            stage_tile(w, l, nb ? ldsK0 : ldsK1, nb ? ldsV0 : ldsV1,
                       kbb, vbb, (t+1)*64);
        __builtin_amdgcn_sched_barrier(0);
        if (t < 12) {
            if (w < 2) asm volatile("s_waitcnt vmcnt(4)" ::: "memory");
            else       asm volatile("s_waitcnt vmcnt(3)" ::: "memory");
        } else {
            asm volatile("s_waitcnt vmcnt(0)" ::: "memory");
        }
        __builtin_amdgcn_s_barrier();
        __builtin_amdgcn_sched_barrier(0);
        compute_tile64(nb ? ldsK1 : ldsK0, nb ? ldsV1 : ldsV0, qf0, qfh,
                       mrun, lrun, o0, o1, o2, lrow, g, t == 0, t == 12);
        __builtin_amdgcn_sched_barrier(0);
        __builtin_amdgcn_s_barrier();
    }

    // epilogue: reduce per-lane partial lrun across the 4 lanes of this query
    lrun += __shfl_xor(lrun, 16);
    lrun += __shfl_xor(lrun, 32);
    float inv = 1.f / lrun;
    f32x4 r0, r1, r2;
    #pragma unroll
    for (int r = 0; r < 4; ++r) {
        r0[r] = o0[r]*inv; r1[r] = o1[r]*inv; r2[r] = o2[r]*inv;
    }
    float* obase = out + ((size_t)b*NN + n0 + lrow)*C_ + h*HD + g*4;
    *(f32x4*)(obase)      = r0;
    *(f32x4*)(obase + 16) = r1;
    *(f32x4*)(obase + 32) = r2;
}

// ---------------------------------------------------------------------------
extern "C" void kernel_launch(void* const* d_in, const int* in_sizes, int n_in,
                              void* d_out, int out_size, void* d_ws, size_t ws_size,
                              hipStream_t stream)
{
    const float* x     = (const float*)d_in[0];
    const float* dw_q  = (const float*)d_in[3];
    const float* bnqg  = (const float*)d_in[4];
    const float* bnqb  = (const float*)d_in[5];
    const float* bnqm  = (const float*)d_in[6];
    const float* bnqv  = (const float*)d_in[7];
    const float* pw_q  = (const float*)d_in[8];
    const float* dw_kv = (const float*)d_in[9];
    const float* bnkg  = (const float*)d_in[10];
    const float* bnkb  = (const float*)d_in[11];
    const float* bnkm  = (const float*)d_in[12];
    const float* bnkvv = (const float*)d_in[13];
    const float* pw_kv = (const float*)d_in[14];
    const float* Wq    = (const float*)d_in[15];
    const float* bq    = (const float*)d_in[16];
    const float* Wk    = (const float*)d_in[17];
    const float* bk    = (const float*)d_in[18];
    const float* Wv    = (const float*)d_in[19];
    const float* bv    = (const float*)d_in[20];
    float* out = (float*)d_out;

    f16* p   = (f16*)d_ws;
    f16* Mq16  = p;  p += C_*C_;
    f16* Mk16  = p;  p += C_*C_;
    f16* Mv16  = p;  p += C_*C_;
    f16* uq16  = p;  p += (size_t)BB*NN*C_ + 256;    // pad: frag tail reads
    f16* ukv16 = p;  p += (size_t)BB*MM*C_;
    f16* kb16  = p;  p += (size_t)BB*MM*C_ + 16384;  // pad: tail-tile staging overread
    f16* vt16  = p;  p += (size_t)BB*C_*VT_LD;

    prep_all<<<1746, 256, 0, stream>>>(
        x, dw_q, bnqg, bnqb, bnqm, bnqv,
        dw_kv, bnkg, bnkb, bnkm, bnkvv,
        Wq, Wk, Wv, pw_q, pw_kv,
        uq16, ukv16, Mq16, Mk16, Mv16, vt16);

    proj_kv<<<2*KVPB, 128, 0, stream>>>(
        ukv16, Mk16, Mv16, bk, bv, kb16, vt16);

    attn_mfma<<<1568, 256, 0, stream>>>(uq16, Mq16, bq, kb16, vt16, out);
}

// Round 24
// 93.917 us; speedup vs baseline: 1.2923x; 1.0118x over previous
//
#include <hip/hip_runtime.h>
#include <cmath>

typedef _Float16 f16;
typedef _Float16 f16x8 __attribute__((ext_vector_type(8)));
typedef _Float16 f16x4 __attribute__((ext_vector_type(4)));
typedef float    f32x4 __attribute__((ext_vector_type(4)));
typedef unsigned int u32;
typedef u32 u32x2 __attribute__((ext_vector_type(2)));

#define C_   192
#define HH   56
#define WW   56
#define NN   3136
#define BB   8
#define MM   784
#define NHEAD 4
#define HD   48
#define VT_LD 832            // padded key-dim of transposed V (784 + 48)
#define KVPB (BB*MM/32)      // 196 proj blocks per K / V path

#define MFMA16(a,b,c)  __builtin_amdgcn_mfma_f32_16x16x32_f16(a,b,c,0,0,0)
#define MFMAK16(a,b,c) __builtin_amdgcn_mfma_f32_16x16x16f16(a,b,c,0,0,0)

static __device__ __forceinline__ u32 pkrtz(float a, float b) {
    typedef __fp16 fp16x2 __attribute__((ext_vector_type(2)));
    fp16x2 h = __builtin_amdgcn_cvt_pkrtz(a, b);
    return __builtin_bit_cast(u32, h);
}

// async global->LDS, 16B per lane; LDS dst = wave-uniform base + lane*16
static __device__ __forceinline__ void gload16(const void* g, void* l) {
    __builtin_amdgcn_global_load_lds(
        (const __attribute__((address_space(1))) unsigned int*)g,
        (__attribute__((address_space(3))) unsigned int*)l, 16, 0, 0);
}

// ---------------------------------------------------------------------------
// Depthwise 3x3 + BN (stride 1), EIGHT outputs per thread (2x4 octet sharing
// a 4x6 window union): 24 loads / 8 outputs = 3/output. Weights from LDS.
__device__ __forceinline__ void dwbn_oct(
    const float* __restrict__ x, const float* __restrict__ dwL,
    const float* __restrict__ gamma, const float* __restrict__ beta,
    const float* __restrict__ mean,  const float* __restrict__ var,
    f16* __restrict__ out, int idx)
{
    int c4 = idx % 48;
    int r1 = idx / 48;
    int qx = r1 % (WW/4);
    int r2 = r1 / (WW/4);
    int qp = r2 % (HH/2);
    int b  = r2 / (HH/2);
    int c0 = c4*4;

    float4 w4[9];
    #pragma unroll
    for (int j = 0; j < 9; ++j)
        w4[j] = *(const float4*)&dwL[c4*40 + j*4];
    const float* wf = (const float*)w4;   // wf[cc*9 + wi], static indices

    float4 g4  = *(const float4*)(gamma + c0);
    float4 be4 = *(const float4*)(beta + c0);
    float4 m4  = *(const float4*)(mean + c0);
    float4 v4  = *(const float4*)(var  + c0);

    float4 acc[2][4];
    #pragma unroll
    for (int jj = 0; jj < 2; ++jj)
        #pragma unroll
        for (int ii = 0; ii < 4; ++ii)
            acc[jj][ii] = make_float4(0.f,0.f,0.f,0.f);

    int iyTop = 2*qp - 1;
    int ix0   = 4*qx - 1;
    #pragma unroll
    for (int j = 0; j < 4; ++j) {
        int iy = iyTop + j;
        if (iy < 0 || iy >= HH) continue;
        #pragma unroll
        for (int i = 0; i < 6; ++i) {
            int ix = ix0 + i;
            if (ix < 0 || ix >= WW) continue;
            float4 xv = *reinterpret_cast<const float4*>(
                x + ((size_t)b*NN + iy*WW + ix)*C_ + c0);
            #pragma unroll
            for (int jj = 0; jj < 2; ++jj) {
                if (j < jj || j > jj+2) continue;
                #pragma unroll
                for (int ii = 0; ii < 4; ++ii) {
                    if (i < ii || i > ii+2) continue;
                    const int wi = (j-jj)*3 + (i-ii);
                    acc[jj][ii].x = fmaf(wf[ 0+wi], xv.x, acc[jj][ii].x);
                    acc[jj][ii].y = fmaf(wf[ 9+wi], xv.y, acc[jj][ii].y);
                    acc[jj][ii].z = fmaf(wf[18+wi], xv.z, acc[jj][ii].z);
                    acc[jj][ii].w = fmaf(wf[27+wi], xv.w, acc[jj][ii].w);
                }
            }
        }
    }
    float i0 = g4.x*__frsqrt_rn(v4.x + 1e-5f);
    float i1 = g4.y*__frsqrt_rn(v4.y + 1e-5f);
    float i2 = g4.z*__frsqrt_rn(v4.z + 1e-5f);
    float i3 = g4.w*__frsqrt_rn(v4.w + 1e-5f);
    float b0 = be4.x - m4.x*i0, b1 = be4.y - m4.y*i1;
    float b2 = be4.z - m4.z*i2, b3 = be4.w - m4.w*i3;
    #pragma unroll
    for (int jj = 0; jj < 2; ++jj) {
        #pragma unroll
        for (int ii = 0; ii < 4; ++ii) {
            f16x4 r;
            r[0] = (f16)(acc[jj][ii].x*i0 + b0);
            r[1] = (f16)(acc[jj][ii].y*i1 + b1);
            r[2] = (f16)(acc[jj][ii].z*i2 + b2);
            r[3] = (f16)(acc[jj][ii].w*i3 + b3);
            size_t o = (((size_t)b*HH + 2*qp + jj)*WW + 4*qx + ii)*48 + c4;
            *reinterpret_cast<f16x4*>(out + o*4) = r;
        }
    }
}

// ---------------------------------------------------------------------------
// Depthwise 3x3 + BN stride 2, FOUR outputs per thread (2x2 quad, 5x5 window).
__device__ __forceinline__ void dwbn_quad2(
    const float* __restrict__ x, const float* __restrict__ dwL,
    const float* __restrict__ gamma, const float* __restrict__ beta,
    const float* __restrict__ mean,  const float* __restrict__ var,
    f16* __restrict__ out, int idx)
{
    const int OH = 28, OW = 28, STRIDE = 2;
    int c4 = idx % 48;
    int r1 = idx / 48;
    int qx = r1 % (OW/2);
    int r2 = r1 / (OW/2);
    int qp = r2 % (OH/2);
    int b  = r2 / (OH/2);
    int c0 = c4*4;

    float4 w4[9];
    #pragma unroll
    for (int j = 0; j < 9; ++j)
        w4[j] = *(const float4*)&dwL[c4*40 + j*4];
    const float* wf = (const float*)w4;

    float4 g4  = *(const float4*)(gamma + c0);
    float4 be4 = *(const float4*)(beta + c0);
    float4 m4  = *(const float4*)(mean + c0);
    float4 v4  = *(const float4*)(var  + c0);

    float4 a00 = make_float4(0.f,0.f,0.f,0.f);
    float4 a01 = a00, a10 = a00, a11 = a00;
    int iyTop = (2*qp)*STRIDE - 1;
    int ix0   = (2*qx)*STRIDE - 1;
    #pragma unroll
    for (int j = 0; j < STRIDE+3; ++j) {
        int iy = iyTop + j;
        if (iy < 0 || iy >= HH) continue;
        #pragma unroll
        for (int i = 0; i < STRIDE+3; ++i) {
            int ix = ix0 + i;
            if (ix < 0 || ix >= WW) continue;
            float4 xv = *reinterpret_cast<const float4*>(
                x + ((size_t)b*NN + iy*WW + ix)*C_ + c0);
            const bool r0ok = (j <= 2), r1ok = (j >= STRIDE);
            const bool c0ok = (i <= 2), c1ok = (i >= STRIDE);
            if (r0ok && c0ok) { const int wi = j*3 + i;
                a00.x = fmaf(wf[ 0+wi], xv.x, a00.x);
                a00.y = fmaf(wf[ 9+wi], xv.y, a00.y);
                a00.z = fmaf(wf[18+wi], xv.z, a00.z);
                a00.w = fmaf(wf[27+wi], xv.w, a00.w); }
            if (r0ok && c1ok) { const int wi = j*3 + (i-STRIDE);
                a01.x = fmaf(wf[ 0+wi], xv.x, a01.x);
                a01.y = fmaf(wf[ 9+wi], xv.y, a01.y);
                a01.z = fmaf(wf[18+wi], xv.z, a01.z);
                a01.w = fmaf(wf[27+wi], xv.w, a01.w); }
            if (r1ok && c0ok) { const int wi = (j-STRIDE)*3 + i;
                a10.x = fmaf(wf[ 0+wi], xv.x, a10.x);
                a10.y = fmaf(wf[ 9+wi], xv.y, a10.y);
                a10.z = fmaf(wf[18+wi], xv.z, a10.z);
                a10.w = fmaf(wf[27+wi], xv.w, a10.w); }
            if (r1ok && c1ok) { const int wi = (j-STRIDE)*3 + (i-STRIDE);
                a11.x = fmaf(wf[ 0+wi], xv.x, a11.x);
                a11.y = fmaf(wf[ 9+wi], xv.y, a11.y);
                a11.z = fmaf(wf[18+wi], xv.z, a11.z);
                a11.w = fmaf(wf[27+wi], xv.w, a11.w); }
        }
    }
    float i0 = g4.x*__frsqrt_rn(v4.x + 1e-5f);
    float i1 = g4.y*__frsqrt_rn(v4.y + 1e-5f);
    float i2 = g4.z*__frsqrt_rn(v4.z + 1e-5f);
    float i3 = g4.w*__frsqrt_rn(v4.w + 1e-5f);
    float b0 = be4.x - m4.x*i0, b1 = be4.y - m4.y*i1;
    float b2 = be4.z - m4.z*i2, b3 = be4.w - m4.w*i3;
    size_t base = (((size_t)b*OH + 2*qp)*OW + 2*qx)*48 + c4;
    f16x4 r;
    r[0]=(f16)(a00.x*i0+b0); r[1]=(f16)(a00.y*i1+b1);
    r[2]=(f16)(a00.z*i2+b2); r[3]=(f16)(a00.w*i3+b3);
    *reinterpret_cast<f16x4*>(out + base*4) = r;
    r[0]=(f16)(a01.x*i0+b0); r[1]=(f16)(a01.y*i1+b1);
    r[2]=(f16)(a01.z*i2+b2); r[3]=(f16)(a01.w*i3+b3);
    *reinterpret_cast<f16x4*>(out + (base + 48)*4) = r;
    r[0]=(f16)(a10.x*i0+b0); r[1]=(f16)(a10.y*i1+b1);
    r[2]=(f16)(a10.z*i2+b2); r[3]=(f16)(a10.w*i3+b3);
    *reinterpret_cast<f16x4*>(out + (base + (size_t)OW*48)*4) = r;
    r[0]=(f16)(a11.x*i0+b0); r[1]=(f16)(a11.y*i1+b1);
    r[2]=(f16)(a11.z*i2+b2); r[3]=(f16)(a11.w*i3+b3);
    *reinterpret_cast<f16x4*>(out + (base + (size_t)OW*48 + 48)*4) = r;
}

// ---------------------------------------------------------------------------
// Fused prep: dwbn (oct Q, quad KV) + pointwise-fold + Vt pad zero.
__global__ __launch_bounds__(256) void prep_all(
    const float* __restrict__ x,
    const float* __restrict__ dwq,  const float* __restrict__ gq,
    const float* __restrict__ bq_,  const float* __restrict__ mq,
    const float* __restrict__ vq,
    const float* __restrict__ dwkv, const float* __restrict__ gkv,
    const float* __restrict__ bkv,  const float* __restrict__ mkv,
    const float* __restrict__ vkv,
    const float* __restrict__ Wq, const float* __restrict__ Wk,
    const float* __restrict__ Wv, const float* __restrict__ pw_q,
    const float* __restrict__ pw_kv,
    f16* __restrict__ uq, f16* __restrict__ ukv,
    f16* __restrict__ Mq, f16* __restrict__ Mk, f16* __restrict__ Mv,
    f16* __restrict__ vt)
{
    int blk = blockIdx.x, tid = threadIdx.x;
    const int QB = 588, KB = 294;
    if (blk < QB + KB) {
        bool qp = blk < QB;
        __shared__ __align__(16) float dwL[48*40];
        const float* dwg = qp ? dwq : dwkv;
        for (int i = tid; i < 432; i += 256) {
            int f  = i*4;
            int c4 = f/36, r = f%36;
            *(float4*)&dwL[c4*40 + r] = *(const float4*)(dwg + f);
        }
        __syncthreads();
        if (qp)
            dwbn_oct(x, dwL, gq, bq_, mq, vq, uq, blk*256 + tid);
        else
            dwbn_quad2(x, dwL, gkv, bkv, mkv, vkv, ukv, (blk - QB)*256 + tid);
    } else if (blk < QB + KB + 576) {
        int fb = blk - QB - KB;
        int which = fb / 192, o = fb % 192;
        const float* Wm = which == 0 ? Wq : (which == 1 ? Wk : Wv);
        const float* P  = which == 0 ? pw_q : (which == 1 ? pw_kv : pw_kv + C_*C_);
        f16* Mo         = which == 0 ? Mq : (which == 1 ? Mk : Mv);
        __shared__ float wrow[C_];
        if (tid < C_) wrow[tid] = Wm[o*C_ + tid];
        __syncthreads();
        if (tid < C_) {
            float acc = 0.f;
            #pragma unroll 8
            for (int j = 0; j < C_; ++j)
                acc = fmaf(wrow[j], P[j*C_ + tid], acc);
            Mo[o*C_ + tid] = (f16)acc;
        }
    } else {
        int i = (blk - QB - KB - 576)*256 + tid;   // BB*C_*48 = 73728 exactly
        int b = i / (C_*48);
        int rem = i % (C_*48);
        int c = rem / 48;
        int m = MM + (rem % 48);
        vt[((size_t)b*C_ + c)*VT_LD + m] = (f16)0.f;
    }
}

// ---------------------------------------------------------------------------
// K/V projections only (Q is fused into attn). 128-thread blocks, 32 rows.
__global__ __launch_bounds__(128, 1) void proj_kv(
    const f16* __restrict__ ukv,
    const f16* __restrict__ Mk, const f16* __restrict__ Mv,
    const float* __restrict__ bk, const float* __restrict__ bv,
    f16* __restrict__ kb, f16* __restrict__ vt)
{
    int tid  = threadIdx.x;
    int w    = tid >> 6, l = tid & 63;
    int lrow = l & 15,  lgrp = l >> 4;
    int blk  = blockIdx.x;
    int path = blk < KVPB ? 1 : 2;
    int rblk = path == 1 ? blk : blk - KVPB;
    int r0 = rblk*32 + w*16;

    const f16* urow = ukv + (size_t)(r0 + lrow)*C_;
    f16x8 a[6];
    #pragma unroll
    for (int ch = 0; ch < 6; ++ch)
        a[ch] = *(const f16x8*)(urow + ch*32 + lgrp*8);

    f16x8 bfA[6], bfB[6];
    const f16* Mm = path == 1 ? Mk : Mv;

    #pragma unroll
    for (int ch = 0; ch < 6; ++ch)
        bfA[ch] = *(const f16x8*)(Mm + (size_t)lrow*C_ + ch*32 + lgrp*8);

    if (path == 1) {
        #pragma unroll
        for (int ct = 0; ct < 12; ++ct) {            // K projection (swapped)
            f16x8* cur = (ct & 1) ? bfB : bfA;
            f16x8* nxt = (ct & 1) ? bfA : bfB;
            if (ct < 11) {
                const f16* mrow = Mm + (size_t)((ct+1)*16 + lrow)*C_;
                #pragma unroll
                for (int ch = 0; ch < 6; ++ch)
                    nxt[ch] = *(const f16x8*)(mrow + ch*32 + lgrp*8);
            }
            f32x4 acc = {0.f,0.f,0.f,0.f};
            #pragma unroll
            for (int ch = 0; ch < 6; ++ch)
                acc = MFMA16(cur[ch], a[ch], acc);
            float4 bo = *(const float4*)(bk + ct*16 + lgrp*4);
            f16x4 st;
            st[0] = (f16)(acc[0] + bo.x);
            st[1] = (f16)(acc[1] + bo.y);
            st[2] = (f16)(acc[2] + bo.z);
            st[3] = (f16)(acc[3] + bo.w);
            *(f16x4*)(kb + (size_t)(r0 + lrow)*C_ + ct*16 + lgrp*4) = st;
        }
    } else {
        #pragma unroll
        for (int ct = 0; ct < 12; ++ct) {            // V projection (transposed)
            f16x8* cur = (ct & 1) ? bfB : bfA;
            f16x8* nxt = (ct & 1) ? bfA : bfB;
            if (ct < 11) {
                const f16* mrow = Mv + (size_t)((ct+1)*16 + lrow)*C_;
                #pragma unroll
                for (int ch = 0; ch < 6; ++ch)
                    nxt[ch] = *(const f16x8*)(mrow + ch*32 + lgrp*8);
            }
            int o = ct*16 + lrow;
            f32x4 acc = {0.f,0.f,0.f,0.f};
            #pragma unroll
            for (int ch = 0; ch < 6; ++ch)
                acc = MFMA16(a[ch], cur[ch], acc);
            float bo = bv[o];
            int rg = r0 + lgrp*4;
            int b  = rg / MM, m = rg % MM;            // 784 % 16 == 0
            f16x4 st;
            st[0] = (f16)(acc[0] + bo);
            st[1] = (f16)(acc[1] + bo);
            st[2] = (f16)(acc[2] + bo);
            st[3] = (f16)(acc[3] + bo);
            *(f16x4*)(vt + ((size_t)b*C_ + o)*VT_LD + m) = st;
        }
    }
}

// ---------------------------------------------------------------------------
// Flash attention R24: R20 structure + SLIM TAIL. 12 full 64-key tiles, then
// a 16-key tail (keys 768..783) doing 3 MFMAs + 4 exp2 instead of a fully
// masked 64-key tile (bit-identical: masked lanes contributed exact zeros).
__device__ __forceinline__ void stage_tile(
    int w, int l, f16* ldsKb, f16* ldsVb,
    const f16* __restrict__ kbb, const f16* __restrict__ vbb, int m0)
{
    int rr = l >> 3, p = l & 7;
    #pragma unroll
    for (int j = 0; j < 4; ++j) {
        int u = w + j*4;
        if (u < 8) {                      // K rows 8u..8u+7
            int r = u*8 + rr;
            int c = p ^ (r & 7);
            gload16(kbb + (size_t)(m0 + r)*C_ + c*8, ldsKb + u*512);
        } else if (u < 14) {              // V rows (d) 8(u-8)..+7
            int d = (u-8)*8 + rr;
            int c = p ^ (d & 7);
            gload16(vbb + (size_t)d*VT_LD + m0 + c*8, ldsVb + (u-8)*512);
        }
    }
}

__device__ __forceinline__ float max16(const f32x4* s)
{
    float t0 = fmaxf(fmaxf(s[0][0], s[0][1]), fmaxf(s[0][2], s[0][3]));
    float t1 = fmaxf(fmaxf(s[1][0], s[1][1]), fmaxf(s[1][2], s[1][3]));
    float t2 = fmaxf(fmaxf(s[2][0], s[2][1]), fmaxf(s[2][2], s[2][3]));
    float t3 = fmaxf(fmaxf(s[3][0], s[3][1]), fmaxf(s[3][2], s[3][3]));
    return fmaxf(fmaxf(t0, t1), fmaxf(t2, t3));
}

__device__ __forceinline__ void compute_tile64(
    const f16* ldsKb, const f16* ldsVb,
    const f16x8& qf0, const f16x4& qfh,
    float& mrun, float& lrun, f32x4& o0, f32x4& o1, f32x4& o2,
    int lrow, int g, bool first)
{
    const char* kP = (const char*)ldsKb;
    const char* vP = (const char*)ldsVb;
    f32x4 z = {0.f,0.f,0.f,0.f};
    int sw = lrow & 7;
    int cA = (g ^ sw) << 4;                                  // d 0..31 (16B)
    int cH = (((4 + (g >> 1)) ^ sw) << 4) + ((g & 1) << 3);  // d 32..47 (8B)

    f32x4 s[4];
    __builtin_amdgcn_s_setprio(1);
    #pragma unroll
    for (int j = 0; j < 4; ++j) {
        const char* rb = kP + (16*j + lrow)*128;
        f32x4 t = MFMA16(*(const f16x8*)(rb + cA), qf0, z);
        s[j] = MFMAK16(*(const f16x4*)(rb + cH), qfh, t);
    }
    __builtin_amdgcn_s_setprio(0);

    u32 pk[8];
    float tl = max16(s);
    bool fast = false;
    if (!first) fast = (__all(tl <= mrun + 8.0f) != 0);

    if (fast) {
        // defer-max: keep mrun; P = exp2(s - mrun) <= 2^8, no O rescale
        float psum = 0.f;
        #pragma unroll
        for (int j = 0; j < 4; ++j) {
            #pragma unroll
            for (int r = 0; r < 4; ++r) {
                s[j][r] = exp2f(s[j][r] - mrun);
                psum += s[j][r];
            }
        }
        lrun += psum;     // per-lane partial; reduced at epilogue
        #pragma unroll
        for (int j = 0; j < 4; ++j) {
            pk[j*2]   = pkrtz(s[j][0], s[j][1]);
            pk[j*2+1] = pkrtz(s[j][2], s[j][3]);
        }
    } else {
        float tmax = tl;
        tmax = fmaxf(tmax, __shfl_xor(tmax, 16));
        tmax = fmaxf(tmax, __shfl_xor(tmax, 32));
        float mnew = fmaxf(mrun, tmax);
        float corr = exp2f(mrun - mnew);
        mrun = mnew;
        float psum = 0.f;
        #pragma unroll
        for (int j = 0; j < 4; ++j) {
            #pragma unroll
            for (int r = 0; r < 4; ++r) {
                s[j][r] = exp2f(s[j][r] - mnew);
                psum += s[j][r];
            }
        }
        lrun = lrun*corr + psum;
        #pragma unroll
        for (int j = 0; j < 4; ++j) {
            pk[j*2]   = pkrtz(s[j][0], s[j][1]);
            pk[j*2+1] = pkrtz(s[j][2], s[j][3]);
        }
        #pragma unroll
        for (int r = 0; r < 4; ++r) {
            o0[r] *= corr; o1[r] *= corr; o2[r] *= corr;
        }
    }

    // PV: per 16-key chunk, B-frag is lane-local {pk[2ch],pk[2ch+1]};
    // A-frag = Vt[d=16*db+lrow][m0+16ch+g*4 .. +3] (8B swizzled LDS read).
    #pragma unroll
    for (int ch = 0; ch < 4; ++ch) {
        u32x2 pw = { pk[2*ch], pk[2*ch+1] };
        f16x4 pb = __builtin_bit_cast(f16x4, pw);
        int off = (((2*ch + (g >> 1)) ^ sw) << 4) + ((g & 1) << 3);
        f16x4 v0 = *(const f16x4*)(vP + lrow*128      + off);
        f16x4 v1 = *(const f16x4*)(vP + (16+lrow)*128 + off);
        f16x4 v2 = *(const f16x4*)(vP + (32+lrow)*128 + off);
        __builtin_amdgcn_s_setprio(1);
        o0 = MFMAK16(v0, pb, o0);
        o1 = MFMAK16(v1, pb, o1);
        o2 = MFMAK16(v2, pb, o2);
        __builtin_amdgcn_s_setprio(0);
    }
}

// Slim tail: keys m0..m0+15 only (block j=0, PV chunk ch=0). Bit-identical
// to the old masked 64-key tail: masked lanes contributed exp2(-inf)=0.
__device__ __forceinline__ void compute_tail16(
    const f16* ldsKb, const f16* ldsVb,
    const f16x8& qf0, const f16x4& qfh,
    float& mrun, float& lrun, f32x4& o0, f32x4& o1, f32x4& o2,
    int lrow, int g)
{
    const char* kP = (const char*)ldsKb;
    const char* vP = (const char*)ldsVb;
    f32x4 z = {0.f,0.f,0.f,0.f};
    int sw = lrow & 7;
    int cA = (g ^ sw) << 4;
    int cH = (((4 + (g >> 1)) ^ sw) << 4) + ((g & 1) << 3);

    const char* rb = kP + lrow*128;
    f32x4 t  = MFMA16(*(const f16x8*)(rb + cA), qf0, z);
    f32x4 s0 = MFMAK16(*(const f16x4*)(rb + cH), qfh, t);

    float tl = fmaxf(fmaxf(s0[0], s0[1]), fmaxf(s0[2], s0[3]));
    bool fast = (__all(tl <= mrun + 8.0f) != 0);
    u32 pk0, pk1;
    if (fast) {
        float psum = 0.f;
        #pragma unroll
        for (int r = 0; r < 4; ++r) { s0[r] = exp2f(s0[r] - mrun); psum += s0[r]; }
        lrun += psum;
        pk0 = pkrtz(s0[0], s0[1]); pk1 = pkrtz(s0[2], s0[3]);
    } else {
        float tmax = tl;
        tmax = fmaxf(tmax, __shfl_xor(tmax, 16));
        tmax = fmaxf(tmax, __shfl_xor(tmax, 32));
        float mnew = fmaxf(mrun, tmax);
        float corr = exp2f(mrun - mnew);
        mrun = mnew;
        float psum = 0.f;
        #pragma unroll
        for (int r = 0; r < 4; ++r) { s0[r] = exp2f(s0[r] - mnew); psum += s0[r]; }
        lrun = lrun*corr + psum;
        pk0 = pkrtz(s0[0], s0[1]); pk1 = pkrtz(s0[2], s0[3]);
        #pragma unroll
        for (int r = 0; r < 4; ++r) { o0[r] *= corr; o1[r] *= corr; o2[r] *= corr; }
    }
    u32x2 pw = { pk0, pk1 };
    f16x4 pb = __builtin_bit_cast(f16x4, pw);
    int off = (((g >> 1) ^ sw) << 4) + ((g & 1) << 3);   // ch = 0
    f16x4 v0 = *(const f16x4*)(vP + lrow*128      + off);
    f16x4 v1 = *(const f16x4*)(vP + (16+lrow)*128 + off);
    f16x4 v2 = *(const f16x4*)(vP + (32+lrow)*128 + off);
    o0 = MFMAK16(v0, pb, o0);
    o1 = MFMAK16(v1, pb, o1);
    o2 = MFMAK16(v2, pb, o2);
}

__global__ __launch_bounds__(256, 2) void attn_mfma(
    const f16* __restrict__ uq, const f16* __restrict__ Mq,
    const float* __restrict__ bq,
    const f16* __restrict__ kb, const f16* __restrict__ vt,
    float* __restrict__ out)
{
    // flat LDS: K0 | K1 | V0 | V1 ; qL aliases K1 (dead after prologue,
    // first overwritten when tile 1 stages inside the loop)
    __shared__ __align__(16) f16 lds[2*4096 + 2*3072];   // 28672 B
    f16* ldsK0 = lds;
    f16* ldsK1 = lds + 4096;
    f16* ldsV0 = lds + 8192;
    f16* ldsV1 = lds + 8192 + 3072;
    f16* qL    = ldsK1;                  // 4 waves x 896 f16 = 3584 <= 4096

    int tid  = threadIdx.x;
    int w    = tid >> 6, l = tid & 63;
    int lrow = l & 15,  g = l >> 4;
    // XCD swizzle: 1568 = 8*196; 4 (b,h) groups per XCD -> KV L2-resident.
    int swz  = (blockIdx.x & 7)*196 + (blockIdx.x >> 3);
    int bh   = swz / 49, qblk = swz % 49;
    int h    = bh & 3, b = bh >> 2;
    int n0   = qblk*64 + w*16;

    const f16* kbb = kb + (size_t)b*MM*C_ + h*HD;
    const f16* vbb = vt + ((size_t)b*C_ + h*HD)*VT_LD;

    // ---- fused Q projection (u-frags head the dependency chain) ----
    const f16* urow = uq + ((size_t)b*NN + n0 + lrow)*C_;
    f16x8 ufr[6];
    #pragma unroll
    for (int ch = 0; ch < 6; ++ch)
        ufr[ch] = *(const f16x8*)(urow + ch*32 + g*8);
    {
        const float qsc = 0.14433756729740643f * 1.4426950408889634f;
        f16* qw = qL + w*896;
        #pragma unroll
        for (int dt = 0; dt < 3; ++dt) {
            const f16* mrow = Mq + (size_t)(h*HD + dt*16 + lrow)*C_;
            f32x4 acc = {0.f,0.f,0.f,0.f};
            #pragma unroll
            for (int ch = 0; ch < 6; ++ch)
                acc = MFMA16(*(const f16x8*)(mrow + ch*32 + g*8), ufr[ch], acc);
            float4 bo = *(const float4*)(bq + h*HD + dt*16 + g*4);
            f16x4 st;
            st[0] = (f16)((acc[0] + bo.x)*qsc);
            st[1] = (f16)((acc[1] + bo.y)*qsc);
            st[2] = (f16)((acc[2] + bo.z)*qsc);
            st[3] = (f16)((acc[3] + bo.w)*qsc);
            *(f16x4*)(qw + lrow*56 + dt*16 + g*4) = st;   // n=lrow, d=dt*16+g*4+r
        }
    }
    // read own slice (asm forces the lgkm wait), then barrier so no wave
    // stages tile 1 (into ldsK1) before all waves finished reading qL
    f16x8 qf0 = *(const f16x8*)(qL + w*896 + lrow*56 + g*8);
    f16x4 qfh = *(const f16x4*)(qL + w*896 + lrow*56 + 32 + g*4);
    asm volatile("" :: "v"(qf0), "v"(qfh));
    __builtin_amdgcn_s_barrier();

    // stage tile 0 (latency covered by the t=0 vmcnt wait)
    stage_tile(w, l, ldsK0, ldsV0, kbb, vbb, 0);

    float mrun = -1e30f, lrun = 0.f;
    f32x4 o0 = {0.f,0.f,0.f,0.f}, o1 = o0, o2 = o0;

    for (int t = 0; t < 12; ++t) {
        int nb = t & 1;
        stage_tile(w, l, nb ? ldsK0 : ldsK1, nb ? ldsV0 : ldsV1,
                   kbb, vbb, (t+1)*64);
        __builtin_amdgcn_sched_barrier(0);
        if (w < 2) asm volatile("s_waitcnt vmcnt(4)" ::: "memory");
        else       asm volatile("s_waitcnt vmcnt(3)" ::: "memory");
        __builtin_amdgcn_s_barrier();
        __builtin_amdgcn_sched_barrier(0);
        compute_tile64(nb ? ldsK1 : ldsK0, nb ? ldsV1 : ldsV0, qf0, qfh,
                       mrun, lrun, o0, o1, o2, lrow, g, t == 0);
        __builtin_amdgcn_sched_barrier(0);
        __builtin_amdgcn_s_barrier();
    }
    // slim tail: tile 12 (keys 768..783) was staged at t=11 into K0/V0
    asm volatile("s_waitcnt vmcnt(0)" ::: "memory");
    __builtin_amdgcn_s_barrier();
    __builtin_amdgcn_sched_barrier(0);
    compute_tail16(ldsK0, ldsV0, qf0, qfh, mrun, lrun, o0, o1, o2, lrow, g);

    // epilogue: reduce per-lane partial lrun across the 4 lanes of this query
    lrun += __shfl_xor(lrun, 16);
    lrun += __shfl_xor(lrun, 32);
    float inv = 1.f / lrun;
    f32x4 r0, r1, r2;
    #pragma unroll
    for (int r = 0; r < 4; ++r) {
        r0[r] = o0[r]*inv; r1[r] = o1[r]*inv; r2[r] = o2[r]*inv;
    }
    float* obase = out + ((size_t)b*NN + n0 + lrow)*C_ + h*HD + g*4;
    *(f32x4*)(obase)      = r0;
    *(f32x4*)(obase + 16) = r1;
    *(f32x4*)(obase + 32) = r2;
}

// ---------------------------------------------------------------------------
extern "C" void kernel_launch(void* const* d_in, const int* in_sizes, int n_in,
                              void* d_out, int out_size, void* d_ws, size_t ws_size,
                              hipStream_t stream)
{
    const float* x     = (const float*)d_in[0];
    const float* dw_q  = (const float*)d_in[3];
    const float* bnqg  = (const float*)d_in[4];
    const float* bnqb  = (const float*)d_in[5];
    const float* bnqm  = (const float*)d_in[6];
    const float* bnqv  = (const float*)d_in[7];
    const float* pw_q  = (const float*)d_in[8];
    const float* dw_kv = (const float*)d_in[9];
    const float* bnkg  = (const float*)d_in[10];
    const float* bnkb  = (const float*)d_in[11];
    const float* bnkm  = (const float*)d_in[12];
    const float* bnkvv = (const float*)d_in[13];
    const float* pw_kv = (const float*)d_in[14];
    const float* Wq    = (const float*)d_in[15];
    const float* bq    = (const float*)d_in[16];
    const float* Wk    = (const float*)d_in[17];
    const float* bk    = (const float*)d_in[18];
    const float* Wv    = (const float*)d_in[19];
    const float* bv    = (const float*)d_in[20];
    float* out = (float*)d_out;

    f16* p   = (f16*)d_ws;
    f16* Mq16  = p;  p += C_*C_;
    f16* Mk16  = p;  p += C_*C_;
    f16* Mv16  = p;  p += C_*C_;
    f16* uq16  = p;  p += (size_t)BB*NN*C_ + 256;    // pad: frag tail reads
    f16* ukv16 = p;  p += (size_t)BB*MM*C_;
    f16* kb16  = p;  p += (size_t)BB*MM*C_ + 16384;  // pad: tail-tile staging overread
    f16* vt16  = p;  p += (size_t)BB*C_*VT_LD;

    prep_all<<<1746, 256, 0, stream>>>(
        x, dw_q, bnqg, bnqb, bnqm, bnqv,
        dw_kv, bnkg, bnkb, bnkm, bnkvv,
        Wq, Wk, Wv, pw_q, pw_kv,
        uq16, ukv16, Mq16, Mk16, Mv16, vt16);

    proj_kv<<<2*KVPB, 128, 0, stream>>>(
        ukv16, Mk16, Mv16, bk, bv, kb16, vt16);

    attn_mfma<<<1568, 256, 0, stream>>>(uq16, Mq16, bq, kb16, vt16, out);
}

// Round 25
// 93.728 us; speedup vs baseline: 1.2949x; 1.0020x over previous
//
#include <hip/hip_runtime.h>
#include <cmath>

typedef _Float16 f16;
typedef _Float16 f16x8 __attribute__((ext_vector_type(8)));
typedef _Float16 f16x4 __attribute__((ext_vector_type(4)));
typedef float    f32x4 __attribute__((ext_vector_type(4)));
typedef unsigned int u32;
typedef u32 u32x2 __attribute__((ext_vector_type(2)));

#define C_   192
#define HH   56
#define WW   56
#define NN   3136
#define BB   8
#define MM   784
#define NHEAD 4
#define HD   48
#define VT_LD 832            // padded key-dim of transposed V (784 + 48)
#define KVPB (BB*MM/32)      // 196 proj blocks per K / V path

#define MFMA16(a,b,c)  __builtin_amdgcn_mfma_f32_16x16x32_f16(a,b,c,0,0,0)
#define MFMAK16(a,b,c) __builtin_amdgcn_mfma_f32_16x16x16f16(a,b,c,0,0,0)

static __device__ __forceinline__ u32 pkrtz(float a, float b) {
    typedef __fp16 fp16x2 __attribute__((ext_vector_type(2)));
    fp16x2 h = __builtin_amdgcn_cvt_pkrtz(a, b);
    return __builtin_bit_cast(u32, h);
}

// async global->LDS, 16B per lane; LDS dst = wave-uniform base + lane*16
static __device__ __forceinline__ void gload16(const void* g, void* l) {
    __builtin_amdgcn_global_load_lds(
        (const __attribute__((address_space(1))) unsigned int*)g,
        (__attribute__((address_space(3))) unsigned int*)l, 16, 0, 0);
}

// ---------------------------------------------------------------------------
// Depthwise 3x3 + BN (stride 1), EIGHT outputs per thread (2x4 octet sharing
// a 4x6 window union): 24 loads / 8 outputs = 3/output. Weights from LDS.
__device__ __forceinline__ void dwbn_oct(
    const float* __restrict__ x, const float* __restrict__ dwL,
    const float* __restrict__ gamma, const float* __restrict__ beta,
    const float* __restrict__ mean,  const float* __restrict__ var,
    f16* __restrict__ out, int idx)
{
    int c4 = idx % 48;
    int r1 = idx / 48;
    int qx = r1 % (WW/4);
    int r2 = r1 / (WW/4);
    int qp = r2 % (HH/2);
    int b  = r2 / (HH/2);
    int c0 = c4*4;

    float4 w4[9];
    #pragma unroll
    for (int j = 0; j < 9; ++j)
        w4[j] = *(const float4*)&dwL[c4*40 + j*4];
    const float* wf = (const float*)w4;   // wf[cc*9 + wi], static indices

    float4 g4  = *(const float4*)(gamma + c0);
    float4 be4 = *(const float4*)(beta + c0);
    float4 m4  = *(const float4*)(mean + c0);
    float4 v4  = *(const float4*)(var  + c0);

    float4 acc[2][4];
    #pragma unroll
    for (int jj = 0; jj < 2; ++jj)
        #pragma unroll
        for (int ii = 0; ii < 4; ++ii)
            acc[jj][ii] = make_float4(0.f,0.f,0.f,0.f);

    int iyTop = 2*qp - 1;
    int ix0   = 4*qx - 1;
    #pragma unroll
    for (int j = 0; j < 4; ++j) {
        int iy = iyTop + j;
        if (iy < 0 || iy >= HH) continue;
        #pragma unroll
        for (int i = 0; i < 6; ++i) {
            int ix = ix0 + i;
            if (ix < 0 || ix >= WW) continue;
            float4 xv = *reinterpret_cast<const float4*>(
                x + ((size_t)b*NN + iy*WW + ix)*C_ + c0);
            #pragma unroll
            for (int jj = 0; jj < 2; ++jj) {
                if (j < jj || j > jj+2) continue;
                #pragma unroll
                for (int ii = 0; ii < 4; ++ii) {
                    if (i < ii || i > ii+2) continue;
                    const int wi = (j-jj)*3 + (i-ii);
                    acc[jj][ii].x = fmaf(wf[ 0+wi], xv.x, acc[jj][ii].x);
                    acc[jj][ii].y = fmaf(wf[ 9+wi], xv.y, acc[jj][ii].y);
                    acc[jj][ii].z = fmaf(wf[18+wi], xv.z, acc[jj][ii].z);
                    acc[jj][ii].w = fmaf(wf[27+wi], xv.w, acc[jj][ii].w);
                }
            }
        }
    }
    float i0 = g4.x*__frsqrt_rn(v4.x + 1e-5f);
    float i1 = g4.y*__frsqrt_rn(v4.y + 1e-5f);
    float i2 = g4.z*__frsqrt_rn(v4.z + 1e-5f);
    float i3 = g4.w*__frsqrt_rn(v4.w + 1e-5f);
    float b0 = be4.x - m4.x*i0, b1 = be4.y - m4.y*i1;
    float b2 = be4.z - m4.z*i2, b3 = be4.w - m4.w*i3;
    #pragma unroll
    for (int jj = 0; jj < 2; ++jj) {
        #pragma unroll
        for (int ii = 0; ii < 4; ++ii) {
            f16x4 r;
            r[0] = (f16)(acc[jj][ii].x*i0 + b0);
            r[1] = (f16)(acc[jj][ii].y*i1 + b1);
            r[2] = (f16)(acc[jj][ii].z*i2 + b2);
            r[3] = (f16)(acc[jj][ii].w*i3 + b3);
            size_t o = (((size_t)b*HH + 2*qp + jj)*WW + 4*qx + ii)*48 + c4;
            *reinterpret_cast<f16x4*>(out + o*4) = r;
        }
    }
}

// ---------------------------------------------------------------------------
// Depthwise 3x3 + BN stride 2, FOUR outputs per thread (2x2 quad, 5x5 window).
__device__ __forceinline__ void dwbn_quad2(
    const float* __restrict__ x, const float* __restrict__ dwL,
    const float* __restrict__ gamma, const float* __restrict__ beta,
    const float* __restrict__ mean,  const float* __restrict__ var,
    f16* __restrict__ out, int idx)
{
    const int OH = 28, OW = 28, STRIDE = 2;
    int c4 = idx % 48;
    int r1 = idx / 48;
    int qx = r1 % (OW/2);
    int r2 = r1 / (OW/2);
    int qp = r2 % (OH/2);
    int b  = r2 / (OH/2);
    int c0 = c4*4;

    float4 w4[9];
    #pragma unroll
    for (int j = 0; j < 9; ++j)
        w4[j] = *(const float4*)&dwL[c4*40 + j*4];
    const float* wf = (const float*)w4;

    float4 g4  = *(const float4*)(gamma + c0);
    float4 be4 = *(const float4*)(beta + c0);
    float4 m4  = *(const float4*)(mean + c0);
    float4 v4  = *(const float4*)(var  + c0);

    float4 a00 = make_float4(0.f,0.f,0.f,0.f);
    float4 a01 = a00, a10 = a00, a11 = a00;
    int iyTop = (2*qp)*STRIDE - 1;
    int ix0   = (2*qx)*STRIDE - 1;
    #pragma unroll
    for (int j = 0; j < STRIDE+3; ++j) {
        int iy = iyTop + j;
        if (iy < 0 || iy >= HH) continue;
        #pragma unroll
        for (int i = 0; i < STRIDE+3; ++i) {
            int ix = ix0 + i;
            if (ix < 0 || ix >= WW) continue;
            float4 xv = *reinterpret_cast<const float4*>(
                x + ((size_t)b*NN + iy*WW + ix)*C_ + c0);
            const bool r0ok = (j <= 2), r1ok = (j >= STRIDE);
            const bool c0ok = (i <= 2), c1ok = (i >= STRIDE);
            if (r0ok && c0ok) { const int wi = j*3 + i;
                a00.x = fmaf(wf[ 0+wi], xv.x, a00.x);
                a00.y = fmaf(wf[ 9+wi], xv.y, a00.y);
                a00.z = fmaf(wf[18+wi], xv.z, a00.z);
                a00.w = fmaf(wf[27+wi], xv.w, a00.w); }
            if (r0ok && c1ok) { const int wi = j*3 + (i-STRIDE);
                a01.x = fmaf(wf[ 0+wi], xv.x, a01.x);
                a01.y = fmaf(wf[ 9+wi], xv.y, a01.y);
                a01.z = fmaf(wf[18+wi], xv.z, a01.z);
                a01.w = fmaf(wf[27+wi], xv.w, a01.w); }
            if (r1ok && c0ok) { const int wi = (j-STRIDE)*3 + i;
                a10.x = fmaf(wf[ 0+wi], xv.x, a10.x);
                a10.y = fmaf(wf[ 9+wi], xv.y, a10.y);
                a10.z = fmaf(wf[18+wi], xv.z, a10.z);
                a10.w = fmaf(wf[27+wi], xv.w, a10.w); }
            if (r1ok && c1ok) { const int wi = (j-STRIDE)*3 + (i-STRIDE);
                a11.x = fmaf(wf[ 0+wi], xv.x, a11.x);
                a11.y = fmaf(wf[ 9+wi], xv.y, a11.y);
                a11.z = fmaf(wf[18+wi], xv.z, a11.z);
                a11.w = fmaf(wf[27+wi], xv.w, a11.w); }
        }
    }
    float i0 = g4.x*__frsqrt_rn(v4.x + 1e-5f);
    float i1 = g4.y*__frsqrt_rn(v4.y + 1e-5f);
    float i2 = g4.z*__frsqrt_rn(v4.z + 1e-5f);
    float i3 = g4.w*__frsqrt_rn(v4.w + 1e-5f);
    float b0 = be4.x - m4.x*i0, b1 = be4.y - m4.y*i1;
    float b2 = be4.z - m4.z*i2, b3 = be4.w - m4.w*i3;
    size_t base = (((size_t)b*OH + 2*qp)*OW + 2*qx)*48 + c4;
    f16x4 r;
    r[0]=(f16)(a00.x*i0+b0); r[1]=(f16)(a00.y*i1+b1);
    r[2]=(f16)(a00.z*i2+b2); r[3]=(f16)(a00.w*i3+b3);
    *reinterpret_cast<f16x4*>(out + base*4) = r;
    r[0]=(f16)(a01.x*i0+b0); r[1]=(f16)(a01.y*i1+b1);
    r[2]=(f16)(a01.z*i2+b2); r[3]=(f16)(a01.w*i3+b3);
    *reinterpret_cast<f16x4*>(out + (base + 48)*4) = r;
    r[0]=(f16)(a10.x*i0+b0); r[1]=(f16)(a10.y*i1+b1);
    r[2]=(f16)(a10.z*i2+b2); r[3]=(f16)(a10.w*i3+b3);
    *reinterpret_cast<f16x4*>(out + (base + (size_t)OW*48)*4) = r;
    r[0]=(f16)(a11.x*i0+b0); r[1]=(f16)(a11.y*i1+b1);
    r[2]=(f16)(a11.z*i2+b2); r[3]=(f16)(a11.w*i3+b3);
    *reinterpret_cast<f16x4*>(out + (base + (size_t)OW*48 + 48)*4) = r;
}

// ---------------------------------------------------------------------------
// Fused prep: dwbn (oct Q, quad KV) + pointwise-fold + Vt pad zero.
__global__ __launch_bounds__(256) void prep_all(
    const float* __restrict__ x,
    const float* __restrict__ dwq,  const float* __restrict__ gq,
    const float* __restrict__ bq_,  const float* __restrict__ mq,
    const float* __restrict__ vq,
    const float* __restrict__ dwkv, const float* __restrict__ gkv,
    const float* __restrict__ bkv,  const float* __restrict__ mkv,
    const float* __restrict__ vkv,
    const float* __restrict__ Wq, const float* __restrict__ Wk,
    const float* __restrict__ Wv, const float* __restrict__ pw_q,
    const float* __restrict__ pw_kv,
    f16* __restrict__ uq, f16* __restrict__ ukv,
    f16* __restrict__ Mq, f16* __restrict__ Mk, f16* __restrict__ Mv,
    f16* __restrict__ vt)
{
    int blk = blockIdx.x, tid = threadIdx.x;
    const int QB = 588, KB = 294;
    if (blk < QB + KB) {
        bool qp = blk < QB;
        __shared__ __align__(16) float dwL[48*40];
        const float* dwg = qp ? dwq : dwkv;
        for (int i = tid; i < 432; i += 256) {
            int f  = i*4;
            int c4 = f/36, r = f%36;
            *(float4*)&dwL[c4*40 + r] = *(const float4*)(dwg + f);
        }
        __syncthreads();
        if (qp)
            dwbn_oct(x, dwL, gq, bq_, mq, vq, uq, blk*256 + tid);
        else
            dwbn_quad2(x, dwL, gkv, bkv, mkv, vkv, ukv, (blk - QB)*256 + tid);
    } else if (blk < QB + KB + 576) {
        int fb = blk - QB - KB;
        int which = fb / 192, o = fb % 192;
        const float* Wm = which == 0 ? Wq : (which == 1 ? Wk : Wv);
        const float* P  = which == 0 ? pw_q : (which == 1 ? pw_kv : pw_kv + C_*C_);
        f16* Mo         = which == 0 ? Mq : (which == 1 ? Mk : Mv);
        __shared__ float wrow[C_];
        if (tid < C_) wrow[tid] = Wm[o*C_ + tid];
        __syncthreads();
        if (tid < C_) {
            float acc = 0.f;
            #pragma unroll 8
            for (int j = 0; j < C_; ++j)
                acc = fmaf(wrow[j], P[j*C_ + tid], acc);
            Mo[o*C_ + tid] = (f16)acc;
        }
    } else {
        int i = (blk - QB - KB - 576)*256 + tid;   // BB*C_*48 = 73728 exactly
        int b = i / (C_*48);
        int rem = i % (C_*48);
        int c = rem / 48;
        int m = MM + (rem % 48);
        vt[((size_t)b*C_ + c)*VT_LD + m] = (f16)0.f;
    }
}

// ---------------------------------------------------------------------------
// K/V projections only (Q is fused into attn). 128-thread blocks, 32 rows.
__global__ __launch_bounds__(128, 1) void proj_kv(
    const f16* __restrict__ ukv,
    const f16* __restrict__ Mk, const f16* __restrict__ Mv,
    const float* __restrict__ bk, const float* __restrict__ bv,
    f16* __restrict__ kb, f16* __restrict__ vt)
{
    int tid  = threadIdx.x;
    int w    = tid >> 6, l = tid & 63;
    int lrow = l & 15,  lgrp = l >> 4;
    int blk  = blockIdx.x;
    int path = blk < KVPB ? 1 : 2;
    int rblk = path == 1 ? blk : blk - KVPB;
    int r0 = rblk*32 + w*16;

    const f16* urow = ukv + (size_t)(r0 + lrow)*C_;
    f16x8 a[6];
    #pragma unroll
    for (int ch = 0; ch < 6; ++ch)
        a[ch] = *(const f16x8*)(urow + ch*32 + lgrp*8);

    f16x8 bfA[6], bfB[6];
    const f16* Mm = path == 1 ? Mk : Mv;

    #pragma unroll
    for (int ch = 0; ch < 6; ++ch)
        bfA[ch] = *(const f16x8*)(Mm + (size_t)lrow*C_ + ch*32 + lgrp*8);

    if (path == 1) {
        #pragma unroll
        for (int ct = 0; ct < 12; ++ct) {            // K projection (swapped)
            f16x8* cur = (ct & 1) ? bfB : bfA;
            f16x8* nxt = (ct & 1) ? bfA : bfB;
            if (ct < 11) {
                const f16* mrow = Mm + (size_t)((ct+1)*16 + lrow)*C_;
                #pragma unroll
                for (int ch = 0; ch < 6; ++ch)
                    nxt[ch] = *(const f16x8*)(mrow + ch*32 + lgrp*8);
            }
            f32x4 acc = {0.f,0.f,0.f,0.f};
            #pragma unroll
            for (int ch = 0; ch < 6; ++ch)
                acc = MFMA16(cur[ch], a[ch], acc);
            float4 bo = *(const float4*)(bk + ct*16 + lgrp*4);
            f16x4 st;
            st[0] = (f16)(acc[0] + bo.x);
            st[1] = (f16)(acc[1] + bo.y);
            st[2] = (f16)(acc[2] + bo.z);
            st[3] = (f16)(acc[3] + bo.w);
            *(f16x4*)(kb + (size_t)(r0 + lrow)*C_ + ct*16 + lgrp*4) = st;
        }
    } else {
        #pragma unroll
        for (int ct = 0; ct < 12; ++ct) {            // V projection (transposed)
            f16x8* cur = (ct & 1) ? bfB : bfA;
            f16x8* nxt = (ct & 1) ? bfA : bfB;
            if (ct < 11) {
                const f16* mrow = Mv + (size_t)((ct+1)*16 + lrow)*C_;
                #pragma unroll
                for (int ch = 0; ch < 6; ++ch)
                    nxt[ch] = *(const f16x8*)(mrow + ch*32 + lgrp*8);
            }
            int o = ct*16 + lrow;
            f32x4 acc = {0.f,0.f,0.f,0.f};
            #pragma unroll
            for (int ch = 0; ch < 6; ++ch)
                acc = MFMA16(a[ch], cur[ch], acc);
            float bo = bv[o];
            int rg = r0 + lgrp*4;
            int b  = rg / MM, m = rg % MM;            // 784 % 16 == 0
            f16x4 st;
            st[0] = (f16)(acc[0] + bo);
            st[1] = (f16)(acc[1] + bo);
            st[2] = (f16)(acc[2] + bo);
            st[3] = (f16)(acc[3] + bo);
            *(f16x4*)(vt + ((size_t)b*C_ + o)*VT_LD + m) = st;
        }
    }
}

// ---------------------------------------------------------------------------
// Flash attention R25: R24 + tile-0 DMA hoisted ABOVE the Q-proj MFMAs
// (tile 0 targets K0/V0 which do NOT alias qL=K1, so no ordering hazard;
// the ~500-900cy staging latency now hides under the 18 projection MFMAs).
__device__ __forceinline__ void stage_tile(
    int w, int l, f16* ldsKb, f16* ldsVb,
    const f16* __restrict__ kbb, const f16* __restrict__ vbb, int m0)
{
    int rr = l >> 3, p = l & 7;
    #pragma unroll
    for (int j = 0; j < 4; ++j) {
        int u = w + j*4;
        if (u < 8) {                      // K rows 8u..8u+7
            int r = u*8 + rr;
            int c = p ^ (r & 7);
            gload16(kbb + (size_t)(m0 + r)*C_ + c*8, ldsKb + u*512);
        } else if (u < 14) {              // V rows (d) 8(u-8)..+7
            int d = (u-8)*8 + rr;
            int c = p ^ (d & 7);
            gload16(vbb + (size_t)d*VT_LD + m0 + c*8, ldsVb + (u-8)*512);
        }
    }
}

__device__ __forceinline__ float max16(const f32x4* s)
{
    float t0 = fmaxf(fmaxf(s[0][0], s[0][1]), fmaxf(s[0][2], s[0][3]));
    float t1 = fmaxf(fmaxf(s[1][0], s[1][1]), fmaxf(s[1][2], s[1][3]));
    float t2 = fmaxf(fmaxf(s[2][0], s[2][1]), fmaxf(s[2][2], s[2][3]));
    float t3 = fmaxf(fmaxf(s[3][0], s[3][1]), fmaxf(s[3][2], s[3][3]));
    return fmaxf(fmaxf(t0, t1), fmaxf(t2, t3));
}

__device__ __forceinline__ void compute_tile64(
    const f16* ldsKb, const f16* ldsVb,
    const f16x8& qf0, const f16x4& qfh,
    float& mrun, float& lrun, f32x4& o0, f32x4& o1, f32x4& o2,
    int lrow, int g, bool first)
{
    const char* kP = (const char*)ldsKb;
    const char* vP = (const char*)ldsVb;
    f32x4 z = {0.f,0.f,0.f,0.f};
    int sw = lrow & 7;
    int cA = (g ^ sw) << 4;                                  // d 0..31 (16B)
    int cH = (((4 + (g >> 1)) ^ sw) << 4) + ((g & 1) << 3);  // d 32..47 (8B)

    f32x4 s[4];
    __builtin_amdgcn_s_setprio(1);
    #pragma unroll
    for (int j = 0; j < 4; ++j) {
        const char* rb = kP + (16*j + lrow)*128;
        f32x4 t = MFMA16(*(const f16x8*)(rb + cA), qf0, z);
        s[j] = MFMAK16(*(const f16x4*)(rb + cH), qfh, t);
    }
    __builtin_amdgcn_s_setprio(0);

    u32 pk[8];
    float tl = max16(s);
    bool fast = false;
    if (!first) fast = (__all(tl <= mrun + 8.0f) != 0);

    if (fast) {
        // defer-max: keep mrun; P = exp2(s - mrun) <= 2^8, no O rescale
        float psum = 0.f;
        #pragma unroll
        for (int j = 0; j < 4; ++j) {
            #pragma unroll
            for (int r = 0; r < 4; ++r) {
                s[j][r] = exp2f(s[j][r] - mrun);
                psum += s[j][r];
            }
        }
        lrun += psum;     // per-lane partial; reduced at epilogue
        #pragma unroll
        for (int j = 0; j < 4; ++j) {
            pk[j*2]   = pkrtz(s[j][0], s[j][1]);
            pk[j*2+1] = pkrtz(s[j][2], s[j][3]);
        }
    } else {
        float tmax = tl;
        tmax = fmaxf(tmax, __shfl_xor(tmax, 16));
        tmax = fmaxf(tmax, __shfl_xor(tmax, 32));
        float mnew = fmaxf(mrun, tmax);
        float corr = exp2f(mrun - mnew);
        mrun = mnew;
        float psum = 0.f;
        #pragma unroll
        for (int j = 0; j < 4; ++j) {
            #pragma unroll
            for (int r = 0; r < 4; ++r) {
                s[j][r] = exp2f(s[j][r] - mnew);
                psum += s[j][r];
            }
        }
        lrun = lrun*corr + psum;
        #pragma unroll
        for (int j = 0; j < 4; ++j) {
            pk[j*2]   = pkrtz(s[j][0], s[j][1]);
            pk[j*2+1] = pkrtz(s[j][2], s[j][3]);
        }
        #pragma unroll
        for (int r = 0; r < 4; ++r) {
            o0[r] *= corr; o1[r] *= corr; o2[r] *= corr;
        }
    }

    // PV: per 16-key chunk, B-frag is lane-local {pk[2ch],pk[2ch+1]};
    // A-frag = Vt[d=16*db+lrow][m0+16ch+g*4 .. +3] (8B swizzled LDS read).
    #pragma unroll
    for (int ch = 0; ch < 4; ++ch) {
        u32x2 pw = { pk[2*ch], pk[2*ch+1] };
        f16x4 pb = __builtin_bit_cast(f16x4, pw);
        int off = (((2*ch + (g >> 1)) ^ sw) << 4) + ((g & 1) << 3);
        f16x4 v0 = *(const f16x4*)(vP + lrow*128      + off);
        f16x4 v1 = *(const f16x4*)(vP + (16+lrow)*128 + off);
        f16x4 v2 = *(const f16x4*)(vP + (32+lrow)*128 + off);
        __builtin_amdgcn_s_setprio(1);
        o0 = MFMAK16(v0, pb, o0);
        o1 = MFMAK16(v1, pb, o1);
        o2 = MFMAK16(v2, pb, o2);
        __builtin_amdgcn_s_setprio(0);
    }
}

// Slim tail: keys m0..m0+15 only (block j=0, PV chunk ch=0). Bit-identical
// to a masked 64-key tail: masked lanes contributed exp2(-inf)=0.
__device__ __forceinline__ void compute_tail16(
    const f16* ldsKb, const f16* ldsVb,
    const f16x8& qf0, const f16x4& qfh,
    float& mrun, float& lrun, f32x4& o0, f32x4& o1, f32x4& o2,
    int lrow, int g)
{
    const char* kP = (const char*)ldsKb;
    const char* vP = (const char*)ldsVb;
    f32x4 z = {0.f,0.f,0.f,0.f};
    int sw = lrow & 7;
    int cA = (g ^ sw) << 4;
    int cH = (((4 + (g >> 1)) ^ sw) << 4) + ((g & 1) << 3);

    const char* rb = kP + lrow*128;
    f32x4 t  = MFMA16(*(const f16x8*)(rb + cA), qf0, z);
    f32x4 s0 = MFMAK16(*(const f16x4*)(rb + cH), qfh, t);

    float tl = fmaxf(fmaxf(s0[0], s0[1]), fmaxf(s0[2], s0[3]));
    bool fast = (__all(tl <= mrun + 8.0f) != 0);
    u32 pk0, pk1;
    if (fast) {
        float psum = 0.f;
        #pragma unroll
        for (int r = 0; r < 4; ++r) { s0[r] = exp2f(s0[r] - mrun); psum += s0[r]; }
        lrun += psum;
        pk0 = pkrtz(s0[0], s0[1]); pk1 = pkrtz(s0[2], s0[3]);
    } else {
        float tmax = tl;
        tmax = fmaxf(tmax, __shfl_xor(tmax, 16));
        tmax = fmaxf(tmax, __shfl_xor(tmax, 32));
        float mnew = fmaxf(mrun, tmax);
        float corr = exp2f(mrun - mnew);
        mrun = mnew;
        float psum = 0.f;
        #pragma unroll
        for (int r = 0; r < 4; ++r) { s0[r] = exp2f(s0[r] - mnew); psum += s0[r]; }
        lrun = lrun*corr + psum;
        pk0 = pkrtz(s0[0], s0[1]); pk1 = pkrtz(s0[2], s0[3]);
        #pragma unroll
        for (int r = 0; r < 4; ++r) { o0[r] *= corr; o1[r] *= corr; o2[r] *= corr; }
    }
    u32x2 pw = { pk0, pk1 };
    f16x4 pb = __builtin_bit_cast(f16x4, pw);
    int off = (((g >> 1) ^ sw) << 4) + ((g & 1) << 3);   // ch = 0
    f16x4 v0 = *(const f16x4*)(vP + lrow*128      + off);
    f16x4 v1 = *(const f16x4*)(vP + (16+lrow)*128 + off);
    f16x4 v2 = *(const f16x4*)(vP + (32+lrow)*128 + off);
    o0 = MFMAK16(v0, pb, o0);
    o1 = MFMAK16(v1, pb, o1);
    o2 = MFMAK16(v2, pb, o2);
}

__global__ __launch_bounds__(256, 2) void attn_mfma(
    const f16* __restrict__ uq, const f16* __restrict__ Mq,
    const float* __restrict__ bq,
    const f16* __restrict__ kb, const f16* __restrict__ vt,
    float* __restrict__ out)
{
    // flat LDS: K0 | K1 | V0 | V1 ; qL aliases K1 (dead after prologue,
    // first overwritten when tile 1 stages inside the loop)
    __shared__ __align__(16) f16 lds[2*4096 + 2*3072];   // 28672 B
    f16* ldsK0 = lds;
    f16* ldsK1 = lds + 4096;
    f16* ldsV0 = lds + 8192;
    f16* ldsV1 = lds + 8192 + 3072;
    f16* qL    = ldsK1;                  // 4 waves x 896 f16 = 3584 <= 4096

    int tid  = threadIdx.x;
    int w    = tid >> 6, l = tid & 63;
    int lrow = l & 15,  g = l >> 4;
    // XCD swizzle: 1568 = 8*196; 4 (b,h) groups per XCD -> KV L2-resident.
    int swz  = (blockIdx.x & 7)*196 + (blockIdx.x >> 3);
    int bh   = swz / 49, qblk = swz % 49;
    int h    = bh & 3, b = bh >> 2;
    int n0   = qblk*64 + w*16;

    const f16* kbb = kb + (size_t)b*MM*C_ + h*HD;
    const f16* vbb = vt + ((size_t)b*C_ + h*HD)*VT_LD;

    // ---- u-frags head the dependency chain: issue first ----
    const f16* urow = uq + ((size_t)b*NN + n0 + lrow)*C_;
    f16x8 ufr[6];
    #pragma unroll
    for (int ch = 0; ch < 6; ++ch)
        ufr[ch] = *(const f16x8*)(urow + ch*32 + g*8);

    // ---- HOISTED: stage tile 0 into K0/V0 (no qL alias) so its DMA
    //      latency hides under the Q-projection MFMAs below ----
    stage_tile(w, l, ldsK0, ldsV0, kbb, vbb, 0);

    // ---- fused Q projection ----
    {
        const float qsc = 0.14433756729740643f * 1.4426950408889634f;
        f16* qw = qL + w*896;
        #pragma unroll
        for (int dt = 0; dt < 3; ++dt) {
            const f16* mrow = Mq + (size_t)(h*HD + dt*16 + lrow)*C_;
            f32x4 acc = {0.f,0.f,0.f,0.f};
            #pragma unroll
            for (int ch = 0; ch < 6; ++ch)
                acc = MFMA16(*(const f16x8*)(mrow + ch*32 + g*8), ufr[ch], acc);
            float4 bo = *(const float4*)(bq + h*HD + dt*16 + g*4);
            f16x4 st;
            st[0] = (f16)((acc[0] + bo.x)*qsc);
            st[1] = (f16)((acc[1] + bo.y)*qsc);
            st[2] = (f16)((acc[2] + bo.z)*qsc);
            st[3] = (f16)((acc[3] + bo.w)*qsc);
            *(f16x4*)(qw + lrow*56 + dt*16 + g*4) = st;   // n=lrow, d=dt*16+g*4+r
        }
    }
    // read own slice (asm forces the lgkm wait), then barrier so no wave
    // stages tile 1 (into ldsK1) before all waves finished reading qL
    f16x8 qf0 = *(const f16x8*)(qL + w*896 + lrow*56 + g*8);
    f16x4 qfh = *(const f16x4*)(qL + w*896 + lrow*56 + 32 + g*4);
    asm volatile("" :: "v"(qf0), "v"(qfh));
    __builtin_amdgcn_s_barrier();

    float mrun = -1e30f, lrun = 0.f;
    f32x4 o0 = {0.f,0.f,0.f,0.f}, o1 = o0, o2 = o0;

    for (int t = 0; t < 12; ++t) {
        int nb = t & 1;
        stage_tile(w, l, nb ? ldsK0 : ldsK1, nb ? ldsV0 : ldsV1,
                   kbb, vbb, (t+1)*64);
        __builtin_amdgcn_sched_barrier(0);
        if (w < 2) asm volatile("s_waitcnt vmcnt(4)" ::: "memory");
        else       asm volatile("s_waitcnt vmcnt(3)" ::: "memory");
        __builtin_amdgcn_s_barrier();
        __builtin_amdgcn_sched_barrier(0);
        compute_tile64(nb ? ldsK1 : ldsK0, nb ? ldsV1 : ldsV0, qf0, qfh,
                       mrun, lrun, o0, o1, o2, lrow, g, t == 0);
        __builtin_amdgcn_sched_barrier(0);
        __builtin_amdgcn_s_barrier();
    }
    // slim tail: tile 12 (keys 768..783) was staged at t=11 into K0/V0
    asm volatile("s_waitcnt vmcnt(0)" ::: "memory");
    __builtin_amdgcn_s_barrier();
    __builtin_amdgcn_sched_barrier(0);
    compute_tail16(ldsK0, ldsV0, qf0, qfh, mrun, lrun, o0, o1, o2, lrow, g);

    // epilogue: reduce per-lane partial lrun across the 4 lanes of this query
    lrun += __shfl_xor(lrun, 16);
    lrun += __shfl_xor(lrun, 32);
    float inv = 1.f / lrun;
    f32x4 r0, r1, r2;
    #pragma unroll
    for (int r = 0; r < 4; ++r) {
        r0[r] = o0[r]*inv; r1[r] = o1[r]*inv; r2[r] = o2[r]*inv;
    }
    float* obase = out + ((size_t)b*NN + n0 + lrow)*C_ + h*HD + g*4;
    *(f32x4*)(obase)      = r0;
    *(f32x4*)(obase + 16) = r1;
    *(f32x4*)(obase + 32) = r2;
}

// ---------------------------------------------------------------------------
extern "C" void kernel_launch(void* const* d_in, const int* in_sizes, int n_in,
                              void* d_out, int out_size, void* d_ws, size_t ws_size,
                              hipStream_t stream)
{
    const float* x     = (const float*)d_in[0];
    const float* dw_q  = (const float*)d_in[3];
    const float* bnqg  = (const float*)d_in[4];
    const float* bnqb  = (const float*)d_in[5];
    const float* bnqm  = (const float*)d_in[6];
    const float* bnqv  = (const float*)d_in[7];
    const float* pw_q  = (const float*)d_in[8];
    const float* dw_kv = (const float*)d_in[9];
    const float* bnkg  = (const float*)d_in[10];
    const float* bnkb  = (const float*)d_in[11];
    const float* bnkm  = (const float*)d_in[12];
    const float* bnkvv = (const float*)d_in[13];
    const float* pw_kv = (const float*)d_in[14];
    const float* Wq    = (const float*)d_in[15];
    const float* bq    = (const float*)d_in[16];
    const float* Wk    = (const float*)d_in[17];
    const float* bk    = (const float*)d_in[18];
    const float* Wv    = (const float*)d_in[19];
    const float* bv    = (const float*)d_in[20];
    float* out = (float*)d_out;

    f16* p   = (f16*)d_ws;
    f16* Mq16  = p;  p += C_*C_;
    f16* Mk16  = p;  p += C_*C_;
    f16* Mv16  = p;  p += C_*C_;
    f16* uq16  = p;  p += (size_t)BB*NN*C_ + 256;    // pad: frag tail reads
    f16* ukv16 = p;  p += (size_t)BB*MM*C_;
    f16* kb16  = p;  p += (size_t)BB*MM*C_ + 16384;  // pad: tail-tile staging overread
    f16* vt16  = p;  p += (size_t)BB*C_*VT_LD;

    prep_all<<<1746, 256, 0, stream>>>(
        x, dw_q, bnqg, bnqb, bnqm, bnqv,
        dw_kv, bnkg, bnkb, bnkm, bnkvv,
        Wq, Wk, Wv, pw_q, pw_kv,
        uq16, ukv16, Mq16, Mk16, Mv16, vt16);

    proj_kv<<<2*KVPB, 128, 0, stream>>>(
        ukv16, Mk16, Mv16, bk, bv, kb16, vt16);

    attn_mfma<<<1568, 256, 0, stream>>>(uq16, Mq16, bq, kb16, vt16, out);
}